// Round 1
// baseline (719.121 us; speedup 1.0000x reference)
//
#include <hip/hip_runtime.h>
#include <math.h>

// Problem constants (fixed instance)
#define E_EDGES 524288
#define NNODES  5120
#define KF      64
#define DF      128
#define FF      32
#define NPER    80   // nodes per batch (16 nuc + 64 elec)

// workspace layout (bytes)
#define WS_CNT   0
#define WS_Z     256
#define Z_BYTES  (3u*NNODES*KF*4u)                 // 3,932,160
#define WS_HX    (WS_Z + Z_BYTES)                  // 3,932,416
#define HX_BYTES (NNODES*KF*4u)                    // 1,310,720
#define LIST_CAP (E_EDGES + 128)
#define WS_EL    (WS_HX + HX_BYTES)
#define WS_SL    (WS_EL + LIST_CAP*4u)
#define WS_RL    (WS_SL + LIST_CAP*4u)

__device__ __forceinline__ float ssp_f(float x) {
    float t  = __expf(-fabsf(x));
    float sp = fmaxf(x, 0.0f) + __logf(1.0f + t);
    return sp - 0.6931471805599453f;
}

__device__ __forceinline__ int slot_of(int t, int r) {
    int slot = (t == 3) ? 0 : (t == 4) ? 1 : (t == 1) ? 2 : -1;
    if ((r % NPER) < 16) slot = -1;   // nuc receivers never read
    return slot;
}

// ---- build hx = concat(nuc, elec @ h_W + h_b) -------------------------------
__global__ void hx_k(const float* __restrict__ nuc, const float* __restrict__ elec,
                     const float* __restrict__ hW, const float* __restrict__ hb,
                     float* __restrict__ hx)
{
    int gw   = (blockIdx.x * blockDim.x + threadIdx.x) >> 6;  // one wave per node
    int lane = threadIdx.x & 63;
    if (gw >= NNODES) return;
    int b = gw / NPER, p = gw % NPER;
    float v;
    if (p < 16) {
        v = nuc[((size_t)b * 16 + p) * KF + lane];
    } else {
        int pe = p - 16;
        const float* er = elec + ((size_t)b * 64 + pe) * DF;
        float acc = hb[lane];
        #pragma unroll 8
        for (int d = 0; d < DF; d++) acc = __fmaf_rn(er[d], hW[d * KF + lane], acc);
        v = acc;
    }
    hx[(size_t)gw * KF + lane] = v;
}

// ---- count active edges per slot -------------------------------------------
__global__ void count_k(const int* __restrict__ et, const int* __restrict__ recv,
                        int* __restrict__ cnt)
{
    int e    = blockIdx.x * blockDim.x + threadIdx.x;
    int lane = threadIdx.x & 63;
    int slot = slot_of(et[e], recv[e]);
    #pragma unroll
    for (int s = 0; s < 3; s++) {
        unsigned long long m = __ballot(slot == s);
        if (m && lane == (__ffsll((unsigned long long)m) - 1))
            atomicAdd(&cnt[s], __popcll(m));
    }
}

// ---- compute 64-aligned segment starts/ends/cursors ------------------------
__global__ void scan_k(int* __restrict__ c)
{
    int c0 = c[0], c1 = c[1], c2 = c[2];
    int a0 = (c0 + 63) & ~63, a1 = (c1 + 63) & ~63, a2 = (c2 + 63) & ~63;
    c[8]  = 0;          c[9]  = a0;        c[10] = a0 + a1;        // starts
    c[12] = c0;         c[13] = a0 + c1;   c[14] = a0 + a1 + c2;   // ends
    c[4]  = 0;          c[5]  = a0;        c[6]  = a0 + a1;        // cursors
    c[16] = a0 + a1 + a2;                                          // total padded
}

// ---- scatter compacted edge lists ------------------------------------------
__global__ void scatter_k(const int* __restrict__ et, const int* __restrict__ snd,
                          const int* __restrict__ recv, int* __restrict__ cnt,
                          int* __restrict__ elist, int* __restrict__ slist,
                          int* __restrict__ rlist)
{
    int e    = blockIdx.x * blockDim.x + threadIdx.x;
    int lane = threadIdx.x & 63;
    int slot = slot_of(et[e], recv[e]);
    int sv = snd[e], rv = recv[e];
    #pragma unroll
    for (int s = 0; s < 3; s++) {
        unsigned long long m = __ballot(slot == s);
        if (!m) continue;
        int leader = __ffsll((unsigned long long)m) - 1;
        int base = 0;
        if (lane == leader) base = atomicAdd(&cnt[4 + s], __popcll(m));
        base = __shfl(base, leader);
        if (slot == s) {
            int pos = base + __popcll(m & ((1ull << lane) - 1ull));
            elist[pos] = e; slist[pos] = sv; rlist[pos] = rv;
        }
    }
}

// ---- main: per-edge MLP + transpose + coalesced atomic scatter -------------
__global__ __launch_bounds__(256, 2) void edge_k(
    const float* __restrict__ dist, const float* __restrict__ hx,
    const int* __restrict__ elist, const int* __restrict__ slist,
    const int* __restrict__ rlist, const int* __restrict__ cnt,
    float* __restrict__ z,
    const float* __restrict__ w1_0, const float* __restrict__ b1_0,
    const float* __restrict__ w2_0, const float* __restrict__ b2_0,
    const float* __restrict__ w1_1, const float* __restrict__ b1_1,
    const float* __restrict__ w2_1, const float* __restrict__ b2_1,
    const float* __restrict__ w1_2, const float* __restrict__ b1_2,
    const float* __restrict__ w2_2, const float* __restrict__ b2_2)
{
    __shared__ float tb[4 * 64 * 64];    // 64 KiB: one 64x64 f32 tile per wave
    const int lane = threadIdx.x & 63;
    const int wid  = threadIdx.x >> 6;
    float* tw = &tb[wid * 64 * 64];

    const int start1 = cnt[9], start2 = cnt[10];
    const int end0 = cnt[12], end1 = cnt[13], end2 = cnt[14];
    const int total = cnt[16];
    const int wavestride = gridDim.x * 4 * 64;

    for (int base = (blockIdx.x * 4 + wid) * 64; base < total; base += wavestride) {
        int idx = base + lane;
        int s = (base >= start2) ? 2 : (base >= start1) ? 1 : 0;
        int endS = (s == 0) ? end0 : (s == 1) ? end1 : end2;
        bool act = idx < endS;
        unsigned long long amask = __ballot(act);
        int nact = __popcll(amask);
        if (nact == 0) continue;

        int e = 0, sj_own = 0, rj_own = 0;
        if (act) { e = elist[idx]; sj_own = slist[idx]; rj_own = rlist[idx]; }

        s = __builtin_amdgcn_readfirstlane(s);
        const float *W1, *B1, *W2, *B2;
        if (s == 0)      { W1 = w1_0; B1 = b1_0; W2 = w2_0; B2 = b2_0; }
        else if (s == 1) { W1 = w1_1; B1 = b1_1; W2 = w2_1; B2 = b2_1; }
        else             { W1 = w1_2; B1 = b1_2; W2 = w2_2; B2 = b2_2; }

        // load dist row (32 floats) into registers
        float dv[32];
        {
            const float4* dp = (const float4*)(dist + (size_t)e * FF);
            #pragma unroll
            for (int q = 0; q < 8; q++) {
                float4 v = dp[q];
                dv[q*4+0] = v.x; dv[q*4+1] = v.y; dv[q*4+2] = v.z; dv[q*4+3] = v.w;
            }
        }
        // layer 1: h = ssp(d @ W1 + b1)   (weights wave-uniform -> s_load)
        float h[32];
        #pragma unroll
        for (int j = 0; j < 32; j++) h[j] = B1[j];
        #pragma unroll
        for (int i = 0; i < 32; i++) {
            float di = dv[i];
            #pragma unroll
            for (int j = 0; j < 32; j++) h[j] = __fmaf_rn(di, W1[i*32 + j], h[j]);
        }
        #pragma unroll
        for (int j = 0; j < 32; j++) h[j] = ssp_f(h[j]);

        // layer 2: o = h @ W2 + b2
        float o[64];
        #pragma unroll
        for (int k = 0; k < 64; k++) o[k] = B2[k];
        #pragma unroll
        for (int j = 0; j < 32; j++) {
            float hj = h[j];
            #pragma unroll
            for (int k = 0; k < 64; k++) o[k] = __fmaf_rn(hj, W2[j*64 + k], o[k]);
        }

        // transpose into LDS, XOR-swizzled float4 quads (conflict-floor writes)
        #pragma unroll
        for (int q = 0; q < 16; q++) {
            int c4 = q ^ (lane & 15);
            float4 v = make_float4(o[q*4+0], o[q*4+1], o[q*4+2], o[q*4+3]);
            *(float4*)&tw[lane * 64 + c4 * 4] = v;
        }

        // scatter: per edge j, lanes k=0..63 do contiguous atomic adds
        float* zs = z + (size_t)s * NNODES * KF;
        for (int j = 0; j < nact; j++) {
            int rj = __shfl(rj_own, j);
            int sj = __shfl(sj_own, j);
            float ov = tw[j * 64 + (((lane >> 2) ^ (j & 15)) << 2) + (lane & 3)];
            float hv = hx[(size_t)sj * KF + lane];
            atomicAdd(&zs[(size_t)rj * KF + lane], ov * hv);
        }
    }
}

// ---- output: elec_out = elec + sum_s (z_s[:,16:] @ gW_s + gb_s) ------------
__global__ void out_k(const float* __restrict__ elec, const float* __restrict__ z,
                      const float* __restrict__ g0W, const float* __restrict__ g0b,
                      const float* __restrict__ g1W, const float* __restrict__ g1b,
                      const float* __restrict__ g2W, const float* __restrict__ g2b,
                      float* __restrict__ out)
{
    __shared__ float zr[8][192];
    int row0 = blockIdx.x * 8;            // 512 blocks, 8 elec rows each
    int tid  = threadIdx.x;               // 128 threads
    for (int t = tid; t < 8 * 192; t += 128) {
        int n = t / 192, u = t % 192;
        int s = u >> 6, k = u & 63;
        int row = row0 + n;
        int node = (row >> 6) * NPER + 16 + (row & 63);
        zr[n][u] = z[((size_t)s * NNODES + node) * KF + k];
    }
    __syncthreads();
    int d = tid;
    float gb = g0b[d] + g1b[d] + g2b[d];
    float acc[8];
    #pragma unroll
    for (int n = 0; n < 8; n++) acc[n] = elec[(size_t)(row0 + n) * DF + d] + gb;

    for (int k = 0; k < 64; k++) {
        float w = g0W[k * DF + d];
        #pragma unroll
        for (int n = 0; n < 8; n++) acc[n] = __fmaf_rn(zr[n][k], w, acc[n]);
    }
    for (int k = 0; k < 64; k++) {
        float w = g1W[k * DF + d];
        #pragma unroll
        for (int n = 0; n < 8; n++) acc[n] = __fmaf_rn(zr[n][64 + k], w, acc[n]);
    }
    for (int k = 0; k < 64; k++) {
        float w = g2W[k * DF + d];
        #pragma unroll
        for (int n = 0; n < 8; n++) acc[n] = __fmaf_rn(zr[n][128 + k], w, acc[n]);
    }
    #pragma unroll
    for (int n = 0; n < 8; n++) out[(size_t)(row0 + n) * DF + d] = acc[n];
}

extern "C" void kernel_launch(void* const* d_in, const int* in_sizes, int n_in,
                              void* d_out, int out_size, void* d_ws, size_t ws_size,
                              hipStream_t stream)
{
    const float* nuc  = (const float*)d_in[0];
    const float* elec = (const float*)d_in[1];
    const float* dist = (const float*)d_in[2];
    const float* wsW1 = (const float*)d_in[3];
    const float* wsB1 = (const float*)d_in[4];
    const float* wsW2 = (const float*)d_in[5];
    const float* wsB2 = (const float*)d_in[6];
    const float* gsW  = (const float*)d_in[7];
    const float* gsB  = (const float*)d_in[8];
    const float* waW1 = (const float*)d_in[9];
    const float* waB1 = (const float*)d_in[10];
    const float* waW2 = (const float*)d_in[11];
    const float* waB2 = (const float*)d_in[12];
    const float* gaW  = (const float*)d_in[13];
    const float* gaB  = (const float*)d_in[14];
    const float* wnW1 = (const float*)d_in[15];
    const float* wnB1 = (const float*)d_in[16];
    const float* wnW2 = (const float*)d_in[17];
    const float* wnB2 = (const float*)d_in[18];
    const float* gnW  = (const float*)d_in[19];
    const float* gnB  = (const float*)d_in[20];
    const float* hW   = (const float*)d_in[21];
    const float* hb   = (const float*)d_in[22];
    const int* e_typ    = (const int*)d_in[23];
    const int* senders  = (const int*)d_in[24];
    const int* receivers= (const int*)d_in[25];
    float* out = (float*)d_out;

    char* ws = (char*)d_ws;
    int*   cnt   = (int*)(ws + WS_CNT);
    float* z     = (float*)(ws + WS_Z);
    float* hx    = (float*)(ws + WS_HX);
    int*   elist = (int*)(ws + WS_EL);
    int*   slist = (int*)(ws + WS_SL);
    int*   rlist = (int*)(ws + WS_RL);

    // zero counters + z in one shot (contiguous)
    hipMemsetAsync(d_ws, 0, WS_Z + Z_BYTES, stream);

    hx_k<<<dim3(NNODES * 64 / 256), dim3(256), 0, stream>>>(nuc, elec, hW, hb, hx);
    count_k<<<dim3(E_EDGES / 256), dim3(256), 0, stream>>>(e_typ, receivers, cnt);
    scan_k<<<dim3(1), dim3(1), 0, stream>>>(cnt);
    scatter_k<<<dim3(E_EDGES / 256), dim3(256), 0, stream>>>(e_typ, senders, receivers,
                                                             cnt, elist, slist, rlist);
    edge_k<<<dim3(1024), dim3(256), 0, stream>>>(
        dist, hx, elist, slist, rlist, cnt, z,
        wsW1, wsB1, wsW2, wsB2,    // slot 0: same (et==3)
        waW1, waB1, waW2, waB2,    // slot 1: anti (et==4)
        wnW1, wnB1, wnW2, wnB2);   // slot 2: n    (et==1)
    out_k<<<dim3(512), dim3(128), 0, stream>>>(elec, z, gsW, gsB, gaW, gaB, gnW, gnB, out);
}

// Round 2
// 165.863 us; speedup vs baseline: 4.3356x; 4.3356x over previous
//
#include <hip/hip_runtime.h>
#include <math.h>

// Problem constants (fixed instance)
#define E_EDGES 524288
#define NNODES  5120
#define KF      64
#define DF      128
#define FF      32
#define NPER    80   // nodes per batch (16 nuc + 64 elec)
#define NBLK    2048 // E_EDGES / 256

// workspace layout (bytes)
#define WS_CNT   0
#define WS_Z     256
#define Z_BYTES  (3u*NNODES*KF*4u)                 // 3,932,160
#define WS_HX    (WS_Z + Z_BYTES)                  // 3,932,416
#define HX_BYTES (NNODES*KF*4u)                    // 1,310,720
#define LIST_CAP (E_EDGES + 128)
#define WS_EL    (WS_HX + HX_BYTES)
#define WS_SL    (WS_EL + LIST_CAP*4u)
#define WS_RL    (WS_SL + LIST_CAP*4u)
#define WS_BC    (WS_RL + LIST_CAP*4u)             // blk counts  [3][NBLK]
#define WS_BB    (WS_BC + 3u*NBLK*4u)              // blk bases   [3][NBLK]

__device__ __forceinline__ float ssp_f(float x) {
    float t  = __expf(-fabsf(x));
    float sp = fmaxf(x, 0.0f) + __logf(1.0f + t);
    return sp - 0.6931471805599453f;
}

__device__ __forceinline__ int slot_of(int t, int r) {
    int slot = (t == 3) ? 0 : (t == 4) ? 1 : (t == 1) ? 2 : -1;
    if ((r % NPER) < 16) slot = -1;   // nuc receivers never read
    return slot;
}

// ---- build hx = concat(nuc, elec @ h_W + h_b) -------------------------------
__global__ void hx_k(const float* __restrict__ nuc, const float* __restrict__ elec,
                     const float* __restrict__ hW, const float* __restrict__ hb,
                     float* __restrict__ hx)
{
    int gw   = (blockIdx.x * blockDim.x + threadIdx.x) >> 6;  // one wave per node
    int lane = threadIdx.x & 63;
    if (gw >= NNODES) return;
    int b = gw / NPER, p = gw % NPER;
    float v;
    if (p < 16) {
        v = nuc[((size_t)b * 16 + p) * KF + lane];
    } else {
        int pe = p - 16;
        const float* er = elec + ((size_t)b * 64 + pe) * DF;
        float acc = hb[lane];
        #pragma unroll 8
        for (int d = 0; d < DF; d++) acc = __fmaf_rn(er[d], hW[d * KF + lane], acc);
        v = acc;
    }
    hx[(size_t)gw * KF + lane] = v;
}

// ---- A: per-block per-slot counts (no returning atomics) -------------------
__global__ void count_k(const int* __restrict__ et, const int* __restrict__ recv,
                        int* __restrict__ blkcnt)
{
    __shared__ int bc[3];
    int tid = threadIdx.x;
    if (tid < 3) bc[tid] = 0;
    __syncthreads();
    int e    = blockIdx.x * blockDim.x + tid;
    int lane = tid & 63;
    int slot = slot_of(et[e], recv[e]);
    #pragma unroll
    for (int s = 0; s < 3; s++) {
        unsigned long long m = __ballot(slot == s);
        if (lane == 0 && m) atomicAdd(&bc[s], __popcll(m));
    }
    __syncthreads();
    if (tid < 3) blkcnt[tid * NBLK + blockIdx.x] = bc[tid];
}

// ---- B: single-block scan of block counts; segment starts/ends -------------
__global__ void scan_k(const int* __restrict__ blkcnt, int* __restrict__ blkbase,
                       int* __restrict__ c)
{
    __shared__ int tot[3];
    int s    = threadIdx.x >> 6;    // 3 waves, one per slot
    int lane = threadIdx.x & 63;
    int running = 0;
    for (int ch = 0; ch < NBLK / 64; ch++) {
        int v = blkcnt[s * NBLK + ch * 64 + lane];
        int x = v;
        #pragma unroll
        for (int off = 1; off < 64; off <<= 1) {
            int y = __shfl_up(x, off);
            if (lane >= off) x += y;
        }
        blkbase[s * NBLK + ch * 64 + lane] = running + x - v;  // exclusive
        running += __shfl(x, 63);
    }
    if (lane == 0) tot[s] = running;
    __syncthreads();
    if (threadIdx.x == 0) {
        int c0 = tot[0], c1 = tot[1], c2 = tot[2];
        int a0 = (c0 + 63) & ~63, a1 = (c1 + 63) & ~63, a2 = (c2 + 63) & ~63;
        c[8]  = 0;   c[9]  = a0;       c[10] = a0 + a1;        // starts
        c[12] = c0;  c[13] = a0 + c1;  c[14] = a0 + a1 + c2;   // ends
        c[16] = a0 + a1 + a2;                                  // total padded
    }
}

// ---- C: deterministic scatter (no global atomics) --------------------------
__global__ void scatter_k(const int* __restrict__ et, const int* __restrict__ snd,
                          const int* __restrict__ recv, const int* __restrict__ blkbase,
                          const int* __restrict__ cnt,
                          int* __restrict__ elist, int* __restrict__ slist,
                          int* __restrict__ rlist)
{
    __shared__ int wv[4][3];
    int tid  = threadIdx.x;
    int lane = tid & 63;
    int wid  = tid >> 6;
    int e    = blockIdx.x * blockDim.x + tid;
    int slot = slot_of(et[e], recv[e]);
    int sv = snd[e], rv = recv[e];
    unsigned long long msel = 0;
    #pragma unroll
    for (int s = 0; s < 3; s++) {
        unsigned long long m = __ballot(slot == s);
        if (lane == 0) wv[wid][s] = __popcll(m);
        if (slot == s) msel = m;
    }
    __syncthreads();
    if (slot >= 0) {
        int pre = 0;
        for (int w = 0; w < 4; w++) if (w < wid) pre += wv[w][slot];
        int pos = cnt[8 + slot] + blkbase[slot * NBLK + blockIdx.x] + pre
                + __popcll(msel & ((1ull << lane) - 1ull));
        elist[pos] = e; slist[pos] = sv; rlist[pos] = rv;
    }
}

// ---- main: per-edge MLP + transpose + coalesced atomic scatter -------------
__global__ __launch_bounds__(256, 2) void edge_k(
    const float* __restrict__ dist, const float* __restrict__ hx,
    const int* __restrict__ elist, const int* __restrict__ slist,
    const int* __restrict__ rlist, const int* __restrict__ cnt,
    float* __restrict__ z,
    const float* __restrict__ w1_0, const float* __restrict__ b1_0,
    const float* __restrict__ w2_0, const float* __restrict__ b2_0,
    const float* __restrict__ w1_1, const float* __restrict__ b1_1,
    const float* __restrict__ w2_1, const float* __restrict__ b2_1,
    const float* __restrict__ w1_2, const float* __restrict__ b1_2,
    const float* __restrict__ w2_2, const float* __restrict__ b2_2)
{
    __shared__ float tb[4 * 64 * 64];    // 64 KiB: one 64x64 f32 tile per wave
    const int lane = threadIdx.x & 63;
    const int wid  = threadIdx.x >> 6;
    float* tw = &tb[wid * 64 * 64];

    const int start1 = cnt[9], start2 = cnt[10];
    const int end0 = cnt[12], end1 = cnt[13], end2 = cnt[14];
    const int total = cnt[16];
    const int wavestride = gridDim.x * 4 * 64;

    for (int base = (blockIdx.x * 4 + wid) * 64; base < total; base += wavestride) {
        int idx = base + lane;
        int s = (base >= start2) ? 2 : (base >= start1) ? 1 : 0;
        int endS = (s == 0) ? end0 : (s == 1) ? end1 : end2;
        bool act = idx < endS;
        unsigned long long amask = __ballot(act);
        int nact = __popcll(amask);
        if (nact == 0) continue;

        int e = 0, sj_own = 0, rj_own = 0;
        if (act) { e = elist[idx]; sj_own = slist[idx]; rj_own = rlist[idx]; }

        s = __builtin_amdgcn_readfirstlane(s);
        const float *W1, *B1, *W2, *B2;
        if (s == 0)      { W1 = w1_0; B1 = b1_0; W2 = w2_0; B2 = b2_0; }
        else if (s == 1) { W1 = w1_1; B1 = b1_1; W2 = w2_1; B2 = b2_1; }
        else             { W1 = w1_2; B1 = b1_2; W2 = w2_2; B2 = b2_2; }

        // load dist row (32 floats) into registers
        float dv[32];
        {
            const float4* dp = (const float4*)(dist + (size_t)e * FF);
            #pragma unroll
            for (int q = 0; q < 8; q++) {
                float4 v = dp[q];
                dv[q*4+0] = v.x; dv[q*4+1] = v.y; dv[q*4+2] = v.z; dv[q*4+3] = v.w;
            }
        }
        // layer 1: h = ssp(d @ W1 + b1)   (weights wave-uniform -> s_load)
        float h[32];
        #pragma unroll
        for (int j = 0; j < 32; j++) h[j] = B1[j];
        #pragma unroll
        for (int i = 0; i < 32; i++) {
            float di = dv[i];
            #pragma unroll
            for (int j = 0; j < 32; j++) h[j] = __fmaf_rn(di, W1[i*32 + j], h[j]);
        }
        #pragma unroll
        for (int j = 0; j < 32; j++) h[j] = ssp_f(h[j]);

        // layer 2: o = h @ W2 + b2
        float o[64];
        #pragma unroll
        for (int k = 0; k < 64; k++) o[k] = B2[k];
        #pragma unroll
        for (int j = 0; j < 32; j++) {
            float hj = h[j];
            #pragma unroll
            for (int k = 0; k < 64; k++) o[k] = __fmaf_rn(hj, W2[j*64 + k], o[k]);
        }

        // transpose into LDS, XOR-swizzled float4 quads (conflict-floor writes)
        #pragma unroll
        for (int q = 0; q < 16; q++) {
            int c4 = q ^ (lane & 15);
            float4 v = make_float4(o[q*4+0], o[q*4+1], o[q*4+2], o[q*4+3]);
            *(float4*)&tw[lane * 64 + c4 * 4] = v;
        }

        // scatter: per edge j, lanes k=0..63 do contiguous atomic adds
        float* zs = z + (size_t)s * NNODES * KF;
        for (int j = 0; j < nact; j++) {
            int rj = __shfl(rj_own, j);
            int sj = __shfl(sj_own, j);
            float ov = tw[j * 64 + (((lane >> 2) ^ (j & 15)) << 2) + (lane & 3)];
            float hv = hx[(size_t)sj * KF + lane];
            atomicAdd(&zs[(size_t)rj * KF + lane], ov * hv);
        }
    }
}

// ---- output: elec_out = elec + sum_s (z_s[:,16:] @ gW_s + gb_s) ------------
__global__ void out_k(const float* __restrict__ elec, const float* __restrict__ z,
                      const float* __restrict__ g0W, const float* __restrict__ g0b,
                      const float* __restrict__ g1W, const float* __restrict__ g1b,
                      const float* __restrict__ g2W, const float* __restrict__ g2b,
                      float* __restrict__ out)
{
    __shared__ float zr[8][192];
    int row0 = blockIdx.x * 8;            // 512 blocks, 8 elec rows each
    int tid  = threadIdx.x;               // 128 threads
    for (int t = tid; t < 8 * 192; t += 128) {
        int n = t / 192, u = t % 192;
        int s = u >> 6, k = u & 63;
        int row = row0 + n;
        int node = (row >> 6) * NPER + 16 + (row & 63);
        zr[n][u] = z[((size_t)s * NNODES + node) * KF + k];
    }
    __syncthreads();
    int d = tid;
    float gb = g0b[d] + g1b[d] + g2b[d];
    float acc[8];
    #pragma unroll
    for (int n = 0; n < 8; n++) acc[n] = elec[(size_t)(row0 + n) * DF + d] + gb;

    for (int k = 0; k < 64; k++) {
        float w = g0W[k * DF + d];
        #pragma unroll
        for (int n = 0; n < 8; n++) acc[n] = __fmaf_rn(zr[n][k], w, acc[n]);
    }
    for (int k = 0; k < 64; k++) {
        float w = g1W[k * DF + d];
        #pragma unroll
        for (int n = 0; n < 8; n++) acc[n] = __fmaf_rn(zr[n][64 + k], w, acc[n]);
    }
    for (int k = 0; k < 64; k++) {
        float w = g2W[k * DF + d];
        #pragma unroll
        for (int n = 0; n < 8; n++) acc[n] = __fmaf_rn(zr[n][128 + k], w, acc[n]);
    }
    #pragma unroll
    for (int n = 0; n < 8; n++) out[(size_t)(row0 + n) * DF + d] = acc[n];
}

extern "C" void kernel_launch(void* const* d_in, const int* in_sizes, int n_in,
                              void* d_out, int out_size, void* d_ws, size_t ws_size,
                              hipStream_t stream)
{
    const float* nuc  = (const float*)d_in[0];
    const float* elec = (const float*)d_in[1];
    const float* dist = (const float*)d_in[2];
    const float* wsW1 = (const float*)d_in[3];
    const float* wsB1 = (const float*)d_in[4];
    const float* wsW2 = (const float*)d_in[5];
    const float* wsB2 = (const float*)d_in[6];
    const float* gsW  = (const float*)d_in[7];
    const float* gsB  = (const float*)d_in[8];
    const float* waW1 = (const float*)d_in[9];
    const float* waB1 = (const float*)d_in[10];
    const float* waW2 = (const float*)d_in[11];
    const float* waB2 = (const float*)d_in[12];
    const float* gaW  = (const float*)d_in[13];
    const float* gaB  = (const float*)d_in[14];
    const float* wnW1 = (const float*)d_in[15];
    const float* wnB1 = (const float*)d_in[16];
    const float* wnW2 = (const float*)d_in[17];
    const float* wnB2 = (const float*)d_in[18];
    const float* gnW  = (const float*)d_in[19];
    const float* gnB  = (const float*)d_in[20];
    const float* hW   = (const float*)d_in[21];
    const float* hb   = (const float*)d_in[22];
    const int* e_typ    = (const int*)d_in[23];
    const int* senders  = (const int*)d_in[24];
    const int* receivers= (const int*)d_in[25];
    float* out = (float*)d_out;

    char* ws = (char*)d_ws;
    int*   cnt    = (int*)(ws + WS_CNT);
    float* z      = (float*)(ws + WS_Z);
    float* hx     = (float*)(ws + WS_HX);
    int*   elist  = (int*)(ws + WS_EL);
    int*   slist  = (int*)(ws + WS_SL);
    int*   rlist  = (int*)(ws + WS_RL);
    int*   blkcnt = (int*)(ws + WS_BC);
    int*   blkbase= (int*)(ws + WS_BB);

    // zero counters + z in one shot (contiguous)
    hipMemsetAsync(d_ws, 0, WS_Z + Z_BYTES, stream);

    hx_k<<<dim3(NNODES * 64 / 256), dim3(256), 0, stream>>>(nuc, elec, hW, hb, hx);
    count_k<<<dim3(NBLK), dim3(256), 0, stream>>>(e_typ, receivers, blkcnt);
    scan_k<<<dim3(1), dim3(192), 0, stream>>>(blkcnt, blkbase, cnt);
    scatter_k<<<dim3(NBLK), dim3(256), 0, stream>>>(e_typ, senders, receivers,
                                                    blkbase, cnt, elist, slist, rlist);
    edge_k<<<dim3(1024), dim3(256), 0, stream>>>(
        dist, hx, elist, slist, rlist, cnt, z,
        wsW1, wsB1, wsW2, wsB2,    // slot 0: same (et==3)
        waW1, waB1, waW2, waB2,    // slot 1: anti (et==4)
        wnW1, wnB1, wnW2, wnB2);   // slot 2: n    (et==1)
    out_k<<<dim3(512), dim3(128), 0, stream>>>(elec, z, gsW, gsB, gaW, gaB, gnW, gnB, out);
}

// Round 3
// 155.177 us; speedup vs baseline: 4.6342x; 1.0689x over previous
//
#include <hip/hip_runtime.h>
#include <math.h>

// Problem constants (fixed instance)
#define E_EDGES 524288
#define NNODES  5120
#define KF      64
#define DF      128
#define FF      32
#define NPER    80    // nodes per batch (16 nuc + 64 elec)
#define NEBLK   2048  // E_EDGES / 256
#define NBUCK   (3 * NNODES)

// workspace layout (bytes) -- zeroed region first: [cnt][z][bucketCnt][cursor]
#define WS_CNT   0u
#define WS_Z     256u
#define Z_BYTES  (3u*NNODES*KF*4u)                 // 3,932,160
#define WS_BC    (WS_Z + Z_BYTES)                  // bucket counts [3*5120]
#define WS_CUR   (WS_BC + NBUCK*4u)                // cursors       [3*5120]
#define WS_ZEND  (WS_CUR + NBUCK*4u)               // end of memset range
#define WS_HX    WS_ZEND
#define HX_BYTES (NNODES*KF*4u)                    // 1,310,720
#define LIST_CAP (E_EDGES + 256)
#define WS_EL    (WS_HX + HX_BYTES)
#define WS_SL    (WS_EL + LIST_CAP*4u)
#define WS_RL    (WS_SL + LIST_CAP*4u)
#define WS_BB    (WS_RL + LIST_CAP*4u)             // bucket bases [3*5120]

__device__ __forceinline__ float ssp_f(float x) {
    float t  = __expf(-fabsf(x));
    float sp = fmaxf(x, 0.0f) + __logf(1.0f + t);
    return sp - 0.6931471805599453f;
}

__device__ __forceinline__ int slot_of(int t, int r) {
    int slot = (t == 3) ? 0 : (t == 4) ? 1 : (t == 1) ? 2 : -1;
    if ((r % NPER) < 16) slot = -1;   // nuc receivers never read
    return slot;
}

// ---- build hx = concat(nuc, elec @ h_W + h_b) -------------------------------
__global__ void hx_k(const float* __restrict__ nuc, const float* __restrict__ elec,
                     const float* __restrict__ hW, const float* __restrict__ hb,
                     float* __restrict__ hx)
{
    int gw   = (blockIdx.x * blockDim.x + threadIdx.x) >> 6;  // one wave per node
    int lane = threadIdx.x & 63;
    if (gw >= NNODES) return;
    int b = gw / NPER, p = gw % NPER;
    float v;
    if (p < 16) {
        v = nuc[((size_t)b * 16 + p) * KF + lane];
    } else {
        int pe = p - 16;
        const float* er = elec + ((size_t)b * 64 + pe) * DF;
        float acc = hb[lane];
        #pragma unroll 8
        for (int d = 0; d < DF; d++) acc = __fmaf_rn(er[d], hW[d * KF + lane], acc);
        v = acc;
    }
    hx[(size_t)gw * KF + lane] = v;
}

// ---- A: bucket counts per (slot, receiver) ----------------------------------
__global__ void count2_k(const int* __restrict__ et, const int* __restrict__ recv,
                         int* __restrict__ bc)
{
    int e  = blockIdx.x * blockDim.x + threadIdx.x;
    int rv = recv[e];
    int slot = slot_of(et[e], rv);
    if (slot >= 0) atomicAdd(&bc[slot * NNODES + rv], 1);
}

// ---- B: single-block segmented exclusive scan of 15360 bucket counts --------
// 384 threads; thread t handles buckets [t*40, t*40+40); slot s = t/128.
__global__ void scan2_k(const int* __restrict__ bc, int* __restrict__ bb,
                        int* __restrict__ c)
{
    __shared__ int wtot[6];
    __shared__ int slotStart[3];
    int t    = threadIdx.x;
    int lane = t & 63, w = t >> 6;
    int base = t * 40;
    int ssum = 0;
    #pragma unroll
    for (int i = 0; i < 40; i++) ssum += bc[base + i];
    int x = ssum;
    #pragma unroll
    for (int off = 1; off < 64; off <<= 1) {
        int y = __shfl_up(x, off);
        if (lane >= off) x += y;
    }
    if (lane == 63) wtot[w] = x;
    __syncthreads();
    if (t == 0) {
        int t0 = wtot[0] + wtot[1], t1 = wtot[2] + wtot[3], t2 = wtot[4] + wtot[5];
        int a0 = (t0 + 63) & ~63, a1 = (t1 + 63) & ~63, a2 = (t2 + 63) & ~63;
        slotStart[0] = 0; slotStart[1] = a0; slotStart[2] = a0 + a1;
        c[8]  = 0;   c[9]  = a0;       c[10] = a0 + a1;        // aligned starts
        c[12] = t0;  c[13] = a0 + t1;  c[14] = a0 + a1 + t2;   // ends
        c[16] = a0 + a1 + a2;                                  // total padded
    }
    __syncthreads();
    int s = t >> 7;                                  // slot of this thread
    int preWave = (w & 1) ? wtot[w - 1] : 0;         // slot-local wave prefix
    int run = slotStart[s] + (x - ssum) + preWave;   // exclusive prefix
    #pragma unroll
    for (int i = 0; i < 40; i++) { int v = bc[base + i]; bb[base + i] = run; run += v; }
}

// ---- C: counting-sort scatter (per-thread cursor atomics, 15360 addresses) --
__global__ void scatter2_k(const int* __restrict__ et, const int* __restrict__ snd,
                           const int* __restrict__ recv, const int* __restrict__ bb,
                           int* __restrict__ cur,
                           int* __restrict__ elist, int* __restrict__ slist,
                           int* __restrict__ rlist)
{
    int e  = blockIdx.x * blockDim.x + threadIdx.x;
    int rv = recv[e], sv = snd[e];
    int slot = slot_of(et[e], rv);
    if (slot >= 0) {
        int bidx = slot * NNODES + rv;
        int pos = bb[bidx] + atomicAdd(&cur[bidx], 1);
        elist[pos] = e; slist[pos] = sv; rlist[pos] = rv;
    }
}

// ---- main: per-edge MLP + chunked transpose + run-length atomic scatter -----
__global__ __launch_bounds__(256, 5) void edge_k(
    const float* __restrict__ dist, const float* __restrict__ hx,
    const int* __restrict__ elist, const int* __restrict__ slist,
    const int* __restrict__ rlist, const int* __restrict__ cnt,
    float* __restrict__ z,
    const float* __restrict__ w1_0, const float* __restrict__ b1_0,
    const float* __restrict__ w2_0, const float* __restrict__ b2_0,
    const float* __restrict__ w1_1, const float* __restrict__ b1_1,
    const float* __restrict__ w2_1, const float* __restrict__ b2_1,
    const float* __restrict__ w1_2, const float* __restrict__ b1_2,
    const float* __restrict__ w2_2, const float* __restrict__ b2_2)
{
    __shared__ float tb[4 * 16 * 64];    // 16 KiB: 16-edge x 64-k tile per wave
    const int lane = threadIdx.x & 63;
    const int wid  = threadIdx.x >> 6;
    float* tw = &tb[wid * 16 * 64];

    const int start1 = cnt[9], start2 = cnt[10];
    const int end0 = cnt[12], end1 = cnt[13], end2 = cnt[14];
    const int total = cnt[16];
    const int wavestride = gridDim.x * 4 * 64;

    for (int base = (blockIdx.x * 4 + wid) * 64; base < total; base += wavestride) {
        int idx = base + lane;
        int s = (base >= start2) ? 2 : (base >= start1) ? 1 : 0;
        int endS = (s == 0) ? end0 : (s == 1) ? end1 : end2;
        bool act = idx < endS;
        int nact = __popcll(__ballot(act));   // active lanes are 0..nact-1
        if (nact == 0) continue;

        int e = 0, sj_own = 0, rj_own = 0;
        if (act) { e = elist[idx]; sj_own = slist[idx]; rj_own = rlist[idx]; }

        s = __builtin_amdgcn_readfirstlane(s);
        const float *W1, *B1, *W2, *B2;
        if (s == 0)      { W1 = w1_0; B1 = b1_0; W2 = w2_0; B2 = b2_0; }
        else if (s == 1) { W1 = w1_1; B1 = b1_1; W2 = w2_1; B2 = b2_1; }
        else             { W1 = w1_2; B1 = b1_2; W2 = w2_2; B2 = b2_2; }

        // load dist row (32 floats)
        float dv[32];
        {
            const float4* dp = (const float4*)(dist + (size_t)e * FF);
            #pragma unroll
            for (int q = 0; q < 8; q++) {
                float4 v = dp[q];
                dv[q*4+0] = v.x; dv[q*4+1] = v.y; dv[q*4+2] = v.z; dv[q*4+3] = v.w;
            }
        }
        // layer 1: h = ssp(d @ W1 + b1)   (weights wave-uniform -> s_load)
        float h[32];
        #pragma unroll
        for (int j = 0; j < 32; j++) h[j] = B1[j];
        #pragma unroll
        for (int i = 0; i < 32; i++) {
            float di = dv[i];
            #pragma unroll
            for (int j = 0; j < 32; j++) h[j] = __fmaf_rn(di, W1[i*32 + j], h[j]);
        }
        #pragma unroll
        for (int j = 0; j < 32; j++) h[j] = ssp_f(h[j]);

        // layer 2: o = h @ W2 + b2
        float o[64];
        #pragma unroll
        for (int k = 0; k < 64; k++) o[k] = B2[k];
        #pragma unroll
        for (int j = 0; j < 32; j++) {
            float hj = h[j];
            #pragma unroll
            for (int k = 0; k < 64; k++) o[k] = __fmaf_rn(hj, W2[j*64 + k], o[k]);
        }

        // chunked transpose (16 edges at a time) + run-length accumulate scatter.
        // Edges sorted by (slot, receiver) -> equal receivers are consecutive:
        // accumulate in a register, one atomicAdd per distinct receiver.
        float* zs = z + (size_t)s * NNODES * KF;
        float accv = 0.0f;
        int prev_r = -1;
        for (int c = 0; c < 4; c++) {
            int j0 = c * 16;
            if (j0 >= nact) break;
            int j1 = (nact < j0 + 16) ? nact : j0 + 16;
            if ((lane >> 4) == c) {
                int r = lane & 15;
                #pragma unroll
                for (int q = 0; q < 16; q++) {
                    int c4 = q ^ r;
                    *(float4*)&tw[r * 64 + c4 * 4] =
                        make_float4(o[q*4+0], o[q*4+1], o[q*4+2], o[q*4+3]);
                }
            }
            for (int j = j0; j < j1; j++) {
                int rj = __shfl(rj_own, j);
                int sj = __shfl(sj_own, j);
                int r  = j & 15;
                float ov = tw[r * 64 + (((lane >> 2) ^ r) << 2) + (lane & 3)];
                float hv = hx[(size_t)sj * KF + lane];
                if (rj != prev_r) {                      // wave-uniform branch
                    if (prev_r >= 0) atomicAdd(&zs[(size_t)prev_r * KF + lane], accv);
                    accv = 0.0f; prev_r = rj;
                }
                accv = __fmaf_rn(ov, hv, accv);
            }
        }
        if (prev_r >= 0) atomicAdd(&zs[(size_t)prev_r * KF + lane], accv);
    }
}

// ---- output: elec_out = elec + sum_s (z_s[:,16:] @ gW_s + gb_s) ------------
__global__ void out_k(const float* __restrict__ elec, const float* __restrict__ z,
                      const float* __restrict__ g0W, const float* __restrict__ g0b,
                      const float* __restrict__ g1W, const float* __restrict__ g1b,
                      const float* __restrict__ g2W, const float* __restrict__ g2b,
                      float* __restrict__ out)
{
    __shared__ float zr[8][192];
    int row0 = blockIdx.x * 8;            // 512 blocks, 8 elec rows each
    int tid  = threadIdx.x;               // 128 threads
    for (int t = tid; t < 8 * 192; t += 128) {
        int n = t / 192, u = t % 192;
        int s = u >> 6, k = u & 63;
        int row = row0 + n;
        int node = (row >> 6) * NPER + 16 + (row & 63);
        zr[n][u] = z[((size_t)s * NNODES + node) * KF + k];
    }
    __syncthreads();
    int d = tid;
    float gb = g0b[d] + g1b[d] + g2b[d];
    float acc[8];
    #pragma unroll
    for (int n = 0; n < 8; n++) acc[n] = elec[(size_t)(row0 + n) * DF + d] + gb;

    for (int k = 0; k < 64; k++) {
        float w = g0W[k * DF + d];
        #pragma unroll
        for (int n = 0; n < 8; n++) acc[n] = __fmaf_rn(zr[n][k], w, acc[n]);
    }
    for (int k = 0; k < 64; k++) {
        float w = g1W[k * DF + d];
        #pragma unroll
        for (int n = 0; n < 8; n++) acc[n] = __fmaf_rn(zr[n][64 + k], w, acc[n]);
    }
    for (int k = 0; k < 64; k++) {
        float w = g2W[k * DF + d];
        #pragma unroll
        for (int n = 0; n < 8; n++) acc[n] = __fmaf_rn(zr[n][128 + k], w, acc[n]);
    }
    #pragma unroll
    for (int n = 0; n < 8; n++) out[(size_t)(row0 + n) * DF + d] = acc[n];
}

extern "C" void kernel_launch(void* const* d_in, const int* in_sizes, int n_in,
                              void* d_out, int out_size, void* d_ws, size_t ws_size,
                              hipStream_t stream)
{
    const float* nuc  = (const float*)d_in[0];
    const float* elec = (const float*)d_in[1];
    const float* dist = (const float*)d_in[2];
    const float* wsW1 = (const float*)d_in[3];
    const float* wsB1 = (const float*)d_in[4];
    const float* wsW2 = (const float*)d_in[5];
    const float* wsB2 = (const float*)d_in[6];
    const float* gsW  = (const float*)d_in[7];
    const float* gsB  = (const float*)d_in[8];
    const float* waW1 = (const float*)d_in[9];
    const float* waB1 = (const float*)d_in[10];
    const float* waW2 = (const float*)d_in[11];
    const float* waB2 = (const float*)d_in[12];
    const float* gaW  = (const float*)d_in[13];
    const float* gaB  = (const float*)d_in[14];
    const float* wnW1 = (const float*)d_in[15];
    const float* wnB1 = (const float*)d_in[16];
    const float* wnW2 = (const float*)d_in[17];
    const float* wnB2 = (const float*)d_in[18];
    const float* gnW  = (const float*)d_in[19];
    const float* gnB  = (const float*)d_in[20];
    const float* hW   = (const float*)d_in[21];
    const float* hb   = (const float*)d_in[22];
    const int* e_typ    = (const int*)d_in[23];
    const int* senders  = (const int*)d_in[24];
    const int* receivers= (const int*)d_in[25];
    float* out = (float*)d_out;

    char* ws = (char*)d_ws;
    int*   cnt    = (int*)(ws + WS_CNT);
    float* z      = (float*)(ws + WS_Z);
    int*   bc     = (int*)(ws + WS_BC);
    int*   cur    = (int*)(ws + WS_CUR);
    float* hx     = (float*)(ws + WS_HX);
    int*   elist  = (int*)(ws + WS_EL);
    int*   slist  = (int*)(ws + WS_SL);
    int*   rlist  = (int*)(ws + WS_RL);
    int*   bb     = (int*)(ws + WS_BB);

    // zero counters + z + bucket counts + cursors in one contiguous shot
    hipMemsetAsync(d_ws, 0, WS_ZEND, stream);

    hx_k<<<dim3(NNODES * 64 / 256), dim3(256), 0, stream>>>(nuc, elec, hW, hb, hx);
    count2_k<<<dim3(NEBLK), dim3(256), 0, stream>>>(e_typ, receivers, bc);
    scan2_k<<<dim3(1), dim3(384), 0, stream>>>(bc, bb, cnt);
    scatter2_k<<<dim3(NEBLK), dim3(256), 0, stream>>>(e_typ, senders, receivers,
                                                      bb, cur, elist, slist, rlist);
    edge_k<<<dim3(1280), dim3(256), 0, stream>>>(
        dist, hx, elist, slist, rlist, cnt, z,
        wsW1, wsB1, wsW2, wsB2,    // slot 0: same (et==3)
        waW1, waB1, waW2, waB2,    // slot 1: anti (et==4)
        wnW1, wnB1, wnW2, wnB2);   // slot 2: n    (et==1)
    out_k<<<dim3(512), dim3(128), 0, stream>>>(elec, z, gsW, gsB, gaW, gaB, gnW, gnB, out);
}

// Round 4
// 154.271 us; speedup vs baseline: 4.6614x; 1.0059x over previous
//
#include <hip/hip_runtime.h>
#include <math.h>

// Problem constants (fixed instance)
#define E_EDGES 524288
#define NNODES  5120
#define KF      64
#define DF      128
#define FF      32
#define NPER    80    // nodes per batch (16 nuc + 64 elec)
#define NEBLK   2048  // E_EDGES / 256
#define NBUCK   (3 * NNODES)

// workspace layout (bytes) -- zeroed region first: [cnt][z][bucketCnt][cursor]
#define WS_CNT   0u
#define WS_Z     256u
#define Z_BYTES  (3u*NNODES*KF*4u)                 // 3,932,160
#define WS_BC    (WS_Z + Z_BYTES)                  // bucket counts [3*5120]
#define WS_CUR   (WS_BC + NBUCK*4u)                // cursors       [3*5120]
#define WS_ZEND  (WS_CUR + NBUCK*4u)               // end of memset range
#define WS_HX    WS_ZEND
#define HX_BYTES (NNODES*KF*4u)                    // 1,310,720
#define LIST_CAP (E_EDGES + 256)
#define WS_EL    (WS_HX + HX_BYTES)
#define WS_SL    (WS_EL + LIST_CAP*4u)
#define WS_RL    (WS_SL + LIST_CAP*4u)
#define WS_BB    (WS_RL + LIST_CAP*4u)             // bucket bases [3*5120]

__device__ __forceinline__ float ssp_f(float x) {
    float t  = __expf(-fabsf(x));
    float sp = fmaxf(x, 0.0f) + __logf(1.0f + t);
    return sp - 0.6931471805599453f;
}

__device__ __forceinline__ int slot_of(int t, int r) {
    int slot = (t == 3) ? 0 : (t == 4) ? 1 : (t == 1) ? 2 : -1;
    if ((r % NPER) < 16) slot = -1;   // nuc receivers never read
    return slot;
}

// ---- build hx = concat(nuc, elec @ h_W + h_b) -------------------------------
__global__ void hx_k(const float* __restrict__ nuc, const float* __restrict__ elec,
                     const float* __restrict__ hW, const float* __restrict__ hb,
                     float* __restrict__ hx)
{
    int gw   = (blockIdx.x * blockDim.x + threadIdx.x) >> 6;  // one wave per node
    int lane = threadIdx.x & 63;
    if (gw >= NNODES) return;
    int b = gw / NPER, p = gw % NPER;
    float v;
    if (p < 16) {
        v = nuc[((size_t)b * 16 + p) * KF + lane];
    } else {
        int pe = p - 16;
        const float* er = elec + ((size_t)b * 64 + pe) * DF;
        float acc = hb[lane];
        #pragma unroll 8
        for (int d = 0; d < DF; d++) acc = __fmaf_rn(er[d], hW[d * KF + lane], acc);
        v = acc;
    }
    hx[(size_t)gw * KF + lane] = v;
}

// ---- A: bucket counts per (slot, receiver) ----------------------------------
__global__ void count2_k(const int* __restrict__ et, const int* __restrict__ recv,
                         int* __restrict__ bc)
{
    int e  = blockIdx.x * blockDim.x + threadIdx.x;
    int rv = recv[e];
    int slot = slot_of(et[e], rv);
    if (slot >= 0) atomicAdd(&bc[slot * NNODES + rv], 1);
}

// ---- B: single-block segmented exclusive scan of 15360 bucket counts --------
// 384 threads; thread t handles buckets [t*40, t*40+40); slot s = t/128.
__global__ void scan2_k(const int* __restrict__ bc, int* __restrict__ bb,
                        int* __restrict__ c)
{
    __shared__ int wtot[6];
    __shared__ int slotStart[3];
    int t    = threadIdx.x;
    int lane = t & 63, w = t >> 6;
    int base = t * 40;
    int ssum = 0;
    #pragma unroll
    for (int i = 0; i < 40; i++) ssum += bc[base + i];
    int x = ssum;
    #pragma unroll
    for (int off = 1; off < 64; off <<= 1) {
        int y = __shfl_up(x, off);
        if (lane >= off) x += y;
    }
    if (lane == 63) wtot[w] = x;
    __syncthreads();
    if (t == 0) {
        int t0 = wtot[0] + wtot[1], t1 = wtot[2] + wtot[3], t2 = wtot[4] + wtot[5];
        int a0 = (t0 + 63) & ~63, a1 = (t1 + 63) & ~63, a2 = (t2 + 63) & ~63;
        slotStart[0] = 0; slotStart[1] = a0; slotStart[2] = a0 + a1;
        c[8]  = 0;   c[9]  = a0;       c[10] = a0 + a1;        // aligned starts
        c[12] = t0;  c[13] = a0 + t1;  c[14] = a0 + a1 + t2;   // ends
        c[16] = a0 + a1 + a2;                                  // total padded
    }
    __syncthreads();
    int s = t >> 7;                                  // slot of this thread
    int preWave = (w & 1) ? wtot[w - 1] : 0;         // slot-local wave prefix
    int run = slotStart[s] + (x - ssum) + preWave;   // exclusive prefix
    #pragma unroll
    for (int i = 0; i < 40; i++) { int v = bc[base + i]; bb[base + i] = run; run += v; }
}

// ---- C: counting-sort scatter (per-thread cursor atomics, 15360 addresses) --
__global__ void scatter2_k(const int* __restrict__ et, const int* __restrict__ snd,
                           const int* __restrict__ recv, const int* __restrict__ bb,
                           int* __restrict__ cur,
                           int* __restrict__ elist, int* __restrict__ slist,
                           int* __restrict__ rlist)
{
    int e  = blockIdx.x * blockDim.x + threadIdx.x;
    int rv = recv[e], sv = snd[e];
    int slot = slot_of(et[e], rv);
    if (slot >= 0) {
        int bidx = slot * NNODES + rv;
        int pos = bb[bidx] + atomicAdd(&cur[bidx], 1);
        elist[pos] = e; slist[pos] = sv; rlist[pos] = rv;
    }
}

// ---- main: per-edge MLP + chunked transpose + run-length atomic scatter -----
__global__ __launch_bounds__(256, 3) void edge_k(
    const float* __restrict__ dist, const float* __restrict__ hx,
    const int* __restrict__ elist, const int* __restrict__ slist,
    const int* __restrict__ rlist, const int* __restrict__ cnt,
    float* __restrict__ z,
    const float* __restrict__ w1_0, const float* __restrict__ b1_0,
    const float* __restrict__ w2_0, const float* __restrict__ b2_0,
    const float* __restrict__ w1_1, const float* __restrict__ b1_1,
    const float* __restrict__ w2_1, const float* __restrict__ b2_1,
    const float* __restrict__ w1_2, const float* __restrict__ b1_2,
    const float* __restrict__ w2_2, const float* __restrict__ b2_2)
{
    __shared__ float tb[4 * 16 * 64];    // 16 KiB: 16-edge x 64-k tile per wave
    const int lane = threadIdx.x & 63;
    const int wid  = threadIdx.x >> 6;
    float* tw = &tb[wid * 16 * 64];

    const int start1 = cnt[9], start2 = cnt[10];
    const int end0 = cnt[12], end1 = cnt[13], end2 = cnt[14];
    const int total = cnt[16];
    const int wavestride = gridDim.x * 4 * 64;

    for (int base = (blockIdx.x * 4 + wid) * 64; base < total; base += wavestride) {
        int idx = base + lane;
        int s = (base >= start2) ? 2 : (base >= start1) ? 1 : 0;
        int endS = (s == 0) ? end0 : (s == 1) ? end1 : end2;
        bool act = idx < endS;
        int nact = __popcll(__ballot(act));   // active lanes are 0..nact-1
        if (nact == 0) continue;

        int e = 0, sj_own = 0, rj_own = 0;
        if (act) { e = elist[idx]; sj_own = slist[idx]; rj_own = rlist[idx]; }

        s = __builtin_amdgcn_readfirstlane(s);
        const float *W1, *B1, *W2, *B2;
        if (s == 0)      { W1 = w1_0; B1 = b1_0; W2 = w2_0; B2 = b2_0; }
        else if (s == 1) { W1 = w1_1; B1 = b1_1; W2 = w2_1; B2 = b2_1; }
        else             { W1 = w1_2; B1 = b1_2; W2 = w2_2; B2 = b2_2; }

        // load dist row (32 floats)
        float dv[32];
        {
            const float4* dp = (const float4*)(dist + (size_t)e * FF);
            #pragma unroll
            for (int q = 0; q < 8; q++) {
                float4 v = dp[q];
                dv[q*4+0] = v.x; dv[q*4+1] = v.y; dv[q*4+2] = v.z; dv[q*4+3] = v.w;
            }
        }
        // layer 1: h = ssp(d @ W1 + b1)   (weights wave-uniform -> s_load)
        float h[32];
        #pragma unroll
        for (int j = 0; j < 32; j++) h[j] = B1[j];
        #pragma unroll
        for (int i = 0; i < 32; i++) {
            float di = dv[i];
            #pragma unroll
            for (int j = 0; j < 32; j++) h[j] = __fmaf_rn(di, W1[i*32 + j], h[j]);
        }
        #pragma unroll
        for (int j = 0; j < 32; j++) h[j] = ssp_f(h[j]);

        // layer 2: o = h @ W2 + b2
        float o[64];
        #pragma unroll
        for (int k = 0; k < 64; k++) o[k] = B2[k];
        #pragma unroll
        for (int j = 0; j < 32; j++) {
            float hj = h[j];
            #pragma unroll
            for (int k = 0; k < 64; k++) o[k] = __fmaf_rn(hj, W2[j*64 + k], o[k]);
        }

        // chunked transpose (16 edges at a time) + run-length accumulate scatter.
        // Edges sorted by (slot, receiver) -> equal receivers are consecutive:
        // accumulate in a register, one atomicAdd per distinct receiver.
        float* zs = z + (size_t)s * NNODES * KF;
        float accv = 0.0f;
        int prev_r = -1;
        for (int c = 0; c < 4; c++) {
            int j0 = c * 16;
            if (j0 >= nact) break;
            int j1 = (nact < j0 + 16) ? nact : j0 + 16;
            if ((lane >> 4) == c) {
                int r = lane & 15;
                #pragma unroll
                for (int q = 0; q < 16; q++) {
                    int c4 = q ^ r;
                    *(float4*)&tw[r * 64 + c4 * 4] =
                        make_float4(o[q*4+0], o[q*4+1], o[q*4+2], o[q*4+3]);
                }
            }
            for (int j = j0; j < j1; j++) {
                int rj = __shfl(rj_own, j);
                int sj = __shfl(sj_own, j);
                int r  = j & 15;
                float ov = tw[r * 64 + (((lane >> 2) ^ r) << 2) + (lane & 3)];
                float hv = hx[(size_t)sj * KF + lane];
                if (rj != prev_r) {                      // wave-uniform branch
                    if (prev_r >= 0) atomicAdd(&zs[(size_t)prev_r * KF + lane], accv);
                    accv = 0.0f; prev_r = rj;
                }
                accv = __fmaf_rn(ov, hv, accv);
            }
        }
        if (prev_r >= 0) atomicAdd(&zs[(size_t)prev_r * KF + lane], accv);
    }
}

// ---- output: elec_out = elec + sum_s (z_s[:,16:] @ gW_s + gb_s) ------------
__global__ void out_k(const float* __restrict__ elec, const float* __restrict__ z,
                      const float* __restrict__ g0W, const float* __restrict__ g0b,
                      const float* __restrict__ g1W, const float* __restrict__ g1b,
                      const float* __restrict__ g2W, const float* __restrict__ g2b,
                      float* __restrict__ out)
{
    __shared__ float zr[8][192];
    int row0 = blockIdx.x * 8;            // 512 blocks, 8 elec rows each
    int tid  = threadIdx.x;               // 128 threads
    for (int t = tid; t < 8 * 192; t += 128) {
        int n = t / 192, u = t % 192;
        int s = u >> 6, k = u & 63;
        int row = row0 + n;
        int node = (row >> 6) * NPER + 16 + (row & 63);
        zr[n][u] = z[((size_t)s * NNODES + node) * KF + k];
    }
    __syncthreads();
    int d = tid;
    float gb = g0b[d] + g1b[d] + g2b[d];
    float acc[8];
    #pragma unroll
    for (int n = 0; n < 8; n++) acc[n] = elec[(size_t)(row0 + n) * DF + d] + gb;

    for (int k = 0; k < 64; k++) {
        float w = g0W[k * DF + d];
        #pragma unroll
        for (int n = 0; n < 8; n++) acc[n] = __fmaf_rn(zr[n][k], w, acc[n]);
    }
    for (int k = 0; k < 64; k++) {
        float w = g1W[k * DF + d];
        #pragma unroll
        for (int n = 0; n < 8; n++) acc[n] = __fmaf_rn(zr[n][64 + k], w, acc[n]);
    }
    for (int k = 0; k < 64; k++) {
        float w = g2W[k * DF + d];
        #pragma unroll
        for (int n = 0; n < 8; n++) acc[n] = __fmaf_rn(zr[n][128 + k], w, acc[n]);
    }
    #pragma unroll
    for (int n = 0; n < 8; n++) out[(size_t)(row0 + n) * DF + d] = acc[n];
}

extern "C" void kernel_launch(void* const* d_in, const int* in_sizes, int n_in,
                              void* d_out, int out_size, void* d_ws, size_t ws_size,
                              hipStream_t stream)
{
    const float* nuc  = (const float*)d_in[0];
    const float* elec = (const float*)d_in[1];
    const float* dist = (const float*)d_in[2];
    const float* wsW1 = (const float*)d_in[3];
    const float* wsB1 = (const float*)d_in[4];
    const float* wsW2 = (const float*)d_in[5];
    const float* wsB2 = (const float*)d_in[6];
    const float* gsW  = (const float*)d_in[7];
    const float* gsB  = (const float*)d_in[8];
    const float* waW1 = (const float*)d_in[9];
    const float* waB1 = (const float*)d_in[10];
    const float* waW2 = (const float*)d_in[11];
    const float* waB2 = (const float*)d_in[12];
    const float* gaW  = (const float*)d_in[13];
    const float* gaB  = (const float*)d_in[14];
    const float* wnW1 = (const float*)d_in[15];
    const float* wnB1 = (const float*)d_in[16];
    const float* wnW2 = (const float*)d_in[17];
    const float* wnB2 = (const float*)d_in[18];
    const float* gnW  = (const float*)d_in[19];
    const float* gnB  = (const float*)d_in[20];
    const float* hW   = (const float*)d_in[21];
    const float* hb   = (const float*)d_in[22];
    const int* e_typ    = (const int*)d_in[23];
    const int* senders  = (const int*)d_in[24];
    const int* receivers= (const int*)d_in[25];
    float* out = (float*)d_out;

    char* ws = (char*)d_ws;
    int*   cnt    = (int*)(ws + WS_CNT);
    float* z      = (float*)(ws + WS_Z);
    int*   bc     = (int*)(ws + WS_BC);
    int*   cur    = (int*)(ws + WS_CUR);
    float* hx     = (float*)(ws + WS_HX);
    int*   elist  = (int*)(ws + WS_EL);
    int*   slist  = (int*)(ws + WS_SL);
    int*   rlist  = (int*)(ws + WS_RL);
    int*   bb     = (int*)(ws + WS_BB);

    // zero counters + z + bucket counts + cursors in one contiguous shot
    hipMemsetAsync(d_ws, 0, WS_ZEND, stream);

    hx_k<<<dim3(NNODES * 64 / 256), dim3(256), 0, stream>>>(nuc, elec, hW, hb, hx);
    count2_k<<<dim3(NEBLK), dim3(256), 0, stream>>>(e_typ, receivers, bc);
    scan2_k<<<dim3(1), dim3(384), 0, stream>>>(bc, bb, cnt);
    scatter2_k<<<dim3(NEBLK), dim3(256), 0, stream>>>(e_typ, senders, receivers,
                                                      bb, cur, elist, slist, rlist);
    edge_k<<<dim3(1280), dim3(256), 0, stream>>>(
        dist, hx, elist, slist, rlist, cnt, z,
        wsW1, wsB1, wsW2, wsB2,    // slot 0: same (et==3)
        waW1, waB1, waW2, waB2,    // slot 1: anti (et==4)
        wnW1, wnB1, wnW2, wnB2);   // slot 2: n    (et==1)
    out_k<<<dim3(512), dim3(128), 0, stream>>>(elec, z, gsW, gsB, gaW, gaB, gnW, gnB, out);
}

// Round 5
// 132.546 us; speedup vs baseline: 5.4255x; 1.1639x over previous
//
#include <hip/hip_runtime.h>
#include <math.h>

// Problem constants (fixed instance)
#define E_EDGES 524288
#define NNODES  5120
#define KF      64
#define DF      128
#define FF      32
#define NPER    80    // nodes per batch (16 nuc + 64 elec)
#define NEBLK   2048  // E_EDGES / 256
#define NBUCK   (3 * NNODES)
#define HXBLK   1280  // NNODES*64/256

// workspace layout (bytes)
// [cnt 256][bc 60K][cur 60K] <- memset region | z | hx | elist | slist | rlist | bb | wo
#define WS_CNT   0u
#define WS_BC    256u
#define WS_CUR   (WS_BC + NBUCK*4u)
#define WS_SMALL (WS_CUR + NBUCK*4u)               // 123,136 B memset
#define WS_Z     WS_SMALL
#define Z_BYTES  (3u*NNODES*KF*4u)                 // 3,932,160
#define WS_HX    (WS_Z + Z_BYTES)
#define HX_BYTES (NNODES*KF*4u)                    // 1,310,720
#define LIST_CAP (E_EDGES + 256)
#define WS_EL    (WS_HX + HX_BYTES)
#define WS_SL    (WS_EL + LIST_CAP*4u)
#define WS_RL    (WS_SL + LIST_CAP*4u)
#define WS_BB    (WS_RL + LIST_CAP*4u)
#define WS_WO    (WS_BB + NBUCK*4u)                // 11,721,984 (256-aligned)
#define WO_BYTES ((size_t)LIST_CAP * KF * 4u)      // 134,283,264
#define WS_END   ((size_t)WS_WO + WO_BYTES)        // ~146 MB

__device__ __forceinline__ float ssp_f(float x) {
    float t  = __expf(-fabsf(x));
    float sp = fmaxf(x, 0.0f) + __logf(1.0f + t);
    return sp - 0.6931471805599453f;
}

__device__ __forceinline__ int slot_of(int t, int r) {
    int slot = (t == 3) ? 0 : (t == 4) ? 1 : (t == 1) ? 2 : -1;
    if ((r % NPER) < 16) slot = -1;   // nuc receivers never read
    return slot;
}

// ---- fused: hx build (blocks [0,HXBLK)) + bucket counts (rest) --------------
__global__ void prep_k(const float* __restrict__ nuc, const float* __restrict__ elec,
                       const float* __restrict__ hW, const float* __restrict__ hb,
                       float* __restrict__ hx,
                       const int* __restrict__ et, const int* __restrict__ recv,
                       int* __restrict__ bc)
{
    if (blockIdx.x < HXBLK) {
        int gw   = (blockIdx.x * blockDim.x + threadIdx.x) >> 6;  // one wave per node
        int lane = threadIdx.x & 63;
        int b = gw / NPER, p = gw % NPER;
        float v;
        if (p < 16) {
            v = nuc[((size_t)b * 16 + p) * KF + lane];
        } else {
            int pe = p - 16;
            const float* er = elec + ((size_t)b * 64 + pe) * DF;
            float acc = hb[lane];
            #pragma unroll 8
            for (int d = 0; d < DF; d++) acc = __fmaf_rn(er[d], hW[d * KF + lane], acc);
            v = acc;
        }
        hx[(size_t)gw * KF + lane] = v;
    } else {
        int e  = (blockIdx.x - HXBLK) * blockDim.x + threadIdx.x;
        int rv = recv[e];
        int slot = slot_of(et[e], rv);
        if (slot >= 0) atomicAdd(&bc[slot * NNODES + rv], 1);
    }
}

// ---- B: single-block segmented exclusive scan of 15360 bucket counts --------
// 768 threads; thread t handles buckets [t*20, t*20+20); slot s = t>>8.
__global__ void scan2_k(const int* __restrict__ bc, int* __restrict__ bb,
                        int* __restrict__ c)
{
    __shared__ int wtot[12];
    __shared__ int slotStart[3];
    int t    = threadIdx.x;
    int lane = t & 63, w = t >> 6;       // 12 waves
    int s    = t >> 8;                   // 4 waves per slot
    int base = t * 20;
    int ssum = 0;
    #pragma unroll
    for (int i = 0; i < 20; i++) ssum += bc[base + i];
    int x = ssum;
    #pragma unroll
    for (int off = 1; off < 64; off <<= 1) {
        int y = __shfl_up(x, off);
        if (lane >= off) x += y;
    }
    if (lane == 63) wtot[w] = x;
    __syncthreads();
    if (t == 0) {
        int t0 = wtot[0] + wtot[1] + wtot[2]  + wtot[3];
        int t1 = wtot[4] + wtot[5] + wtot[6]  + wtot[7];
        int t2 = wtot[8] + wtot[9] + wtot[10] + wtot[11];
        int a0 = (t0 + 63) & ~63, a1 = (t1 + 63) & ~63, a2 = (t2 + 63) & ~63;
        slotStart[0] = 0; slotStart[1] = a0; slotStart[2] = a0 + a1;
        c[8]  = 0;   c[9]  = a0;       c[10] = a0 + a1;        // aligned starts
        c[12] = t0;  c[13] = a0 + t1;  c[14] = a0 + a1 + t2;   // ends
        c[16] = a0 + a1 + a2;                                  // total padded
    }
    __syncthreads();
    int preWave = 0;
    for (int w2 = s * 4; w2 < w; ++w2) preWave += wtot[w2];
    int run = slotStart[s] + preWave + (x - ssum);   // exclusive prefix
    #pragma unroll
    for (int i = 0; i < 20; i++) { int v = bc[base + i]; bb[base + i] = run; run += v; }
}

// ---- C: counting-sort scatter (per-thread cursor atomics, 15360 addresses) --
__global__ void scatter2_k(const int* __restrict__ et, const int* __restrict__ snd,
                           const int* __restrict__ recv, const int* __restrict__ bb,
                           int* __restrict__ cur,
                           int* __restrict__ elist, int* __restrict__ slist,
                           int* __restrict__ rlist)
{
    int e  = blockIdx.x * blockDim.x + threadIdx.x;
    int rv = recv[e], sv = snd[e];
    int slot = slot_of(et[e], rv);
    if (slot >= 0) {
        int bidx = slot * NNODES + rv;
        int pos = bb[bidx] + atomicAdd(&cur[bidx], 1);
        elist[pos] = e; slist[pos] = sv; rlist[pos] = rv;
    }
}

// ---- split path 1: per-edge MLP -> streamed we rows (no atomics) ------------
__global__ __launch_bounds__(256, 3) void mlp_k(
    const float* __restrict__ dist, const int* __restrict__ elist,
    const int* __restrict__ cnt, float* __restrict__ wo,
    const float* __restrict__ w1_0, const float* __restrict__ b1_0,
    const float* __restrict__ w2_0, const float* __restrict__ b2_0,
    const float* __restrict__ w1_1, const float* __restrict__ b1_1,
    const float* __restrict__ w2_1, const float* __restrict__ b2_1,
    const float* __restrict__ w1_2, const float* __restrict__ b1_2,
    const float* __restrict__ w2_2, const float* __restrict__ b2_2)
{
    __shared__ float tb[4 * 16 * 64];    // 16 KiB: 16-edge x 64-k tile per wave
    const int lane = threadIdx.x & 63;
    const int wid  = threadIdx.x >> 6;
    float* tw = &tb[wid * 16 * 64];

    const int start1 = cnt[9], start2 = cnt[10];
    const int end0 = cnt[12], end1 = cnt[13], end2 = cnt[14];
    const int total = cnt[16];

    int base = (blockIdx.x * 4 + wid) * 64;
    if (base >= total) return;
    int idx = base + lane;
    int s = (base >= start2) ? 2 : (base >= start1) ? 1 : 0;
    int endS = (s == 0) ? end0 : (s == 1) ? end1 : end2;
    bool act = idx < endS;
    int nact = __popcll(__ballot(act));
    if (nact == 0) return;

    int e = act ? elist[idx] : 0;

    s = __builtin_amdgcn_readfirstlane(s);
    const float *W1, *B1, *W2, *B2;
    if (s == 0)      { W1 = w1_0; B1 = b1_0; W2 = w2_0; B2 = b2_0; }
    else if (s == 1) { W1 = w1_1; B1 = b1_1; W2 = w2_1; B2 = b2_1; }
    else             { W1 = w1_2; B1 = b1_2; W2 = w2_2; B2 = b2_2; }

    // load dist row (32 floats)
    float dv[32];
    {
        const float4* dp = (const float4*)(dist + (size_t)e * FF);
        #pragma unroll
        for (int q = 0; q < 8; q++) {
            float4 v = dp[q];
            dv[q*4+0] = v.x; dv[q*4+1] = v.y; dv[q*4+2] = v.z; dv[q*4+3] = v.w;
        }
    }
    // layer 1: h = ssp(d @ W1 + b1)   (weights wave-uniform -> s_load)
    float h[32];
    #pragma unroll
    for (int j = 0; j < 32; j++) h[j] = B1[j];
    #pragma unroll
    for (int i = 0; i < 32; i++) {
        float di = dv[i];
        #pragma unroll
        for (int j = 0; j < 32; j++) h[j] = __fmaf_rn(di, W1[i*32 + j], h[j]);
    }
    #pragma unroll
    for (int j = 0; j < 32; j++) h[j] = ssp_f(h[j]);

    // layer 2: o = h @ W2 + b2
    float o[64];
    #pragma unroll
    for (int k = 0; k < 64; k++) o[k] = B2[k];
    #pragma unroll
    for (int j = 0; j < 32; j++) {
        float hj = h[j];
        #pragma unroll
        for (int k = 0; k < 64; k++) o[k] = __fmaf_rn(hj, W2[j*64 + k], o[k]);
    }

    // 16-edge tile transpose through LDS, then coalesced row stores to wo
    for (int c = 0; c < 4; c++) {
        int j0 = c * 16;
        if (j0 >= nact) break;
        int j1 = (nact < j0 + 16) ? nact : j0 + 16;
        if ((lane >> 4) == c) {
            int r = lane & 15;
            #pragma unroll
            for (int q = 0; q < 16; q++) {
                int c4 = q ^ r;
                *(float4*)&tw[r * 64 + c4 * 4] =
                    make_float4(o[q*4+0], o[q*4+1], o[q*4+2], o[q*4+3]);
            }
        }
        for (int j = j0; j < j1; j++) {
            int r = j & 15;
            float v = tw[r * 64 + (((lane >> 2) ^ r) << 2) + (lane & 3)];
            wo[(size_t)(base + j) * KF + lane] = v;
        }
    }
}

// ---- split path 2: one wave per bucket, streaming sum, plain store ----------
__global__ __launch_bounds__(256, 8) void gather_k(
    const float* __restrict__ wo, const float* __restrict__ hx,
    const int* __restrict__ slist, const int* __restrict__ bc,
    const int* __restrict__ bb, float* __restrict__ z)
{
    int wv   = blockIdx.x * 4 + (threadIdx.x >> 6);   // bucket = s*NNODES+node
    int lane = threadIdx.x & 63;
    int n    = bc[wv];
    int base = bb[wv];
    float acc = 0.0f;
    int i = 0;
    for (; i + 4 <= n; i += 4) {
        int s0 = slist[base+i+0], s1 = slist[base+i+1];
        int s2 = slist[base+i+2], s3 = slist[base+i+3];
        float w0 = wo[(size_t)(base+i+0) * KF + lane];
        float w1 = wo[(size_t)(base+i+1) * KF + lane];
        float w2 = wo[(size_t)(base+i+2) * KF + lane];
        float w3 = wo[(size_t)(base+i+3) * KF + lane];
        float h0 = hx[(size_t)s0 * KF + lane];
        float h1 = hx[(size_t)s1 * KF + lane];
        float h2 = hx[(size_t)s2 * KF + lane];
        float h3 = hx[(size_t)s3 * KF + lane];
        acc = __fmaf_rn(w0, h0, acc); acc = __fmaf_rn(w1, h1, acc);
        acc = __fmaf_rn(w2, h2, acc); acc = __fmaf_rn(w3, h3, acc);
    }
    for (; i < n; ++i) {
        int sj = slist[base+i];
        float w = wo[(size_t)(base+i) * KF + lane];
        float hv = hx[(size_t)sj * KF + lane];
        acc = __fmaf_rn(w, hv, acc);
    }
    z[(size_t)wv * KF + lane] = acc;   // covers all buckets -> no z memset
}

// ---- fallback (small ws): fused MLP + run-length atomic scatter -------------
__global__ __launch_bounds__(256, 3) void edge_k(
    const float* __restrict__ dist, const float* __restrict__ hx,
    const int* __restrict__ elist, const int* __restrict__ slist,
    const int* __restrict__ rlist, const int* __restrict__ cnt,
    float* __restrict__ z,
    const float* __restrict__ w1_0, const float* __restrict__ b1_0,
    const float* __restrict__ w2_0, const float* __restrict__ b2_0,
    const float* __restrict__ w1_1, const float* __restrict__ b1_1,
    const float* __restrict__ w2_1, const float* __restrict__ b2_1,
    const float* __restrict__ w1_2, const float* __restrict__ b1_2,
    const float* __restrict__ w2_2, const float* __restrict__ b2_2)
{
    __shared__ float tb[4 * 16 * 64];
    const int lane = threadIdx.x & 63;
    const int wid  = threadIdx.x >> 6;
    float* tw = &tb[wid * 16 * 64];

    const int start1 = cnt[9], start2 = cnt[10];
    const int end0 = cnt[12], end1 = cnt[13], end2 = cnt[14];
    const int total = cnt[16];
    const int wavestride = gridDim.x * 4 * 64;

    for (int base = (blockIdx.x * 4 + wid) * 64; base < total; base += wavestride) {
        int idx = base + lane;
        int s = (base >= start2) ? 2 : (base >= start1) ? 1 : 0;
        int endS = (s == 0) ? end0 : (s == 1) ? end1 : end2;
        bool act = idx < endS;
        int nact = __popcll(__ballot(act));
        if (nact == 0) continue;

        int e = 0, sj_own = 0, rj_own = 0;
        if (act) { e = elist[idx]; sj_own = slist[idx]; rj_own = rlist[idx]; }

        s = __builtin_amdgcn_readfirstlane(s);
        const float *W1, *B1, *W2, *B2;
        if (s == 0)      { W1 = w1_0; B1 = b1_0; W2 = w2_0; B2 = b2_0; }
        else if (s == 1) { W1 = w1_1; B1 = b1_1; W2 = w2_1; B2 = b2_1; }
        else             { W1 = w1_2; B1 = b1_2; W2 = w2_2; B2 = b2_2; }

        float dv[32];
        {
            const float4* dp = (const float4*)(dist + (size_t)e * FF);
            #pragma unroll
            for (int q = 0; q < 8; q++) {
                float4 v = dp[q];
                dv[q*4+0] = v.x; dv[q*4+1] = v.y; dv[q*4+2] = v.z; dv[q*4+3] = v.w;
            }
        }
        float h[32];
        #pragma unroll
        for (int j = 0; j < 32; j++) h[j] = B1[j];
        #pragma unroll
        for (int i = 0; i < 32; i++) {
            float di = dv[i];
            #pragma unroll
            for (int j = 0; j < 32; j++) h[j] = __fmaf_rn(di, W1[i*32 + j], h[j]);
        }
        #pragma unroll
        for (int j = 0; j < 32; j++) h[j] = ssp_f(h[j]);

        float o[64];
        #pragma unroll
        for (int k = 0; k < 64; k++) o[k] = B2[k];
        #pragma unroll
        for (int j = 0; j < 32; j++) {
            float hj = h[j];
            #pragma unroll
            for (int k = 0; k < 64; k++) o[k] = __fmaf_rn(hj, W2[j*64 + k], o[k]);
        }

        float* zs = z + (size_t)s * NNODES * KF;
        float accv = 0.0f;
        int prev_r = -1;
        for (int c = 0; c < 4; c++) {
            int j0 = c * 16;
            if (j0 >= nact) break;
            int j1 = (nact < j0 + 16) ? nact : j0 + 16;
            if ((lane >> 4) == c) {
                int r = lane & 15;
                #pragma unroll
                for (int q = 0; q < 16; q++) {
                    int c4 = q ^ r;
                    *(float4*)&tw[r * 64 + c4 * 4] =
                        make_float4(o[q*4+0], o[q*4+1], o[q*4+2], o[q*4+3]);
                }
            }
            for (int j = j0; j < j1; j++) {
                int rj = __shfl(rj_own, j);
                int sj = __shfl(sj_own, j);
                int r  = j & 15;
                float ov = tw[r * 64 + (((lane >> 2) ^ r) << 2) + (lane & 3)];
                float hv = hx[(size_t)sj * KF + lane];
                if (rj != prev_r) {
                    if (prev_r >= 0) atomicAdd(&zs[(size_t)prev_r * KF + lane], accv);
                    accv = 0.0f; prev_r = rj;
                }
                accv = __fmaf_rn(ov, hv, accv);
            }
        }
        if (prev_r >= 0) atomicAdd(&zs[(size_t)prev_r * KF + lane], accv);
    }
}

// ---- output: elec_out = elec + sum_s (z_s[:,16:] @ gW_s + gb_s) ------------
__global__ void out_k(const float* __restrict__ elec, const float* __restrict__ z,
                      const float* __restrict__ g0W, const float* __restrict__ g0b,
                      const float* __restrict__ g1W, const float* __restrict__ g1b,
                      const float* __restrict__ g2W, const float* __restrict__ g2b,
                      float* __restrict__ out)
{
    __shared__ float zr[8][192];
    int row0 = blockIdx.x * 8;            // 512 blocks, 8 elec rows each
    int tid  = threadIdx.x;               // 128 threads
    for (int t = tid; t < 8 * 192; t += 128) {
        int n = t / 192, u = t % 192;
        int s = u >> 6, k = u & 63;
        int row = row0 + n;
        int node = (row >> 6) * NPER + 16 + (row & 63);
        zr[n][u] = z[((size_t)s * NNODES + node) * KF + k];
    }
    __syncthreads();
    int d = tid;
    float gb = g0b[d] + g1b[d] + g2b[d];
    float acc[8];
    #pragma unroll
    for (int n = 0; n < 8; n++) acc[n] = elec[(size_t)(row0 + n) * DF + d] + gb;

    for (int k = 0; k < 64; k++) {
        float w = g0W[k * DF + d];
        #pragma unroll
        for (int n = 0; n < 8; n++) acc[n] = __fmaf_rn(zr[n][k], w, acc[n]);
    }
    for (int k = 0; k < 64; k++) {
        float w = g1W[k * DF + d];
        #pragma unroll
        for (int n = 0; n < 8; n++) acc[n] = __fmaf_rn(zr[n][64 + k], w, acc[n]);
    }
    for (int k = 0; k < 64; k++) {
        float w = g2W[k * DF + d];
        #pragma unroll
        for (int n = 0; n < 8; n++) acc[n] = __fmaf_rn(zr[n][128 + k], w, acc[n]);
    }
    #pragma unroll
    for (int n = 0; n < 8; n++) out[(size_t)(row0 + n) * DF + d] = acc[n];
}

extern "C" void kernel_launch(void* const* d_in, const int* in_sizes, int n_in,
                              void* d_out, int out_size, void* d_ws, size_t ws_size,
                              hipStream_t stream)
{
    const float* nuc  = (const float*)d_in[0];
    const float* elec = (const float*)d_in[1];
    const float* dist = (const float*)d_in[2];
    const float* wsW1 = (const float*)d_in[3];
    const float* wsB1 = (const float*)d_in[4];
    const float* wsW2 = (const float*)d_in[5];
    const float* wsB2 = (const float*)d_in[6];
    const float* gsW  = (const float*)d_in[7];
    const float* gsB  = (const float*)d_in[8];
    const float* waW1 = (const float*)d_in[9];
    const float* waB1 = (const float*)d_in[10];
    const float* waW2 = (const float*)d_in[11];
    const float* waB2 = (const float*)d_in[12];
    const float* gaW  = (const float*)d_in[13];
    const float* gaB  = (const float*)d_in[14];
    const float* wnW1 = (const float*)d_in[15];
    const float* wnB1 = (const float*)d_in[16];
    const float* wnW2 = (const float*)d_in[17];
    const float* wnB2 = (const float*)d_in[18];
    const float* gnW  = (const float*)d_in[19];
    const float* gnB  = (const float*)d_in[20];
    const float* hW   = (const float*)d_in[21];
    const float* hb   = (const float*)d_in[22];
    const int* e_typ    = (const int*)d_in[23];
    const int* senders  = (const int*)d_in[24];
    const int* receivers= (const int*)d_in[25];
    float* out = (float*)d_out;

    char* ws = (char*)d_ws;
    int*   cnt    = (int*)(ws + WS_CNT);
    int*   bc     = (int*)(ws + WS_BC);
    int*   cur    = (int*)(ws + WS_CUR);
    float* z      = (float*)(ws + WS_Z);
    float* hx     = (float*)(ws + WS_HX);
    int*   elist  = (int*)(ws + WS_EL);
    int*   slist  = (int*)(ws + WS_SL);
    int*   rlist  = (int*)(ws + WS_RL);
    int*   bb     = (int*)(ws + WS_BB);
    float* wo     = (float*)(ws + WS_WO);

    const bool split = (ws_size >= WS_END);

    // zero cnt + bucket counts + cursors (121 KB)
    hipMemsetAsync(d_ws, 0, WS_SMALL, stream);

    prep_k<<<dim3(HXBLK + NEBLK), dim3(256), 0, stream>>>(nuc, elec, hW, hb, hx,
                                                          e_typ, receivers, bc);
    scan2_k<<<dim3(1), dim3(768), 0, stream>>>(bc, bb, cnt);
    scatter2_k<<<dim3(NEBLK), dim3(256), 0, stream>>>(e_typ, senders, receivers,
                                                      bb, cur, elist, slist, rlist);
    if (split) {
        // covers worst-case padded total (E + 3*63, 64-aligned), device-guarded
        mlp_k<<<dim3(2049), dim3(256), 0, stream>>>(
            dist, elist, cnt, wo,
            wsW1, wsB1, wsW2, wsB2,
            waW1, waB1, waW2, waB2,
            wnW1, wnB1, wnW2, wnB2);
        gather_k<<<dim3(NBUCK / 4), dim3(256), 0, stream>>>(wo, hx, slist, bc, bb, z);
    } else {
        hipMemsetAsync(z, 0, Z_BYTES, stream);
        edge_k<<<dim3(988), dim3(256), 0, stream>>>(
            dist, hx, elist, slist, rlist, cnt, z,
            wsW1, wsB1, wsW2, wsB2,
            waW1, waB1, waW2, waB2,
            wnW1, wnB1, wnW2, wnB2);
    }
    out_k<<<dim3(512), dim3(128), 0, stream>>>(elec, z, gsW, gsB, gaW, gaB, gnW, gnB, out);
}

// Round 6
// 118.605 us; speedup vs baseline: 6.0632x; 1.1175x over previous
//
#include <hip/hip_runtime.h>
#include <math.h>

// Problem constants (fixed instance)
#define E_EDGES 524288
#define NNODES  5120
#define KF      64
#define DF      128
#define FF      32
#define NPER    80    // nodes per batch (16 nuc + 64 elec)
#define NEBLK   2048  // E_EDGES / 256
#define NBUCK   (3 * NNODES)
#define HXBLK   1280  // NNODES*64/256

// workspace layout (bytes)
// [cnt 256][bc 60K][cur 60K] <- memset region | z | hx | elist | slist | rlist | bb | wo
#define WS_CNT   0u
#define WS_BC    256u
#define WS_CUR   (WS_BC + NBUCK*4u)
#define WS_SMALL (WS_CUR + NBUCK*4u)               // 123,136 B memset
#define WS_Z     WS_SMALL
#define Z_BYTES  (3u*NNODES*KF*4u)                 // 3,932,160
#define WS_HX    (WS_Z + Z_BYTES)
#define HX_BYTES (NNODES*KF*4u)                    // 1,310,720
#define LIST_CAP (E_EDGES + 256)
#define WS_EL    (WS_HX + HX_BYTES)
#define WS_SL    (WS_EL + LIST_CAP*4u)
#define WS_RL    (WS_SL + LIST_CAP*4u)
#define WS_BB    (WS_RL + LIST_CAP*4u)
#define WS_WO    (WS_BB + NBUCK*4u)                // 256-aligned
#define WO_BYTES ((size_t)LIST_CAP * KF * 2u)      // bf16: 67,141,632
#define WS_END   ((size_t)WS_WO + WO_BYTES)        // ~79 MB

__device__ __forceinline__ float ssp_f(float x) {
    float t  = __expf(-fabsf(x));
    float sp = fmaxf(x, 0.0f) + __logf(1.0f + t);
    return sp - 0.6931471805599453f;
}

__device__ __forceinline__ unsigned short f2bf(float f) {
    union { float f; unsigned u; } c; c.f = f;
    unsigned r = c.u + 0x7FFFu + ((c.u >> 16) & 1u);   // RNE
    return (unsigned short)(r >> 16);
}
__device__ __forceinline__ float bf2f(unsigned short u) {
    union { unsigned u; float f; } c; c.u = ((unsigned)u) << 16;
    return c.f;
}

__device__ __forceinline__ int slot_of(int t, int r) {
    int slot = (t == 3) ? 0 : (t == 4) ? 1 : (t == 1) ? 2 : -1;
    if ((r % NPER) < 16) slot = -1;   // nuc receivers never read
    return slot;
}

// ---- fused: hx build (blocks [0,HXBLK)) + bucket counts (rest) --------------
__global__ void prep_k(const float* __restrict__ nuc, const float* __restrict__ elec,
                       const float* __restrict__ hW, const float* __restrict__ hb,
                       float* __restrict__ hx,
                       const int* __restrict__ et, const int* __restrict__ recv,
                       int* __restrict__ bc)
{
    if (blockIdx.x < HXBLK) {
        int gw   = (blockIdx.x * blockDim.x + threadIdx.x) >> 6;  // one wave per node
        int lane = threadIdx.x & 63;
        int b = gw / NPER, p = gw % NPER;
        float v;
        if (p < 16) {
            v = nuc[((size_t)b * 16 + p) * KF + lane];
        } else {
            int pe = p - 16;
            const float* er = elec + ((size_t)b * 64 + pe) * DF;
            float acc = hb[lane];
            #pragma unroll 8
            for (int d = 0; d < DF; d++) acc = __fmaf_rn(er[d], hW[d * KF + lane], acc);
            v = acc;
        }
        hx[(size_t)gw * KF + lane] = v;
    } else {
        int e  = (blockIdx.x - HXBLK) * blockDim.x + threadIdx.x;
        int rv = recv[e];
        int slot = slot_of(et[e], rv);
        if (slot >= 0) atomicAdd(&bc[slot * NNODES + rv], 1);
    }
}

// ---- B: single-block segmented exclusive scan of 15360 bucket counts --------
// 768 threads; thread t handles buckets [t*20, t*20+20); slot s = t>>8.
__global__ void scan2_k(const int* __restrict__ bc, int* __restrict__ bb,
                        int* __restrict__ c)
{
    __shared__ int wtot[12];
    __shared__ int slotStart[3];
    int t    = threadIdx.x;
    int lane = t & 63, w = t >> 6;       // 12 waves
    int s    = t >> 8;                   // 4 waves per slot
    int base = t * 20;
    int ssum = 0;
    #pragma unroll
    for (int i = 0; i < 20; i++) ssum += bc[base + i];
    int x = ssum;
    #pragma unroll
    for (int off = 1; off < 64; off <<= 1) {
        int y = __shfl_up(x, off);
        if (lane >= off) x += y;
    }
    if (lane == 63) wtot[w] = x;
    __syncthreads();
    if (t == 0) {
        int t0 = wtot[0] + wtot[1] + wtot[2]  + wtot[3];
        int t1 = wtot[4] + wtot[5] + wtot[6]  + wtot[7];
        int t2 = wtot[8] + wtot[9] + wtot[10] + wtot[11];
        int a0 = (t0 + 63) & ~63, a1 = (t1 + 63) & ~63, a2 = (t2 + 63) & ~63;
        slotStart[0] = 0; slotStart[1] = a0; slotStart[2] = a0 + a1;
        c[8]  = 0;   c[9]  = a0;       c[10] = a0 + a1;        // aligned starts
        c[12] = t0;  c[13] = a0 + t1;  c[14] = a0 + a1 + t2;   // ends
        c[16] = a0 + a1 + a2;                                  // total padded
    }
    __syncthreads();
    int preWave = 0;
    for (int w2 = s * 4; w2 < w; ++w2) preWave += wtot[w2];
    int run = slotStart[s] + preWave + (x - ssum);   // exclusive prefix
    #pragma unroll
    for (int i = 0; i < 20; i++) { int v = bc[base + i]; bb[base + i] = run; run += v; }
}

// ---- C: counting-sort scatter (per-thread cursor atomics, 15360 addresses) --
__global__ void scatter2_k(const int* __restrict__ et, const int* __restrict__ snd,
                           const int* __restrict__ recv, const int* __restrict__ bb,
                           int* __restrict__ cur,
                           int* __restrict__ elist, int* __restrict__ slist,
                           int* __restrict__ rlist)
{
    int e  = blockIdx.x * blockDim.x + threadIdx.x;
    int rv = recv[e], sv = snd[e];
    int slot = slot_of(et[e], rv);
    if (slot >= 0) {
        int bidx = slot * NNODES + rv;
        int pos = bb[bidx] + atomicAdd(&cur[bidx], 1);
        elist[pos] = e; slist[pos] = sv; rlist[pos] = rv;
    }
}

// ---- split path 1: per-edge MLP -> streamed bf16 we rows (no atomics) -------
// Layer-2 computed in two 32-wide halves to cap register pressure (~90 live).
__global__ __launch_bounds__(256, 4) void mlp_k(
    const float* __restrict__ dist, const int* __restrict__ elist,
    const int* __restrict__ cnt, unsigned short* __restrict__ wo,
    const float* __restrict__ w1_0, const float* __restrict__ b1_0,
    const float* __restrict__ w2_0, const float* __restrict__ b2_0,
    const float* __restrict__ w1_1, const float* __restrict__ b1_1,
    const float* __restrict__ w2_1, const float* __restrict__ b2_1,
    const float* __restrict__ w1_2, const float* __restrict__ b1_2,
    const float* __restrict__ w2_2, const float* __restrict__ b2_2)
{
    __shared__ float tb[4 * 64 * 32];    // 32 KiB: per-wave 64-edge x 32-k tile
    const int lane = threadIdx.x & 63;
    const int wid  = threadIdx.x >> 6;
    float* tw = &tb[wid * 64 * 32];

    const int start1 = cnt[9], start2 = cnt[10];
    const int end0 = cnt[12], end1 = cnt[13], end2 = cnt[14];
    const int total = cnt[16];

    int base = (blockIdx.x * 4 + wid) * 64;
    if (base >= total) return;
    int idx = base + lane;
    int s = (base >= start2) ? 2 : (base >= start1) ? 1 : 0;
    int endS = (s == 0) ? end0 : (s == 1) ? end1 : end2;
    bool act = idx < endS;
    if (!act && lane == 0) return;        // never happens (base < endS if wave live)
    int e = act ? elist[idx] : 0;

    s = __builtin_amdgcn_readfirstlane(s);
    const float *W1, *B1, *W2, *B2;
    if (s == 0)      { W1 = w1_0; B1 = b1_0; W2 = w2_0; B2 = b2_0; }
    else if (s == 1) { W1 = w1_1; B1 = b1_1; W2 = w2_1; B2 = b2_1; }
    else             { W1 = w1_2; B1 = b1_2; W2 = w2_2; B2 = b2_2; }

    // load dist row (32 floats)
    float dv[32];
    {
        const float4* dp = (const float4*)(dist + (size_t)e * FF);
        #pragma unroll
        for (int q = 0; q < 8; q++) {
            float4 v = dp[q];
            dv[q*4+0] = v.x; dv[q*4+1] = v.y; dv[q*4+2] = v.z; dv[q*4+3] = v.w;
        }
    }
    // layer 1: h = ssp(d @ W1 + b1)   (weights wave-uniform -> s_load operands)
    float h[32];
    #pragma unroll
    for (int j = 0; j < 32; j++) h[j] = B1[j];
    #pragma unroll
    for (int i = 0; i < 32; i++) {
        float di = dv[i];
        #pragma unroll
        for (int j = 0; j < 32; j++) h[j] = __fmaf_rn(di, W1[i*32 + j], h[j]);
    }
    #pragma unroll
    for (int j = 0; j < 32; j++) h[j] = ssp_f(h[j]);

    // layer 2 in two 32-wide halves; each half: transpose via LDS, bf16 store
    #pragma unroll 1
    for (int hf = 0; hf < 2; hf++) {
        const float* W2h = W2 + hf * 32;
        const float* B2h = B2 + hf * 32;
        float o[32];
        #pragma unroll
        for (int k = 0; k < 32; k++) o[k] = B2h[k];
        #pragma unroll
        for (int j = 0; j < 32; j++) {
            float hj = h[j];
            #pragma unroll
            for (int k = 0; k < 32; k++) o[k] = __fmaf_rn(hj, W2h[j*64 + k], o[k]);
        }
        // write own row (64 rows x 32 f32), quad-XOR swizzle: phys p = q ^ (row&7)
        #pragma unroll
        for (int q = 0; q < 8; q++) {
            int p = q ^ (lane & 7);
            *(float4*)&tw[lane * 32 + (p << 2)] =
                make_float4(o[q*4+0], o[q*4+1], o[q*4+2], o[q*4+3]);
        }
        // read 8 rows/instr: lane -> row j = jj*8 + (lane>>3), logical quad m=lane&7
        int m  = lane & 7;
        #pragma unroll
        for (int jj = 0; jj < 8; jj++) {
            int j = jj * 8 + (lane >> 3);
            float4 v = *(float4*)&tw[j * 32 + ((m ^ (j & 7)) << 2)];
            ushort4 us;
            us.x = f2bf(v.x); us.y = f2bf(v.y); us.z = f2bf(v.z); us.w = f2bf(v.w);
            *(ushort4*)&wo[(size_t)(base + j) * KF + hf * 32 + (m << 2)] = us;
        }
    }
}

// ---- split path 2: one wave per bucket, streaming sum, plain store ----------
__global__ __launch_bounds__(256, 8) void gather_k(
    const unsigned short* __restrict__ wo, const float* __restrict__ hx,
    const int* __restrict__ slist, const int* __restrict__ bc,
    const int* __restrict__ bb, float* __restrict__ z)
{
    int wv   = blockIdx.x * 4 + (threadIdx.x >> 6);   // bucket = s*NNODES+node
    int lane = threadIdx.x & 63;
    int n    = bc[wv];
    int base = bb[wv];
    float acc = 0.0f;
    int i = 0;
    for (; i + 4 <= n; i += 4) {
        int s0 = slist[base+i+0], s1 = slist[base+i+1];
        int s2 = slist[base+i+2], s3 = slist[base+i+3];
        float w0 = bf2f(wo[(size_t)(base+i+0) * KF + lane]);
        float w1 = bf2f(wo[(size_t)(base+i+1) * KF + lane]);
        float w2 = bf2f(wo[(size_t)(base+i+2) * KF + lane]);
        float w3 = bf2f(wo[(size_t)(base+i+3) * KF + lane]);
        float h0 = hx[(size_t)s0 * KF + lane];
        float h1 = hx[(size_t)s1 * KF + lane];
        float h2 = hx[(size_t)s2 * KF + lane];
        float h3 = hx[(size_t)s3 * KF + lane];
        acc = __fmaf_rn(w0, h0, acc); acc = __fmaf_rn(w1, h1, acc);
        acc = __fmaf_rn(w2, h2, acc); acc = __fmaf_rn(w3, h3, acc);
    }
    for (; i < n; ++i) {
        int sj = slist[base+i];
        float w = bf2f(wo[(size_t)(base+i) * KF + lane]);
        float hv = hx[(size_t)sj * KF + lane];
        acc = __fmaf_rn(w, hv, acc);
    }
    z[(size_t)wv * KF + lane] = acc;   // covers all buckets -> no z memset
}

// ---- fallback (small ws): fused MLP + run-length atomic scatter -------------
__global__ __launch_bounds__(256, 3) void edge_k(
    const float* __restrict__ dist, const float* __restrict__ hx,
    const int* __restrict__ elist, const int* __restrict__ slist,
    const int* __restrict__ rlist, const int* __restrict__ cnt,
    float* __restrict__ z,
    const float* __restrict__ w1_0, const float* __restrict__ b1_0,
    const float* __restrict__ w2_0, const float* __restrict__ b2_0,
    const float* __restrict__ w1_1, const float* __restrict__ b1_1,
    const float* __restrict__ w2_1, const float* __restrict__ b2_1,
    const float* __restrict__ w1_2, const float* __restrict__ b1_2,
    const float* __restrict__ w2_2, const float* __restrict__ b2_2)
{
    __shared__ float tb[4 * 16 * 64];
    const int lane = threadIdx.x & 63;
    const int wid  = threadIdx.x >> 6;
    float* tw = &tb[wid * 16 * 64];

    const int start1 = cnt[9], start2 = cnt[10];
    const int end0 = cnt[12], end1 = cnt[13], end2 = cnt[14];
    const int total = cnt[16];
    const int wavestride = gridDim.x * 4 * 64;

    for (int base = (blockIdx.x * 4 + wid) * 64; base < total; base += wavestride) {
        int idx = base + lane;
        int s = (base >= start2) ? 2 : (base >= start1) ? 1 : 0;
        int endS = (s == 0) ? end0 : (s == 1) ? end1 : end2;
        bool act = idx < endS;
        int nact = __popcll(__ballot(act));
        if (nact == 0) continue;

        int e = 0, sj_own = 0, rj_own = 0;
        if (act) { e = elist[idx]; sj_own = slist[idx]; rj_own = rlist[idx]; }

        s = __builtin_amdgcn_readfirstlane(s);
        const float *W1, *B1, *W2, *B2;
        if (s == 0)      { W1 = w1_0; B1 = b1_0; W2 = w2_0; B2 = b2_0; }
        else if (s == 1) { W1 = w1_1; B1 = b1_1; W2 = w2_1; B2 = b2_1; }
        else             { W1 = w1_2; B1 = b1_2; W2 = w2_2; B2 = b2_2; }

        float dv[32];
        {
            const float4* dp = (const float4*)(dist + (size_t)e * FF);
            #pragma unroll
            for (int q = 0; q < 8; q++) {
                float4 v = dp[q];
                dv[q*4+0] = v.x; dv[q*4+1] = v.y; dv[q*4+2] = v.z; dv[q*4+3] = v.w;
            }
        }
        float h[32];
        #pragma unroll
        for (int j = 0; j < 32; j++) h[j] = B1[j];
        #pragma unroll
        for (int i = 0; i < 32; i++) {
            float di = dv[i];
            #pragma unroll
            for (int j = 0; j < 32; j++) h[j] = __fmaf_rn(di, W1[i*32 + j], h[j]);
        }
        #pragma unroll
        for (int j = 0; j < 32; j++) h[j] = ssp_f(h[j]);

        float o[64];
        #pragma unroll
        for (int k = 0; k < 64; k++) o[k] = B2[k];
        #pragma unroll
        for (int j = 0; j < 32; j++) {
            float hj = h[j];
            #pragma unroll
            for (int k = 0; k < 64; k++) o[k] = __fmaf_rn(hj, W2[j*64 + k], o[k]);
        }

        float* zs = z + (size_t)s * NNODES * KF;
        float accv = 0.0f;
        int prev_r = -1;
        for (int c = 0; c < 4; c++) {
            int j0 = c * 16;
            if (j0 >= nact) break;
            int j1 = (nact < j0 + 16) ? nact : j0 + 16;
            if ((lane >> 4) == c) {
                int r = lane & 15;
                #pragma unroll
                for (int q = 0; q < 16; q++) {
                    int c4 = q ^ r;
                    *(float4*)&tw[r * 64 + c4 * 4] =
                        make_float4(o[q*4+0], o[q*4+1], o[q*4+2], o[q*4+3]);
                }
            }
            for (int j = j0; j < j1; j++) {
                int rj = __shfl(rj_own, j);
                int sj = __shfl(sj_own, j);
                int r  = j & 15;
                float ov = tw[r * 64 + (((lane >> 2) ^ r) << 2) + (lane & 3)];
                float hv = hx[(size_t)sj * KF + lane];
                if (rj != prev_r) {
                    if (prev_r >= 0) atomicAdd(&zs[(size_t)prev_r * KF + lane], accv);
                    accv = 0.0f; prev_r = rj;
                }
                accv = __fmaf_rn(ov, hv, accv);
            }
        }
        if (prev_r >= 0) atomicAdd(&zs[(size_t)prev_r * KF + lane], accv);
    }
}

// ---- output: elec_out = elec + sum_s (z_s[:,16:] @ gW_s + gb_s) ------------
__global__ void out_k(const float* __restrict__ elec, const float* __restrict__ z,
                      const float* __restrict__ g0W, const float* __restrict__ g0b,
                      const float* __restrict__ g1W, const float* __restrict__ g1b,
                      const float* __restrict__ g2W, const float* __restrict__ g2b,
                      float* __restrict__ out)
{
    __shared__ float zr[8][192];
    int row0 = blockIdx.x * 8;            // 512 blocks, 8 elec rows each
    int tid  = threadIdx.x;               // 128 threads
    for (int t = tid; t < 8 * 192; t += 128) {
        int n = t / 192, u = t % 192;
        int s = u >> 6, k = u & 63;
        int row = row0 + n;
        int node = (row >> 6) * NPER + 16 + (row & 63);
        zr[n][u] = z[((size_t)s * NNODES + node) * KF + k];
    }
    __syncthreads();
    int d = tid;
    float gb = g0b[d] + g1b[d] + g2b[d];
    float acc[8];
    #pragma unroll
    for (int n = 0; n < 8; n++) acc[n] = elec[(size_t)(row0 + n) * DF + d] + gb;

    for (int k = 0; k < 64; k++) {
        float w = g0W[k * DF + d];
        #pragma unroll
        for (int n = 0; n < 8; n++) acc[n] = __fmaf_rn(zr[n][k], w, acc[n]);
    }
    for (int k = 0; k < 64; k++) {
        float w = g1W[k * DF + d];
        #pragma unroll
        for (int n = 0; n < 8; n++) acc[n] = __fmaf_rn(zr[n][64 + k], w, acc[n]);
    }
    for (int k = 0; k < 64; k++) {
        float w = g2W[k * DF + d];
        #pragma unroll
        for (int n = 0; n < 8; n++) acc[n] = __fmaf_rn(zr[n][128 + k], w, acc[n]);
    }
    #pragma unroll
    for (int n = 0; n < 8; n++) out[(size_t)(row0 + n) * DF + d] = acc[n];
}

extern "C" void kernel_launch(void* const* d_in, const int* in_sizes, int n_in,
                              void* d_out, int out_size, void* d_ws, size_t ws_size,
                              hipStream_t stream)
{
    const float* nuc  = (const float*)d_in[0];
    const float* elec = (const float*)d_in[1];
    const float* dist = (const float*)d_in[2];
    const float* wsW1 = (const float*)d_in[3];
    const float* wsB1 = (const float*)d_in[4];
    const float* wsW2 = (const float*)d_in[5];
    const float* wsB2 = (const float*)d_in[6];
    const float* gsW  = (const float*)d_in[7];
    const float* gsB  = (const float*)d_in[8];
    const float* waW1 = (const float*)d_in[9];
    const float* waB1 = (const float*)d_in[10];
    const float* waW2 = (const float*)d_in[11];
    const float* waB2 = (const float*)d_in[12];
    const float* gaW  = (const float*)d_in[13];
    const float* gaB  = (const float*)d_in[14];
    const float* wnW1 = (const float*)d_in[15];
    const float* wnB1 = (const float*)d_in[16];
    const float* wnW2 = (const float*)d_in[17];
    const float* wnB2 = (const float*)d_in[18];
    const float* gnW  = (const float*)d_in[19];
    const float* gnB  = (const float*)d_in[20];
    const float* hW   = (const float*)d_in[21];
    const float* hb   = (const float*)d_in[22];
    const int* e_typ    = (const int*)d_in[23];
    const int* senders  = (const int*)d_in[24];
    const int* receivers= (const int*)d_in[25];
    float* out = (float*)d_out;

    char* ws = (char*)d_ws;
    int*   cnt    = (int*)(ws + WS_CNT);
    int*   bc     = (int*)(ws + WS_BC);
    int*   cur    = (int*)(ws + WS_CUR);
    float* z      = (float*)(ws + WS_Z);
    float* hx     = (float*)(ws + WS_HX);
    int*   elist  = (int*)(ws + WS_EL);
    int*   slist  = (int*)(ws + WS_SL);
    int*   rlist  = (int*)(ws + WS_RL);
    int*   bb     = (int*)(ws + WS_BB);
    unsigned short* wo = (unsigned short*)(ws + WS_WO);

    const bool split = (ws_size >= WS_END);

    // zero cnt + bucket counts + cursors (121 KB)
    hipMemsetAsync(d_ws, 0, WS_SMALL, stream);

    prep_k<<<dim3(HXBLK + NEBLK), dim3(256), 0, stream>>>(nuc, elec, hW, hb, hx,
                                                          e_typ, receivers, bc);
    scan2_k<<<dim3(1), dim3(768), 0, stream>>>(bc, bb, cnt);
    scatter2_k<<<dim3(NEBLK), dim3(256), 0, stream>>>(e_typ, senders, receivers,
                                                      bb, cur, elist, slist, rlist);
    if (split) {
        // covers worst-case padded total (E + 3*63, 64-aligned), device-guarded
        mlp_k<<<dim3(2049), dim3(256), 0, stream>>>(
            dist, elist, cnt, wo,
            wsW1, wsB1, wsW2, wsB2,
            waW1, waB1, waW2, waB2,
            wnW1, wnB1, wnW2, wnB2);
        gather_k<<<dim3(NBUCK / 4), dim3(256), 0, stream>>>(wo, hx, slist, bc, bb, z);
    } else {
        hipMemsetAsync(z, 0, Z_BYTES, stream);
        edge_k<<<dim3(988), dim3(256), 0, stream>>>(
            dist, hx, elist, slist, rlist, cnt, z,
            wsW1, wsB1, wsW2, wsB2,
            waW1, waB1, waW2, waB2,
            wnW1, wnB1, wnW2, wnB2);
    }
    out_k<<<dim3(512), dim3(128), 0, stream>>>(elec, z, gsW, gsB, gaW, gaB, gnW, gnB, out);
}

// Round 7
// 109.780 us; speedup vs baseline: 6.5506x; 1.0804x over previous
//
#include <hip/hip_runtime.h>
#include <math.h>

// Problem constants (fixed instance)
#define E_EDGES 524288
#define NNODES  5120
#define KF      64
#define DF      128
#define FF      32
#define NPER    80    // nodes per batch (16 nuc + 64 elec)
#define NEBLK   2048  // E_EDGES / 256
#define NBUCK   (3 * NNODES)
#define HXBLK   1280  // NNODES*64/256

// workspace layout (bytes)
#define WS_CNT   0u
#define WS_BC    256u
#define WS_CUR   (WS_BC + NBUCK*4u)
#define WS_SMALL (WS_CUR + NBUCK*4u)               // 123,136 B memset
#define WS_Z     WS_SMALL
#define Z_BYTES  (3u*NNODES*KF*4u)                 // 3,932,160
#define WS_HX    (WS_Z + Z_BYTES)
#define HX_BYTES (NNODES*KF*4u)                    // 1,310,720
#define LIST_CAP (E_EDGES + 256)
#define WS_EL    (WS_HX + HX_BYTES)
#define WS_SL    (WS_EL + LIST_CAP*4u)
#define WS_RL    (WS_SL + LIST_CAP*4u)
#define WS_BB    (WS_RL + LIST_CAP*4u)
#define WS_WO    (WS_BB + NBUCK*4u)                // 256-aligned
#define WO_BYTES ((size_t)LIST_CAP * KF * 2u)      // bf16: 67,141,632
#define WS_END   ((size_t)WS_WO + WO_BYTES)        // ~79 MB

typedef __attribute__((ext_vector_type(8))) short bf8_t;   // 8 bf16 (4 VGPRs)
typedef __attribute__((ext_vector_type(4))) float f4_t;    // MFMA 16x16 C/D

union U8 { bf8_t v; unsigned short u[8]; };

__device__ __forceinline__ float ssp_f(float x) {
    float t  = __expf(-fabsf(x));
    float sp = fmaxf(x, 0.0f) + __logf(1.0f + t);
    return sp - 0.6931471805599453f;
}

__device__ __forceinline__ unsigned short f2bf(float f) {
    union { float f; unsigned u; } c; c.f = f;
    unsigned r = c.u + 0x7FFFu + ((c.u >> 16) & 1u);   // RNE
    return (unsigned short)(r >> 16);
}
__device__ __forceinline__ float bf2f(unsigned short u) {
    union { unsigned u; float f; } c; c.u = ((unsigned)u) << 16;
    return c.f;
}

__device__ __forceinline__ int slot_of(int t, int r) {
    int slot = (t == 3) ? 0 : (t == 4) ? 1 : (t == 1) ? 2 : -1;
    if ((r % NPER) < 16) slot = -1;   // nuc receivers never read
    return slot;
}

// ---- fused: hx build (blocks [0,HXBLK)) + bucket counts (rest) --------------
__global__ void prep_k(const float* __restrict__ nuc, const float* __restrict__ elec,
                       const float* __restrict__ hW, const float* __restrict__ hb,
                       float* __restrict__ hx,
                       const int* __restrict__ et, const int* __restrict__ recv,
                       int* __restrict__ bc)
{
    if (blockIdx.x < HXBLK) {
        int gw   = (blockIdx.x * blockDim.x + threadIdx.x) >> 6;  // one wave per node
        int lane = threadIdx.x & 63;
        int b = gw / NPER, p = gw % NPER;
        float v;
        if (p < 16) {
            v = nuc[((size_t)b * 16 + p) * KF + lane];
        } else {
            int pe = p - 16;
            const float* er = elec + ((size_t)b * 64 + pe) * DF;
            float acc = hb[lane];
            #pragma unroll 8
            for (int d = 0; d < DF; d++) acc = __fmaf_rn(er[d], hW[d * KF + lane], acc);
            v = acc;
        }
        hx[(size_t)gw * KF + lane] = v;
    } else {
        int e  = (blockIdx.x - HXBLK) * blockDim.x + threadIdx.x;
        int rv = recv[e];
        int slot = slot_of(et[e], rv);
        if (slot >= 0) atomicAdd(&bc[slot * NNODES + rv], 1);
    }
}

// ---- B: single-block segmented exclusive scan of 15360 bucket counts --------
__global__ void scan2_k(const int* __restrict__ bc, int* __restrict__ bb,
                        int* __restrict__ c)
{
    __shared__ int wtot[12];
    __shared__ int slotStart[3];
    int t    = threadIdx.x;
    int lane = t & 63, w = t >> 6;       // 12 waves
    int s    = t >> 8;                   // 4 waves per slot
    int base = t * 20;
    int ssum = 0;
    #pragma unroll
    for (int i = 0; i < 20; i++) ssum += bc[base + i];
    int x = ssum;
    #pragma unroll
    for (int off = 1; off < 64; off <<= 1) {
        int y = __shfl_up(x, off);
        if (lane >= off) x += y;
    }
    if (lane == 63) wtot[w] = x;
    __syncthreads();
    if (t == 0) {
        int t0 = wtot[0] + wtot[1] + wtot[2]  + wtot[3];
        int t1 = wtot[4] + wtot[5] + wtot[6]  + wtot[7];
        int t2 = wtot[8] + wtot[9] + wtot[10] + wtot[11];
        int a0 = (t0 + 63) & ~63, a1 = (t1 + 63) & ~63, a2 = (t2 + 63) & ~63;
        slotStart[0] = 0; slotStart[1] = a0; slotStart[2] = a0 + a1;
        c[8]  = 0;   c[9]  = a0;       c[10] = a0 + a1;        // aligned starts
        c[12] = t0;  c[13] = a0 + t1;  c[14] = a0 + a1 + t2;   // ends
        c[16] = a0 + a1 + a2;                                  // total padded
    }
    __syncthreads();
    int preWave = 0;
    for (int w2 = s * 4; w2 < w; ++w2) preWave += wtot[w2];
    int run = slotStart[s] + preWave + (x - ssum);   // exclusive prefix
    #pragma unroll
    for (int i = 0; i < 20; i++) { int v = bc[base + i]; bb[base + i] = run; run += v; }
}

// ---- C: counting-sort scatter (per-thread cursor atomics, 15360 addresses) --
__global__ void scatter2_k(const int* __restrict__ et, const int* __restrict__ snd,
                           const int* __restrict__ recv, const int* __restrict__ bb,
                           int* __restrict__ cur,
                           int* __restrict__ elist, int* __restrict__ slist,
                           int* __restrict__ rlist)
{
    int e  = blockIdx.x * blockDim.x + threadIdx.x;
    int rv = recv[e], sv = snd[e];
    int slot = slot_of(et[e], rv);
    if (slot >= 0) {
        int bidx = slot * NNODES + rv;
        int pos = bb[bidx] + atomicAdd(&cur[bidx], 1);
        elist[pos] = e; slist[pos] = sv; rlist[pos] = rv;
    }
}

// ---- split path 1: MFMA MLP -> streamed bf16 we rows ------------------------
// Per 64-edge chunk: layer1 = [64x32]@[32x32] (8 mfma), layer2 = [64x32]@[32x64]
// (16 mfma, two 32-col halves). W frags pre-packed in LDS per block; h and
// output bounce through a per-wave 4 KiB XOR-swizzled LDS tile.
__global__ __launch_bounds__(256, 4) void mlp_k(
    const float* __restrict__ dist, const int* __restrict__ elist,
    const int* __restrict__ cnt, unsigned short* __restrict__ wo,
    const float* __restrict__ w1_0, const float* __restrict__ b1_0,
    const float* __restrict__ w2_0, const float* __restrict__ b2_0,
    const float* __restrict__ w1_1, const float* __restrict__ b1_1,
    const float* __restrict__ w2_1, const float* __restrict__ b2_1,
    const float* __restrict__ w1_2, const float* __restrict__ b1_2,
    const float* __restrict__ w2_2, const float* __restrict__ b2_2)
{
    __shared__ unsigned short wlds[18 * 512];   // 18 KiB: 18 pre-packed B frags
    __shared__ unsigned short hlds[4 * 2048];   // 16 KiB: per-wave 64x32 bf16 tile
    const int lane = threadIdx.x & 63;
    const int wid  = threadIdx.x >> 6;
    const int l15  = lane & 15, l4 = lane >> 4;

    // ---- prestage W fragments (once per block) ----
    {
        const float* W1s[3] = {w1_0, w1_1, w1_2};
        const float* W2s[3] = {w2_0, w2_1, w2_2};
        for (int f = wid; f < 18; f += 4) {
            int sg = f / 6, q = f % 6;
            const float* src = (q < 2) ? W1s[sg] : W2s[sg];
            int stride = (q < 2) ? 32 : 64;
            int cbase  = (q < 2) ? q * 16 : (q - 2) * 16;
            U8 pk;
            #pragma unroll
            for (int j = 0; j < 8; j++)
                pk.u[j] = f2bf(src[(l4 * 8 + j) * stride + cbase + l15]);
            *(bf8_t*)&wlds[f * 512 + lane * 8] = pk.v;
        }
    }
    __syncthreads();

    unsigned short* hs = &hlds[wid * 2048];

    const int start1 = cnt[9], start2 = cnt[10];
    const int end0 = cnt[12], end1 = cnt[13], end2 = cnt[14];
    const int total = cnt[16];

    for (int base = (blockIdx.x * 4 + wid) * 64; base < total; base += gridDim.x * 256) {
        int s = (base >= start2) ? 2 : (base >= start1) ? 1 : 0;
        int endS = (s == 0) ? end0 : (s == 1) ? end1 : end2;
        s = __builtin_amdgcn_readfirstlane(s);
        const float* B1 = (s == 0) ? b1_0 : (s == 1) ? b1_1 : b1_2;
        const float* B2 = (s == 0) ? b2_0 : (s == 1) ? b2_1 : b2_2;

        // layer1 A-frags straight from dist (lane row=l15, k-slice l4*8)
        bf8_t a1[4];
        #pragma unroll
        for (int m = 0; m < 4; m++) {
            int gi = base + m * 16 + l15;
            int e  = (gi < endS) ? elist[gi] : 0;
            const float* dp = dist + (size_t)e * FF + l4 * 8;
            float4 v0 = *(const float4*)dp;
            float4 v1 = *(const float4*)(dp + 4);
            U8 pk;
            pk.u[0]=f2bf(v0.x); pk.u[1]=f2bf(v0.y); pk.u[2]=f2bf(v0.z); pk.u[3]=f2bf(v0.w);
            pk.u[4]=f2bf(v1.x); pk.u[5]=f2bf(v1.y); pk.u[6]=f2bf(v1.z); pk.u[7]=f2bf(v1.w);
            a1[m] = pk.v;
        }

        // layer1 MFMA, bias-initialized C
        float b1v0 = B1[l15], b1v1 = B1[16 + l15];
        f4_t c1[4][2];
        #pragma unroll
        for (int m = 0; m < 4; m++) {
            #pragma unroll
            for (int j = 0; j < 4; j++) { c1[m][0][j] = b1v0; c1[m][1][j] = b1v1; }
        }
        #pragma unroll
        for (int n = 0; n < 2; n++) {
            bf8_t wf = *(bf8_t*)&wlds[(s * 6 + n) * 512 + lane * 8];
            #pragma unroll
            for (int m = 0; m < 4; m++)
                c1[m][n] = __builtin_amdgcn_mfma_f32_16x16x32_bf16(a1[m], wf, c1[m][n], 0, 0, 0);
        }

        // ssp -> h tile (bf16, slot-XOR swizzle within each 64-halfword row)
        #pragma unroll
        for (int m = 0; m < 4; m++)
            #pragma unroll
            for (int n = 0; n < 2; n++)
                #pragma unroll
                for (int r = 0; r < 4; r++) {
                    int row = m * 16 + l4 * 4 + r;
                    int col = n * 16 + l15;
                    int idx = row * 32 + (((col >> 3) ^ (row & 3)) << 3) + (col & 7);
                    hs[idx] = f2bf(ssp_f(c1[m][n][r]));
                }

        // layer2 A-frags (h tile dead afterwards -> reused for output)
        bf8_t ha[4];
        #pragma unroll
        for (int m = 0; m < 4; m++) {
            int row = m * 16 + l15;
            ha[m] = *(bf8_t*)&hs[row * 32 + ((l4 ^ (row & 3)) << 3)];
        }

        // layer2: two 32-col halves
        #pragma unroll 1
        for (int nh = 0; nh < 2; nh++) {
            float b2v0 = B2[nh * 32 + l15], b2v1 = B2[nh * 32 + 16 + l15];
            f4_t c2[4][2];
            #pragma unroll
            for (int m = 0; m < 4; m++) {
                #pragma unroll
                for (int j = 0; j < 4; j++) { c2[m][0][j] = b2v0; c2[m][1][j] = b2v1; }
            }
            #pragma unroll
            for (int n = 0; n < 2; n++) {
                bf8_t wf = *(bf8_t*)&wlds[(s * 6 + 2 + nh * 2 + n) * 512 + lane * 8];
                #pragma unroll
                for (int m = 0; m < 4; m++)
                    c2[m][n] = __builtin_amdgcn_mfma_f32_16x16x32_bf16(ha[m], wf, c2[m][n], 0, 0, 0);
            }
            // transpose through tile, then coalesced 16 B bf16 stores
            #pragma unroll
            for (int m = 0; m < 4; m++)
                #pragma unroll
                for (int n = 0; n < 2; n++)
                    #pragma unroll
                    for (int r = 0; r < 4; r++) {
                        int row = m * 16 + l4 * 4 + r;
                        int col = n * 16 + l15;
                        int idx = row * 32 + (((col >> 3) ^ (row & 3)) << 3) + (col & 7);
                        hs[idx] = f2bf(c2[m][n][r]);
                    }
            #pragma unroll
            for (int t = 0; t < 4; t++) {
                bf8_t v = *(bf8_t*)&hs[lane * 32 + ((t ^ (lane & 3)) << 3)];
                *(bf8_t*)&wo[(size_t)(base + lane) * KF + nh * 32 + t * 8] = v;
            }
        }
    }
}

// ---- split path 2: one wave per bucket, streaming sum, plain store ----------
__global__ __launch_bounds__(256, 8) void gather_k(
    const unsigned short* __restrict__ wo, const float* __restrict__ hx,
    const int* __restrict__ slist, const int* __restrict__ bc,
    const int* __restrict__ bb, float* __restrict__ z)
{
    int wv   = blockIdx.x * 4 + (threadIdx.x >> 6);   // bucket = s*NNODES+node
    int lane = threadIdx.x & 63;
    int n    = bc[wv];
    int base = bb[wv];
    float acc = 0.0f;
    int i = 0;
    for (; i + 4 <= n; i += 4) {
        int s0 = slist[base+i+0], s1 = slist[base+i+1];
        int s2 = slist[base+i+2], s3 = slist[base+i+3];
        float w0 = bf2f(wo[(size_t)(base+i+0) * KF + lane]);
        float w1 = bf2f(wo[(size_t)(base+i+1) * KF + lane]);
        float w2 = bf2f(wo[(size_t)(base+i+2) * KF + lane]);
        float w3 = bf2f(wo[(size_t)(base+i+3) * KF + lane]);
        float h0 = hx[(size_t)s0 * KF + lane];
        float h1 = hx[(size_t)s1 * KF + lane];
        float h2 = hx[(size_t)s2 * KF + lane];
        float h3 = hx[(size_t)s3 * KF + lane];
        acc = __fmaf_rn(w0, h0, acc); acc = __fmaf_rn(w1, h1, acc);
        acc = __fmaf_rn(w2, h2, acc); acc = __fmaf_rn(w3, h3, acc);
    }
    for (; i < n; ++i) {
        int sj = slist[base+i];
        float w = bf2f(wo[(size_t)(base+i) * KF + lane]);
        float hv = hx[(size_t)sj * KF + lane];
        acc = __fmaf_rn(w, hv, acc);
    }
    z[(size_t)wv * KF + lane] = acc;   // covers all buckets -> no z memset
}

// ---- fallback (small ws): fused MLP + run-length atomic scatter -------------
__global__ __launch_bounds__(256, 3) void edge_k(
    const float* __restrict__ dist, const float* __restrict__ hx,
    const int* __restrict__ elist, const int* __restrict__ slist,
    const int* __restrict__ rlist, const int* __restrict__ cnt,
    float* __restrict__ z,
    const float* __restrict__ w1_0, const float* __restrict__ b1_0,
    const float* __restrict__ w2_0, const float* __restrict__ b2_0,
    const float* __restrict__ w1_1, const float* __restrict__ b1_1,
    const float* __restrict__ w2_1, const float* __restrict__ b2_1,
    const float* __restrict__ w1_2, const float* __restrict__ b1_2,
    const float* __restrict__ w2_2, const float* __restrict__ b2_2)
{
    __shared__ float tb[4 * 16 * 64];
    const int lane = threadIdx.x & 63;
    const int wid  = threadIdx.x >> 6;
    float* tw = &tb[wid * 16 * 64];

    const int start1 = cnt[9], start2 = cnt[10];
    const int end0 = cnt[12], end1 = cnt[13], end2 = cnt[14];
    const int total = cnt[16];
    const int wavestride = gridDim.x * 4 * 64;

    for (int base = (blockIdx.x * 4 + wid) * 64; base < total; base += wavestride) {
        int idx = base + lane;
        int s = (base >= start2) ? 2 : (base >= start1) ? 1 : 0;
        int endS = (s == 0) ? end0 : (s == 1) ? end1 : end2;
        bool act = idx < endS;
        int nact = __popcll(__ballot(act));
        if (nact == 0) continue;

        int e = 0, sj_own = 0, rj_own = 0;
        if (act) { e = elist[idx]; sj_own = slist[idx]; rj_own = rlist[idx]; }

        s = __builtin_amdgcn_readfirstlane(s);
        const float *W1, *B1, *W2, *B2;
        if (s == 0)      { W1 = w1_0; B1 = b1_0; W2 = w2_0; B2 = b2_0; }
        else if (s == 1) { W1 = w1_1; B1 = b1_1; W2 = w2_1; B2 = b2_1; }
        else             { W1 = w1_2; B1 = b1_2; W2 = w2_2; B2 = b2_2; }

        float dv[32];
        {
            const float4* dp = (const float4*)(dist + (size_t)e * FF);
            #pragma unroll
            for (int q = 0; q < 8; q++) {
                float4 v = dp[q];
                dv[q*4+0] = v.x; dv[q*4+1] = v.y; dv[q*4+2] = v.z; dv[q*4+3] = v.w;
            }
        }
        float h[32];
        #pragma unroll
        for (int j = 0; j < 32; j++) h[j] = B1[j];
        #pragma unroll
        for (int i = 0; i < 32; i++) {
            float di = dv[i];
            #pragma unroll
            for (int j = 0; j < 32; j++) h[j] = __fmaf_rn(di, W1[i*32 + j], h[j]);
        }
        #pragma unroll
        for (int j = 0; j < 32; j++) h[j] = ssp_f(h[j]);

        float o[64];
        #pragma unroll
        for (int k = 0; k < 64; k++) o[k] = B2[k];
        #pragma unroll
        for (int j = 0; j < 32; j++) {
            float hj = h[j];
            #pragma unroll
            for (int k = 0; k < 64; k++) o[k] = __fmaf_rn(hj, W2[j*64 + k], o[k]);
        }

        float* zs = z + (size_t)s * NNODES * KF;
        float accv = 0.0f;
        int prev_r = -1;
        for (int c = 0; c < 4; c++) {
            int j0 = c * 16;
            if (j0 >= nact) break;
            int j1 = (nact < j0 + 16) ? nact : j0 + 16;
            if ((lane >> 4) == c) {
                int r = lane & 15;
                #pragma unroll
                for (int q = 0; q < 16; q++) {
                    int c4 = q ^ r;
                    *(float4*)&tw[r * 64 + c4 * 4] =
                        make_float4(o[q*4+0], o[q*4+1], o[q*4+2], o[q*4+3]);
                }
            }
            for (int j = j0; j < j1; j++) {
                int rj = __shfl(rj_own, j);
                int sj = __shfl(sj_own, j);
                int r  = j & 15;
                float ov = tw[r * 64 + (((lane >> 2) ^ r) << 2) + (lane & 3)];
                float hv = hx[(size_t)sj * KF + lane];
                if (rj != prev_r) {
                    if (prev_r >= 0) atomicAdd(&zs[(size_t)prev_r * KF + lane], accv);
                    accv = 0.0f; prev_r = rj;
                }
                accv = __fmaf_rn(ov, hv, accv);
            }
        }
        if (prev_r >= 0) atomicAdd(&zs[(size_t)prev_r * KF + lane], accv);
    }
}

// ---- output: elec_out = elec + sum_s (z_s[:,16:] @ gW_s + gb_s) ------------
__global__ void out_k(const float* __restrict__ elec, const float* __restrict__ z,
                      const float* __restrict__ g0W, const float* __restrict__ g0b,
                      const float* __restrict__ g1W, const float* __restrict__ g1b,
                      const float* __restrict__ g2W, const float* __restrict__ g2b,
                      float* __restrict__ out)
{
    __shared__ float zr[8][192];
    int row0 = blockIdx.x * 8;            // 512 blocks, 8 elec rows each
    int tid  = threadIdx.x;               // 128 threads
    for (int t = tid; t < 8 * 192; t += 128) {
        int n = t / 192, u = t % 192;
        int s = u >> 6, k = u & 63;
        int row = row0 + n;
        int node = (row >> 6) * NPER + 16 + (row & 63);
        zr[n][u] = z[((size_t)s * NNODES + node) * KF + k];
    }
    __syncthreads();
    int d = tid;
    float gb = g0b[d] + g1b[d] + g2b[d];
    float acc[8];
    #pragma unroll
    for (int n = 0; n < 8; n++) acc[n] = elec[(size_t)(row0 + n) * DF + d] + gb;

    for (int k = 0; k < 64; k++) {
        float w = g0W[k * DF + d];
        #pragma unroll
        for (int n = 0; n < 8; n++) acc[n] = __fmaf_rn(zr[n][k], w, acc[n]);
    }
    for (int k = 0; k < 64; k++) {
        float w = g1W[k * DF + d];
        #pragma unroll
        for (int n = 0; n < 8; n++) acc[n] = __fmaf_rn(zr[n][64 + k], w, acc[n]);
    }
    for (int k = 0; k < 64; k++) {
        float w = g2W[k * DF + d];
        #pragma unroll
        for (int n = 0; n < 8; n++) acc[n] = __fmaf_rn(zr[n][128 + k], w, acc[n]);
    }
    #pragma unroll
    for (int n = 0; n < 8; n++) out[(size_t)(row0 + n) * DF + d] = acc[n];
}

extern "C" void kernel_launch(void* const* d_in, const int* in_sizes, int n_in,
                              void* d_out, int out_size, void* d_ws, size_t ws_size,
                              hipStream_t stream)
{
    const float* nuc  = (const float*)d_in[0];
    const float* elec = (const float*)d_in[1];
    const float* dist = (const float*)d_in[2];
    const float* wsW1 = (const float*)d_in[3];
    const float* wsB1 = (const float*)d_in[4];
    const float* wsW2 = (const float*)d_in[5];
    const float* wsB2 = (const float*)d_in[6];
    const float* gsW  = (const float*)d_in[7];
    const float* gsB  = (const float*)d_in[8];
    const float* waW1 = (const float*)d_in[9];
    const float* waB1 = (const float*)d_in[10];
    const float* waW2 = (const float*)d_in[11];
    const float* waB2 = (const float*)d_in[12];
    const float* gaW  = (const float*)d_in[13];
    const float* gaB  = (const float*)d_in[14];
    const float* wnW1 = (const float*)d_in[15];
    const float* wnB1 = (const float*)d_in[16];
    const float* wnW2 = (const float*)d_in[17];
    const float* wnB2 = (const float*)d_in[18];
    const float* gnW  = (const float*)d_in[19];
    const float* gnB  = (const float*)d_in[20];
    const float* hW   = (const float*)d_in[21];
    const float* hb   = (const float*)d_in[22];
    const int* e_typ    = (const int*)d_in[23];
    const int* senders  = (const int*)d_in[24];
    const int* receivers= (const int*)d_in[25];
    float* out = (float*)d_out;

    char* ws = (char*)d_ws;
    int*   cnt    = (int*)(ws + WS_CNT);
    int*   bc     = (int*)(ws + WS_BC);
    int*   cur    = (int*)(ws + WS_CUR);
    float* z      = (float*)(ws + WS_Z);
    float* hx     = (float*)(ws + WS_HX);
    int*   elist  = (int*)(ws + WS_EL);
    int*   slist  = (int*)(ws + WS_SL);
    int*   rlist  = (int*)(ws + WS_RL);
    int*   bb     = (int*)(ws + WS_BB);
    unsigned short* wo = (unsigned short*)(ws + WS_WO);

    const bool split = (ws_size >= WS_END);

    // zero cnt + bucket counts + cursors (121 KB)
    hipMemsetAsync(d_ws, 0, WS_SMALL, stream);

    prep_k<<<dim3(HXBLK + NEBLK), dim3(256), 0, stream>>>(nuc, elec, hW, hb, hx,
                                                          e_typ, receivers, bc);
    scan2_k<<<dim3(1), dim3(768), 0, stream>>>(bc, bb, cnt);
    scatter2_k<<<dim3(NEBLK), dim3(256), 0, stream>>>(e_typ, senders, receivers,
                                                      bb, cur, elist, slist, rlist);
    if (split) {
        mlp_k<<<dim3(1024), dim3(256), 0, stream>>>(
            dist, elist, cnt, wo,
            wsW1, wsB1, wsW2, wsB2,
            waW1, waB1, waW2, waB2,
            wnW1, wnB1, wnW2, wnB2);
        gather_k<<<dim3(NBUCK / 4), dim3(256), 0, stream>>>(wo, hx, slist, bc, bb, z);
    } else {
        hipMemsetAsync(z, 0, Z_BYTES, stream);
        edge_k<<<dim3(988), dim3(256), 0, stream>>>(
            dist, hx, elist, slist, rlist, cnt, z,
            wsW1, wsB1, wsW2, wsB2,
            waW1, waB1, waW2, waB2,
            wnW1, wnB1, wnW2, wnB2);
    }
    out_k<<<dim3(512), dim3(128), 0, stream>>>(elec, z, gsW, gsB, gaW, gaB, gnW, gnB, out);
}

// Round 8
// 109.419 us; speedup vs baseline: 6.5722x; 1.0033x over previous
//
#include <hip/hip_runtime.h>
#include <math.h>

// Problem constants (fixed instance)
#define E_EDGES 524288
#define NNODES  5120
#define KF      64
#define DF      128
#define FF      32
#define NPER    80    // nodes per batch (16 nuc + 64 elec)
#define NEBLK   2048  // E_EDGES / 256
#define NBUCK   (3 * NNODES)
#define HXBLK   1280  // NNODES*64/256

// workspace layout (bytes)
#define WS_CNT   0u
#define WS_BC    256u
#define WS_CUR   (WS_BC + NBUCK*4u)
#define WS_SMALL (WS_CUR + NBUCK*4u)               // 123,136 B zeroed per call
#define WS_Z     WS_SMALL
#define Z_BYTES  (3u*NNODES*KF*4u)                 // 3,932,160
#define WS_HX    (WS_Z + Z_BYTES)
#define HX_BYTES (NNODES*KF*4u)                    // 1,310,720
#define LIST_CAP (E_EDGES + 256)
#define WS_EL    (WS_HX + HX_BYTES)
#define WS_SL    (WS_EL + LIST_CAP*4u)
#define WS_RL    (WS_SL + LIST_CAP*4u)
#define WS_BB    (WS_RL + LIST_CAP*4u)
#define WS_WO    (WS_BB + NBUCK*4u)                // 256-aligned
#define WO_BYTES ((size_t)LIST_CAP * KF * 2u)      // bf16: 67,141,632
#define WS_END   ((size_t)WS_WO + WO_BYTES)        // ~79 MB

typedef __attribute__((ext_vector_type(8))) short bf8_t;   // 8 bf16 (4 VGPRs)
typedef __attribute__((ext_vector_type(4))) float f4_t;    // MFMA 16x16 C/D

union U8 { bf8_t v; unsigned short u[8]; };

__device__ __forceinline__ float ssp_f(float x) {
    float t  = __expf(-fabsf(x));
    float sp = fmaxf(x, 0.0f) + __logf(1.0f + t);
    return sp - 0.6931471805599453f;
}

__device__ __forceinline__ unsigned short f2bf(float f) {
    union { float f; unsigned u; } c; c.f = f;
    unsigned r = c.u + 0x7FFFu + ((c.u >> 16) & 1u);   // RNE
    return (unsigned short)(r >> 16);
}
__device__ __forceinline__ float bf2f(unsigned short u) {
    union { unsigned u; float f; } c; c.u = ((unsigned)u) << 16;
    return c.f;
}

__device__ __forceinline__ int slot_of(int t, int r) {
    int slot = (t == 3) ? 0 : (t == 4) ? 1 : (t == 1) ? 2 : -1;
    if ((r % NPER) < 16) slot = -1;   // nuc receivers never read
    return slot;
}

// ---- parallel zero of cnt+bc+cur (hipMemsetAsync small-fill is ~39us!) ------
__global__ void zero_k(float4* __restrict__ p)
{
    int i = blockIdx.x * blockDim.x + threadIdx.x;   // 31*256 = 7936 >= 7696
    if ((unsigned)(i * 16) < WS_SMALL)
        p[i] = make_float4(0.f, 0.f, 0.f, 0.f);
}

// ---- fused: hx build (blocks [0,HXBLK)) + bucket counts (rest) --------------
__global__ void prep_k(const float* __restrict__ nuc, const float* __restrict__ elec,
                       const float* __restrict__ hW, const float* __restrict__ hb,
                       float* __restrict__ hx,
                       const int* __restrict__ et, const int* __restrict__ recv,
                       int* __restrict__ bc)
{
    if (blockIdx.x < HXBLK) {
        int gw   = (blockIdx.x * blockDim.x + threadIdx.x) >> 6;  // one wave per node
        int lane = threadIdx.x & 63;
        int b = gw / NPER, p = gw % NPER;
        float v;
        if (p < 16) {
            v = nuc[((size_t)b * 16 + p) * KF + lane];
        } else {
            int pe = p - 16;
            const float* er = elec + ((size_t)b * 64 + pe) * DF;
            float acc = hb[lane];
            #pragma unroll 8
            for (int d = 0; d < DF; d++) acc = __fmaf_rn(er[d], hW[d * KF + lane], acc);
            v = acc;
        }
        hx[(size_t)gw * KF + lane] = v;
    } else {
        int e  = (blockIdx.x - HXBLK) * blockDim.x + threadIdx.x;
        int rv = recv[e];
        int slot = slot_of(et[e], rv);
        if (slot >= 0) atomicAdd(&bc[slot * NNODES + rv], 1);
    }
}

// ---- B: single-block segmented exclusive scan of 15360 bucket counts --------
__global__ void scan2_k(const int* __restrict__ bc, int* __restrict__ bb,
                        int* __restrict__ c)
{
    __shared__ int wtot[12];
    __shared__ int slotStart[3];
    int t    = threadIdx.x;
    int lane = t & 63, w = t >> 6;       // 12 waves
    int s    = t >> 8;                   // 4 waves per slot
    int base = t * 20;
    int ssum = 0;
    #pragma unroll
    for (int i = 0; i < 20; i++) ssum += bc[base + i];
    int x = ssum;
    #pragma unroll
    for (int off = 1; off < 64; off <<= 1) {
        int y = __shfl_up(x, off);
        if (lane >= off) x += y;
    }
    if (lane == 63) wtot[w] = x;
    __syncthreads();
    if (t == 0) {
        int t0 = wtot[0] + wtot[1] + wtot[2]  + wtot[3];
        int t1 = wtot[4] + wtot[5] + wtot[6]  + wtot[7];
        int t2 = wtot[8] + wtot[9] + wtot[10] + wtot[11];
        int a0 = (t0 + 63) & ~63, a1 = (t1 + 63) & ~63, a2 = (t2 + 63) & ~63;
        slotStart[0] = 0; slotStart[1] = a0; slotStart[2] = a0 + a1;
        c[8]  = 0;   c[9]  = a0;       c[10] = a0 + a1;        // aligned starts
        c[12] = t0;  c[13] = a0 + t1;  c[14] = a0 + a1 + t2;   // ends
        c[16] = a0 + a1 + a2;                                  // total padded
    }
    __syncthreads();
    int preWave = 0;
    for (int w2 = s * 4; w2 < w; ++w2) preWave += wtot[w2];
    int run = slotStart[s] + preWave + (x - ssum);   // exclusive prefix
    #pragma unroll
    for (int i = 0; i < 20; i++) { int v = bc[base + i]; bb[base + i] = run; run += v; }
}

// ---- C: counting-sort scatter (per-thread cursor atomics, 15360 addresses) --
__global__ void scatter2_k(const int* __restrict__ et, const int* __restrict__ snd,
                           const int* __restrict__ recv, const int* __restrict__ bb,
                           int* __restrict__ cur,
                           int* __restrict__ elist, int* __restrict__ slist,
                           int* __restrict__ rlist)
{
    int e  = blockIdx.x * blockDim.x + threadIdx.x;
    int rv = recv[e], sv = snd[e];
    int slot = slot_of(et[e], rv);
    if (slot >= 0) {
        int bidx = slot * NNODES + rv;
        int pos = bb[bidx] + atomicAdd(&cur[bidx], 1);
        elist[pos] = e; slist[pos] = sv; rlist[pos] = rv;
    }
}

// ---- split path 1: MFMA MLP -> streamed bf16 we rows ------------------------
__global__ __launch_bounds__(256, 4) void mlp_k(
    const float* __restrict__ dist, const int* __restrict__ elist,
    const int* __restrict__ cnt, unsigned short* __restrict__ wo,
    const float* __restrict__ w1_0, const float* __restrict__ b1_0,
    const float* __restrict__ w2_0, const float* __restrict__ b2_0,
    const float* __restrict__ w1_1, const float* __restrict__ b1_1,
    const float* __restrict__ w2_1, const float* __restrict__ b2_1,
    const float* __restrict__ w1_2, const float* __restrict__ b1_2,
    const float* __restrict__ w2_2, const float* __restrict__ b2_2)
{
    __shared__ unsigned short wlds[18 * 512];   // 18 KiB: 18 pre-packed B frags
    __shared__ unsigned short hlds[4 * 2048];   // 16 KiB: per-wave 64x32 bf16 tile
    const int lane = threadIdx.x & 63;
    const int wid  = threadIdx.x >> 6;
    const int l15  = lane & 15, l4 = lane >> 4;

    // ---- prestage W fragments (once per block) ----
    {
        const float* W1s[3] = {w1_0, w1_1, w1_2};
        const float* W2s[3] = {w2_0, w2_1, w2_2};
        for (int f = wid; f < 18; f += 4) {
            int sg = f / 6, q = f % 6;
            const float* src = (q < 2) ? W1s[sg] : W2s[sg];
            int stride = (q < 2) ? 32 : 64;
            int cbase  = (q < 2) ? q * 16 : (q - 2) * 16;
            U8 pk;
            #pragma unroll
            for (int j = 0; j < 8; j++)
                pk.u[j] = f2bf(src[(l4 * 8 + j) * stride + cbase + l15]);
            *(bf8_t*)&wlds[f * 512 + lane * 8] = pk.v;
        }
    }
    __syncthreads();

    unsigned short* hs = &hlds[wid * 2048];

    const int start1 = cnt[9], start2 = cnt[10];
    const int end0 = cnt[12], end1 = cnt[13], end2 = cnt[14];
    const int total = cnt[16];

    for (int base = (blockIdx.x * 4 + wid) * 64; base < total; base += gridDim.x * 256) {
        int s = (base >= start2) ? 2 : (base >= start1) ? 1 : 0;
        int endS = (s == 0) ? end0 : (s == 1) ? end1 : end2;
        s = __builtin_amdgcn_readfirstlane(s);
        const float* B1 = (s == 0) ? b1_0 : (s == 1) ? b1_1 : b1_2;
        const float* B2 = (s == 0) ? b2_0 : (s == 1) ? b2_1 : b2_2;

        // layer1 A-frags straight from dist (lane row=l15, k-slice l4*8)
        bf8_t a1[4];
        #pragma unroll
        for (int m = 0; m < 4; m++) {
            int gi = base + m * 16 + l15;
            int e  = (gi < endS) ? elist[gi] : 0;
            const float* dp = dist + (size_t)e * FF + l4 * 8;
            float4 v0 = *(const float4*)dp;
            float4 v1 = *(const float4*)(dp + 4);
            U8 pk;
            pk.u[0]=f2bf(v0.x); pk.u[1]=f2bf(v0.y); pk.u[2]=f2bf(v0.z); pk.u[3]=f2bf(v0.w);
            pk.u[4]=f2bf(v1.x); pk.u[5]=f2bf(v1.y); pk.u[6]=f2bf(v1.z); pk.u[7]=f2bf(v1.w);
            a1[m] = pk.v;
        }

        // layer1 MFMA, bias-initialized C
        float b1v0 = B1[l15], b1v1 = B1[16 + l15];
        f4_t c1[4][2];
        #pragma unroll
        for (int m = 0; m < 4; m++) {
            #pragma unroll
            for (int j = 0; j < 4; j++) { c1[m][0][j] = b1v0; c1[m][1][j] = b1v1; }
        }
        #pragma unroll
        for (int n = 0; n < 2; n++) {
            bf8_t wf = *(bf8_t*)&wlds[(s * 6 + n) * 512 + lane * 8];
            #pragma unroll
            for (int m = 0; m < 4; m++)
                c1[m][n] = __builtin_amdgcn_mfma_f32_16x16x32_bf16(a1[m], wf, c1[m][n], 0, 0, 0);
        }

        // ssp -> h tile (bf16, slot-XOR swizzle within each 64-halfword row)
        #pragma unroll
        for (int m = 0; m < 4; m++)
            #pragma unroll
            for (int n = 0; n < 2; n++)
                #pragma unroll
                for (int r = 0; r < 4; r++) {
                    int row = m * 16 + l4 * 4 + r;
                    int col = n * 16 + l15;
                    int idx = row * 32 + (((col >> 3) ^ (row & 3)) << 3) + (col & 7);
                    hs[idx] = f2bf(ssp_f(c1[m][n][r]));
                }

        // layer2 A-frags (h tile dead afterwards -> reused for output)
        bf8_t ha[4];
        #pragma unroll
        for (int m = 0; m < 4; m++) {
            int row = m * 16 + l15;
            ha[m] = *(bf8_t*)&hs[row * 32 + ((l4 ^ (row & 3)) << 3)];
        }

        // layer2: two 32-col halves
        #pragma unroll 1
        for (int nh = 0; nh < 2; nh++) {
            float b2v0 = B2[nh * 32 + l15], b2v1 = B2[nh * 32 + 16 + l15];
            f4_t c2[4][2];
            #pragma unroll
            for (int m = 0; m < 4; m++) {
                #pragma unroll
                for (int j = 0; j < 4; j++) { c2[m][0][j] = b2v0; c2[m][1][j] = b2v1; }
            }
            #pragma unroll
            for (int n = 0; n < 2; n++) {
                bf8_t wf = *(bf8_t*)&wlds[(s * 6 + 2 + nh * 2 + n) * 512 + lane * 8];
                #pragma unroll
                for (int m = 0; m < 4; m++)
                    c2[m][n] = __builtin_amdgcn_mfma_f32_16x16x32_bf16(ha[m], wf, c2[m][n], 0, 0, 0);
            }
            // transpose through tile, then coalesced 16 B bf16 stores
            #pragma unroll
            for (int m = 0; m < 4; m++)
                #pragma unroll
                for (int n = 0; n < 2; n++)
                    #pragma unroll
                    for (int r = 0; r < 4; r++) {
                        int row = m * 16 + l4 * 4 + r;
                        int col = n * 16 + l15;
                        int idx = row * 32 + (((col >> 3) ^ (row & 3)) << 3) + (col & 7);
                        hs[idx] = f2bf(c2[m][n][r]);
                    }
            #pragma unroll
            for (int t = 0; t < 4; t++) {
                bf8_t v = *(bf8_t*)&hs[lane * 32 + ((t ^ (lane & 3)) << 3)];
                *(bf8_t*)&wo[(size_t)(base + lane) * KF + nh * 32 + t * 8] = v;
            }
        }
    }
}

// ---- split path 2: one wave per bucket, streaming sum, plain store ----------
__global__ __launch_bounds__(256, 8) void gather_k(
    const unsigned short* __restrict__ wo, const float* __restrict__ hx,
    const int* __restrict__ slist, const int* __restrict__ bc,
    const int* __restrict__ bb, float* __restrict__ z)
{
    int wv   = blockIdx.x * 4 + (threadIdx.x >> 6);   // bucket = s*NNODES+node
    int lane = threadIdx.x & 63;
    int n    = bc[wv];
    int base = bb[wv];
    float acc = 0.0f;
    int i = 0;
    for (; i + 4 <= n; i += 4) {
        int s0 = slist[base+i+0], s1 = slist[base+i+1];
        int s2 = slist[base+i+2], s3 = slist[base+i+3];
        float w0 = bf2f(wo[(size_t)(base+i+0) * KF + lane]);
        float w1 = bf2f(wo[(size_t)(base+i+1) * KF + lane]);
        float w2 = bf2f(wo[(size_t)(base+i+2) * KF + lane]);
        float w3 = bf2f(wo[(size_t)(base+i+3) * KF + lane]);
        float h0 = hx[(size_t)s0 * KF + lane];
        float h1 = hx[(size_t)s1 * KF + lane];
        float h2 = hx[(size_t)s2 * KF + lane];
        float h3 = hx[(size_t)s3 * KF + lane];
        acc = __fmaf_rn(w0, h0, acc); acc = __fmaf_rn(w1, h1, acc);
        acc = __fmaf_rn(w2, h2, acc); acc = __fmaf_rn(w3, h3, acc);
    }
    for (; i < n; ++i) {
        int sj = slist[base+i];
        float w = bf2f(wo[(size_t)(base+i) * KF + lane]);
        float hv = hx[(size_t)sj * KF + lane];
        acc = __fmaf_rn(w, hv, acc);
    }
    z[(size_t)wv * KF + lane] = acc;   // covers all buckets -> no z memset
}

// ---- fallback (small ws): fused MLP + run-length atomic scatter -------------
__global__ __launch_bounds__(256, 3) void edge_k(
    const float* __restrict__ dist, const float* __restrict__ hx,
    const int* __restrict__ elist, const int* __restrict__ slist,
    const int* __restrict__ rlist, const int* __restrict__ cnt,
    float* __restrict__ z,
    const float* __restrict__ w1_0, const float* __restrict__ b1_0,
    const float* __restrict__ w2_0, const float* __restrict__ b2_0,
    const float* __restrict__ w1_1, const float* __restrict__ b1_1,
    const float* __restrict__ w2_1, const float* __restrict__ b2_1,
    const float* __restrict__ w1_2, const float* __restrict__ b1_2,
    const float* __restrict__ w2_2, const float* __restrict__ b2_2)
{
    __shared__ float tb[4 * 16 * 64];
    const int lane = threadIdx.x & 63;
    const int wid  = threadIdx.x >> 6;
    float* tw = &tb[wid * 16 * 64];

    const int start1 = cnt[9], start2 = cnt[10];
    const int end0 = cnt[12], end1 = cnt[13], end2 = cnt[14];
    const int total = cnt[16];
    const int wavestride = gridDim.x * 4 * 64;

    for (int base = (blockIdx.x * 4 + wid) * 64; base < total; base += wavestride) {
        int idx = base + lane;
        int s = (base >= start2) ? 2 : (base >= start1) ? 1 : 0;
        int endS = (s == 0) ? end0 : (s == 1) ? end1 : end2;
        bool act = idx < endS;
        int nact = __popcll(__ballot(act));
        if (nact == 0) continue;

        int e = 0, sj_own = 0, rj_own = 0;
        if (act) { e = elist[idx]; sj_own = slist[idx]; rj_own = rlist[idx]; }

        s = __builtin_amdgcn_readfirstlane(s);
        const float *W1, *B1, *W2, *B2;
        if (s == 0)      { W1 = w1_0; B1 = b1_0; W2 = w2_0; B2 = b2_0; }
        else if (s == 1) { W1 = w1_1; B1 = b1_1; W2 = w2_1; B2 = b2_1; }
        else             { W1 = w1_2; B1 = b1_2; W2 = w2_2; B2 = b2_2; }

        float dv[32];
        {
            const float4* dp = (const float4*)(dist + (size_t)e * FF);
            #pragma unroll
            for (int q = 0; q < 8; q++) {
                float4 v = dp[q];
                dv[q*4+0] = v.x; dv[q*4+1] = v.y; dv[q*4+2] = v.z; dv[q*4+3] = v.w;
            }
        }
        float h[32];
        #pragma unroll
        for (int j = 0; j < 32; j++) h[j] = B1[j];
        #pragma unroll
        for (int i = 0; i < 32; i++) {
            float di = dv[i];
            #pragma unroll
            for (int j = 0; j < 32; j++) h[j] = __fmaf_rn(di, W1[i*32 + j], h[j]);
        }
        #pragma unroll
        for (int j = 0; j < 32; j++) h[j] = ssp_f(h[j]);

        float o[64];
        #pragma unroll
        for (int k = 0; k < 64; k++) o[k] = B2[k];
        #pragma unroll
        for (int j = 0; j < 32; j++) {
            float hj = h[j];
            #pragma unroll
            for (int k = 0; k < 64; k++) o[k] = __fmaf_rn(hj, W2[j*64 + k], o[k]);
        }

        float* zs = z + (size_t)s * NNODES * KF;
        float accv = 0.0f;
        int prev_r = -1;
        for (int c = 0; c < 4; c++) {
            int j0 = c * 16;
            if (j0 >= nact) break;
            int j1 = (nact < j0 + 16) ? nact : j0 + 16;
            if ((lane >> 4) == c) {
                int r = lane & 15;
                #pragma unroll
                for (int q = 0; q < 16; q++) {
                    int c4 = q ^ r;
                    *(float4*)&tw[r * 64 + c4 * 4] =
                        make_float4(o[q*4+0], o[q*4+1], o[q*4+2], o[q*4+3]);
                }
            }
            for (int j = j0; j < j1; j++) {
                int rj = __shfl(rj_own, j);
                int sj = __shfl(sj_own, j);
                int r  = j & 15;
                float ov = tw[r * 64 + (((lane >> 2) ^ r) << 2) + (lane & 3)];
                float hv = hx[(size_t)sj * KF + lane];
                if (rj != prev_r) {
                    if (prev_r >= 0) atomicAdd(&zs[(size_t)prev_r * KF + lane], accv);
                    accv = 0.0f; prev_r = rj;
                }
                accv = __fmaf_rn(ov, hv, accv);
            }
        }
        if (prev_r >= 0) atomicAdd(&zs[(size_t)prev_r * KF + lane], accv);
    }
}

// ---- output: elec_out = elec + sum_s (z_s[:,16:] @ gW_s + gb_s) ------------
__global__ void out_k(const float* __restrict__ elec, const float* __restrict__ z,
                      const float* __restrict__ g0W, const float* __restrict__ g0b,
                      const float* __restrict__ g1W, const float* __restrict__ g1b,
                      const float* __restrict__ g2W, const float* __restrict__ g2b,
                      float* __restrict__ out)
{
    __shared__ float zr[8][192];
    int row0 = blockIdx.x * 8;            // 512 blocks, 8 elec rows each
    int tid  = threadIdx.x;               // 128 threads
    for (int t = tid; t < 8 * 192; t += 128) {
        int n = t / 192, u = t % 192;
        int s = u >> 6, k = u & 63;
        int row = row0 + n;
        int node = (row >> 6) * NPER + 16 + (row & 63);
        zr[n][u] = z[((size_t)s * NNODES + node) * KF + k];
    }
    __syncthreads();
    int d = tid;
    float gb = g0b[d] + g1b[d] + g2b[d];
    float acc[8];
    #pragma unroll
    for (int n = 0; n < 8; n++) acc[n] = elec[(size_t)(row0 + n) * DF + d] + gb;

    for (int k = 0; k < 64; k++) {
        float w = g0W[k * DF + d];
        #pragma unroll
        for (int n = 0; n < 8; n++) acc[n] = __fmaf_rn(zr[n][k], w, acc[n]);
    }
    for (int k = 0; k < 64; k++) {
        float w = g1W[k * DF + d];
        #pragma unroll
        for (int n = 0; n < 8; n++) acc[n] = __fmaf_rn(zr[n][64 + k], w, acc[n]);
    }
    for (int k = 0; k < 64; k++) {
        float w = g2W[k * DF + d];
        #pragma unroll
        for (int n = 0; n < 8; n++) acc[n] = __fmaf_rn(zr[n][128 + k], w, acc[n]);
    }
    #pragma unroll
    for (int n = 0; n < 8; n++) out[(size_t)(row0 + n) * DF + d] = acc[n];
}

extern "C" void kernel_launch(void* const* d_in, const int* in_sizes, int n_in,
                              void* d_out, int out_size, void* d_ws, size_t ws_size,
                              hipStream_t stream)
{
    const float* nuc  = (const float*)d_in[0];
    const float* elec = (const float*)d_in[1];
    const float* dist = (const float*)d_in[2];
    const float* wsW1 = (const float*)d_in[3];
    const float* wsB1 = (const float*)d_in[4];
    const float* wsW2 = (const float*)d_in[5];
    const float* wsB2 = (const float*)d_in[6];
    const float* gsW  = (const float*)d_in[7];
    const float* gsB  = (const float*)d_in[8];
    const float* waW1 = (const float*)d_in[9];
    const float* waB1 = (const float*)d_in[10];
    const float* waW2 = (const float*)d_in[11];
    const float* waB2 = (const float*)d_in[12];
    const float* gaW  = (const float*)d_in[13];
    const float* gaB  = (const float*)d_in[14];
    const float* wnW1 = (const float*)d_in[15];
    const float* wnB1 = (const float*)d_in[16];
    const float* wnW2 = (const float*)d_in[17];
    const float* wnB2 = (const float*)d_in[18];
    const float* gnW  = (const float*)d_in[19];
    const float* gnB  = (const float*)d_in[20];
    const float* hW   = (const float*)d_in[21];
    const float* hb   = (const float*)d_in[22];
    const int* e_typ    = (const int*)d_in[23];
    const int* senders  = (const int*)d_in[24];
    const int* receivers= (const int*)d_in[25];
    float* out = (float*)d_out;

    char* ws = (char*)d_ws;
    int*   cnt    = (int*)(ws + WS_CNT);
    int*   bc     = (int*)(ws + WS_BC);
    int*   cur    = (int*)(ws + WS_CUR);
    float* z      = (float*)(ws + WS_Z);
    float* hx     = (float*)(ws + WS_HX);
    int*   elist  = (int*)(ws + WS_EL);
    int*   slist  = (int*)(ws + WS_SL);
    int*   rlist  = (int*)(ws + WS_RL);
    int*   bb     = (int*)(ws + WS_BB);
    unsigned short* wo = (unsigned short*)(ws + WS_WO);

    const bool split = (ws_size >= WS_END);

    // zero cnt + bucket counts + cursors with a properly-gridded kernel
    // (hipMemsetAsync small-fill dispatches a tiny-grid fill: measured ~39 us)
    zero_k<<<dim3(31), dim3(256), 0, stream>>>((float4*)d_ws);

    prep_k<<<dim3(HXBLK + NEBLK), dim3(256), 0, stream>>>(nuc, elec, hW, hb, hx,
                                                          e_typ, receivers, bc);
    scan2_k<<<dim3(1), dim3(768), 0, stream>>>(bc, bb, cnt);
    scatter2_k<<<dim3(NEBLK), dim3(256), 0, stream>>>(e_typ, senders, receivers,
                                                      bb, cur, elist, slist, rlist);
    if (split) {
        mlp_k<<<dim3(1024), dim3(256), 0, stream>>>(
            dist, elist, cnt, wo,
            wsW1, wsB1, wsW2, wsB2,
            waW1, waB1, waW2, waB2,
            wnW1, wnB1, wnW2, wnB2);
        gather_k<<<dim3(NBUCK / 4), dim3(256), 0, stream>>>(wo, hx, slist, bc, bb, z);
    } else {
        hipMemsetAsync(z, 0, Z_BYTES, stream);
        edge_k<<<dim3(988), dim3(256), 0, stream>>>(
            dist, hx, elist, slist, rlist, cnt, z,
            wsW1, wsB1, wsW2, wsB2,
            waW1, waB1, waW2, waB2,
            wnW1, wnB1, wnW2, wnB2);
    }
    out_k<<<dim3(512), dim3(128), 0, stream>>>(elec, z, gsW, gsB, gaW, gaB, gnW, gnB, out);
}

// Round 9
// 103.259 us; speedup vs baseline: 6.9642x; 1.0597x over previous
//
#include <hip/hip_runtime.h>
#include <math.h>

// Problem constants (fixed instance)
#define E_EDGES 524288
#define NNODES  5120
#define KF      64
#define DF      128
#define FF      32
#define NPER    80    // nodes per batch (16 nuc + 64 elec)
#define NBUCK   (3 * NNODES)      // 15360 buckets (slot, node)
#define CAP     64                // rows per bucket (lambda=20.5 -> ~1e-15 overflow)
#define HXBLK   1280              // hx blocks (5120 nodes, 4 waves/block)
#define EBLK    2048              // edge blocks (256 edges each)

// workspace layout (bytes)
#define WS_CUR   0u
#define CUR_BYTES (NBUCK*4u)                        // 61,440 (zeroed per call)
#define WS_Z     CUR_BYTES
#define Z_BYTES  (NBUCK*KF*4u)                      // 3,932,160 (fully written)
#define WS_HX    (WS_Z + Z_BYTES)
#define HX_BYTES (NNODES*KF*4u)                     // 1,310,720
#define WS_SL    (WS_HX + HX_BYTES)
#define SL_BYTES (NBUCK*CAP*4u)                     // 3,932,160
#define WS_WO    (WS_SL + SL_BYTES)                 // 9,236,480 (256-aligned)
#define WO_BYTES ((size_t)NBUCK*CAP*KF*2u)          // 125,829,120
#define WS_END   ((size_t)WS_WO + WO_BYTES)         // ~135 MB

typedef __attribute__((ext_vector_type(8))) short bf8_t;   // 8 bf16 (4 VGPRs)
typedef __attribute__((ext_vector_type(4))) float f4_t;    // MFMA 16x16 C/D

union U8 { bf8_t v; unsigned short u[8]; };

__device__ __forceinline__ float ssp_f(float x) {
    float t  = __expf(-fabsf(x));
    float sp = fmaxf(x, 0.0f) + __logf(1.0f + t);
    return sp - 0.6931471805599453f;
}

__device__ __forceinline__ unsigned short f2bf(float f) {
    union { float f; unsigned u; } c; c.f = f;
    unsigned r = c.u + 0x7FFFu + ((c.u >> 16) & 1u);   // RNE
    return (unsigned short)(r >> 16);
}
__device__ __forceinline__ float bf2f(unsigned short u) {
    union { unsigned u; float f; } c; c.u = ((unsigned)u) << 16;
    return c.f;
}

// ---- K1: zero the bucket cursors (61,440 B) ---------------------------------
__global__ void zero_k(float4* __restrict__ p)
{
    int i = blockIdx.x * blockDim.x + threadIdx.x;   // 15*256 = 3840 exact
    p[i] = make_float4(0.f, 0.f, 0.f, 0.f);
}

// ---- K2: fused hx build + block-sorted MFMA edge MLP + strided scatter ------
__global__ __launch_bounds__(256, 3) void fused_k(
    const float* __restrict__ nuc, const float* __restrict__ elec,
    const float* __restrict__ hW, const float* __restrict__ hb,
    float* __restrict__ hx,
    const float* __restrict__ dist, const int* __restrict__ et,
    const int* __restrict__ snd, const int* __restrict__ recv,
    int* __restrict__ cur, int* __restrict__ slist,
    unsigned short* __restrict__ wo,
    const float* __restrict__ w1_0, const float* __restrict__ b1_0,
    const float* __restrict__ w2_0, const float* __restrict__ b2_0,
    const float* __restrict__ w1_1, const float* __restrict__ b1_1,
    const float* __restrict__ w2_1, const float* __restrict__ b2_1,
    const float* __restrict__ w1_2, const float* __restrict__ b1_2,
    const float* __restrict__ w2_2, const float* __restrict__ b2_2)
{
    if (blockIdx.x < HXBLK) {
        // hx = concat(nuc, elec @ h_W + h_b), one wave per node
        int gw   = (blockIdx.x * 256 + threadIdx.x) >> 6;
        int lane = threadIdx.x & 63;
        int b = gw / NPER, p = gw % NPER;
        float v;
        if (p < 16) {
            v = nuc[((size_t)b * 16 + p) * KF + lane];
        } else {
            int pe = p - 16;
            const float* er = elec + ((size_t)b * 64 + pe) * DF;
            float acc = hb[lane];
            #pragma unroll 8
            for (int d = 0; d < DF; d++) acc = __fmaf_rn(er[d], hW[d * KF + lane], acc);
            v = acc;
        }
        hx[(size_t)gw * KF + lane] = v;
        return;
    }

    __shared__ unsigned short wlds[18 * 512];   // 18 KiB: pre-packed W frags
    __shared__ float blds[3][96];               // biases: b1[32] | b2[64]
    __shared__ unsigned short tlds[4][512];     // per-wave 16x32 bf16 tile
    __shared__ unsigned short reorder[320];     // block-sorted local edge ids
    __shared__ int parr[256];                   // per-local-edge wo row (or -1)
    __shared__ int scnt[4][3], sbase_w[4][3];
    __shared__ int seg_tile[3];                 // first tile index per slot
    __shared__ int tcount;

    const int tid = threadIdx.x, lane = tid & 63, wid = tid >> 6;
    const int l15 = lane & 15, l4 = lane >> 4;
    const int ebase = (blockIdx.x - HXBLK) * 256;
    const int e = ebase + tid;

    int etv = et[e], rv = recv[e], sv = snd[e];
    int slot = (etv == 3) ? 0 : (etv == 4) ? 1 : (etv == 1) ? 2 : -1;
    if ((rv % NPER) < 16) slot = -1;            // nuc receivers never read

    // ---- stage weights/biases, pad reorder ----
    {
        const float* W1s[3] = {w1_0, w1_1, w1_2};
        const float* W2s[3] = {w2_0, w2_1, w2_2};
        for (int f = wid; f < 18; f += 4) {
            int sg = f / 6, q = f % 6;
            const float* src = (q < 2) ? W1s[sg] : W2s[sg];
            int stride = (q < 2) ? 32 : 64;
            int cbase  = (q < 2) ? q * 16 : (q - 2) * 16;
            U8 pk;
            #pragma unroll
            for (int j = 0; j < 8; j++)
                pk.u[j] = f2bf(src[(l4 * 8 + j) * stride + cbase + l15]);
            *(bf8_t*)&wlds[f * 512 + lane * 8] = pk.v;
        }
        const float* B1s[3] = {b1_0, b1_1, b1_2};
        const float* B2s[3] = {b2_0, b2_1, b2_2};
        for (int i = tid; i < 288; i += 256) {
            int sg = i / 96, j = i % 96;
            blds[sg][j] = (j < 32) ? B1s[sg][j] : B2s[sg][j - 32];
        }
        for (int i = tid; i < 320; i += 256) reorder[i] = 0xFFFF;
    }
    // ---- block-local counting sort into 16-padded slot segments ----
    unsigned long long m0 = __ballot(slot == 0);
    unsigned long long m1 = __ballot(slot == 1);
    unsigned long long m2 = __ballot(slot == 2);
    if (lane == 0) {
        scnt[wid][0] = __popcll(m0); scnt[wid][1] = __popcll(m1); scnt[wid][2] = __popcll(m2);
    }
    __syncthreads();
    if (tid == 0) {
        int t = 0;
        for (int s = 0; s < 3; s++) {
            int b = 0;
            for (int w = 0; w < 4; w++) { sbase_w[w][s] = b; b += scnt[w][s]; }
            seg_tile[s] = t;
            t += (b + 15) >> 4;
        }
        tcount = t;                              // <= 19
    }
    __syncthreads();
    int wpos = -1;
    if (slot >= 0) {
        unsigned long long msel = (slot == 0) ? m0 : (slot == 1) ? m1 : m2;
        int rank = sbase_w[wid][slot] + __popcll(msel & ((1ull << lane) - 1ull));
        reorder[seg_tile[slot] * 16 + rank] = (unsigned short)tid;
        int bidx = slot * NNODES + rv;
        int p = atomicAdd(&cur[bidx], 1);
        if (p < CAP) { wpos = bidx * CAP + p; slist[wpos] = sv; }
    }
    parr[tid] = wpos;
    __syncthreads();

    // ---- per-wave tile processing (slot-pure 16x32 tiles) ----
    unsigned short* hs = tlds[wid];
    const int T = tcount;
    for (int t = wid; t < T; t += 4) {
        int s = (t >= seg_tile[2]) ? 2 : (t >= seg_tile[1]) ? 1 : 0;
        s = __builtin_amdgcn_readfirstlane(s);

        int li  = reorder[t * 16 + l15];
        int lie = (li == 0xFFFF) ? 0 : li;
        int wp  = (li == 0xFFFF) ? -1 : parr[lie];

        // A-frag from dist (row = local edge l15, k-slice = l4*8)
        const float* dp = dist + (size_t)(ebase + lie) * FF + l4 * 8;
        float4 v0 = *(const float4*)dp;
        float4 v1 = *(const float4*)(dp + 4);
        U8 pk;
        pk.u[0]=f2bf(v0.x); pk.u[1]=f2bf(v0.y); pk.u[2]=f2bf(v0.z); pk.u[3]=f2bf(v0.w);
        pk.u[4]=f2bf(v1.x); pk.u[5]=f2bf(v1.y); pk.u[6]=f2bf(v1.z); pk.u[7]=f2bf(v1.w);
        bf8_t a1 = pk.v;

        // layer 1: 2 MFMA, bias-initialized C
        f4_t c1[2];
        float bv0 = blds[s][l15], bv1 = blds[s][16 + l15];
        #pragma unroll
        for (int j = 0; j < 4; j++) { c1[0][j] = bv0; c1[1][j] = bv1; }
        #pragma unroll
        for (int n = 0; n < 2; n++) {
            bf8_t wf = *(bf8_t*)&wlds[(s * 6 + n) * 512 + lane * 8];
            c1[n] = __builtin_amdgcn_mfma_f32_16x16x32_bf16(a1, wf, c1[n], 0, 0, 0);
        }
        // ssp -> swizzled h tile (16x32 bf16)
        #pragma unroll
        for (int n = 0; n < 2; n++)
            #pragma unroll
            for (int r = 0; r < 4; r++) {
                int row = l4 * 4 + r, col = n * 16 + l15;
                hs[row * 32 + (((col >> 3) ^ (row & 3)) << 3) + (col & 7)] =
                    f2bf(ssp_f(c1[n][r]));
            }
        // layer-2 A-frag (h tile dead after this read)
        bf8_t ha = *(bf8_t*)&hs[l15 * 32 + ((l4 ^ (l15 & 3)) << 3)];

        // layer 2: two 32-col halves
        #pragma unroll 1
        for (int nh = 0; nh < 2; nh++) {
            f4_t c2[2];
            float d0 = blds[s][32 + nh * 32 + l15];
            float d1 = blds[s][32 + nh * 32 + 16 + l15];
            #pragma unroll
            for (int j = 0; j < 4; j++) { c2[0][j] = d0; c2[1][j] = d1; }
            #pragma unroll
            for (int n = 0; n < 2; n++) {
                bf8_t wf = *(bf8_t*)&wlds[(s * 6 + 2 + nh * 2 + n) * 512 + lane * 8];
                c2[n] = __builtin_amdgcn_mfma_f32_16x16x32_bf16(ha, wf, c2[n], 0, 0, 0);
            }
            #pragma unroll
            for (int n = 0; n < 2; n++)
                #pragma unroll
                for (int r = 0; r < 4; r++) {
                    int row = l4 * 4 + r, col = n * 16 + l15;
                    hs[row * 32 + (((col >> 3) ^ (row & 3)) << 3) + (col & 7)] =
                        f2bf(c2[n][r]);
                }
            // drain: lane owns row l15, 16-B chunk l4 -> scattered bucket rows
            bf8_t ov = *(bf8_t*)&hs[l15 * 32 + ((l4 ^ (l15 & 3)) << 3)];
            if (wp >= 0)
                *(bf8_t*)&wo[(size_t)wp * KF + nh * 32 + l4 * 8] = ov;
        }
    }
}

// ---- K3: one wave per bucket, streaming sum, plain store --------------------
__global__ __launch_bounds__(256, 8) void gather_k(
    const unsigned short* __restrict__ wo, const float* __restrict__ hx,
    const int* __restrict__ slist, const int* __restrict__ cur,
    float* __restrict__ z)
{
    int wv   = blockIdx.x * 4 + (threadIdx.x >> 6);   // bucket
    int lane = threadIdx.x & 63;
    int n    = cur[wv]; if (n > CAP) n = CAP;
    size_t base = (size_t)wv * CAP;
    float acc = 0.0f;
    int i = 0;
    for (; i + 4 <= n; i += 4) {
        int4 ss = *(const int4*)&slist[base + i];
        float w0 = bf2f(wo[(base+i+0) * KF + lane]);
        float w1 = bf2f(wo[(base+i+1) * KF + lane]);
        float w2 = bf2f(wo[(base+i+2) * KF + lane]);
        float w3 = bf2f(wo[(base+i+3) * KF + lane]);
        float h0 = hx[(size_t)ss.x * KF + lane];
        float h1 = hx[(size_t)ss.y * KF + lane];
        float h2 = hx[(size_t)ss.z * KF + lane];
        float h3 = hx[(size_t)ss.w * KF + lane];
        acc = __fmaf_rn(w0, h0, acc); acc = __fmaf_rn(w1, h1, acc);
        acc = __fmaf_rn(w2, h2, acc); acc = __fmaf_rn(w3, h3, acc);
    }
    for (; i < n; ++i) {
        int sj = slist[base + i];
        float w = bf2f(wo[(base+i) * KF + lane]);
        acc = __fmaf_rn(w, hx[(size_t)sj * KF + lane], acc);
    }
    z[(size_t)wv * KF + lane] = acc;   // all buckets written -> no z memset
}

// ---- K4: out = elec + sum_s z_s[:,elec] @ gW_s + gb_s (register-blocked) ----
__global__ __launch_bounds__(256, 4) void out_k(
    const float* __restrict__ elec, const float* __restrict__ z,
    const float* __restrict__ g0W, const float* __restrict__ g0b,
    const float* __restrict__ g1W, const float* __restrict__ g1b,
    const float* __restrict__ g2W, const float* __restrict__ g2b,
    float* __restrict__ out)
{
    __shared__ float zr[32 * 192];     // 24 KiB: 32 rows x 192 k
    const int tid = threadIdx.x;
    const int rb  = blockIdx.x * 32;   // 128 blocks x 32 elec rows

    // load z tile (coalesced float4)
    for (int u4 = tid; u4 < 32 * 48; u4 += 256) {
        int row = u4 / 48, kq = u4 % 48;
        int gr = rb + row;
        int node = (gr >> 6) * NPER + 16 + (gr & 63);
        int k = kq * 4, s = k >> 6, kk = k & 63;
        *(float4*)&zr[row * 192 + k] =
            *(const float4*)&z[((size_t)(s * NNODES + node)) * KF + kk];
    }
    __syncthreads();

    const int dt = tid & 31, rg = tid >> 5;
    const int d0 = dt * 4, r0 = rg * 4;

    float4 acc[4];
    float4 gb;
    gb.x = g0b[d0+0] + g1b[d0+0] + g2b[d0+0];
    gb.y = g0b[d0+1] + g1b[d0+1] + g2b[d0+1];
    gb.z = g0b[d0+2] + g1b[d0+2] + g2b[d0+2];
    gb.w = g0b[d0+3] + g1b[d0+3] + g2b[d0+3];
    #pragma unroll
    for (int n = 0; n < 4; n++) {
        float4 ev = *(const float4*)&elec[(size_t)(rb + r0 + n) * DF + d0];
        acc[n] = make_float4(ev.x + gb.x, ev.y + gb.y, ev.z + gb.z, ev.w + gb.w);
    }

    const float* Ws[3] = {g0W, g1W, g2W};
    #pragma unroll 1
    for (int s = 0; s < 3; s++) {
        const float* W = Ws[s];
        for (int kq = 0; kq < 16; kq++) {
            float4 zk[4];
            #pragma unroll
            for (int n = 0; n < 4; n++)
                zk[n] = *(float4*)&zr[(r0 + n) * 192 + s * 64 + kq * 4];
            #pragma unroll
            for (int j = 0; j < 4; j++) {
                float4 w = *(const float4*)&W[(kq * 4 + j) * DF + d0];
                #pragma unroll
                for (int n = 0; n < 4; n++) {
                    float zv = (j == 0) ? zk[n].x : (j == 1) ? zk[n].y
                             : (j == 2) ? zk[n].z : zk[n].w;
                    acc[n].x = __fmaf_rn(zv, w.x, acc[n].x);
                    acc[n].y = __fmaf_rn(zv, w.y, acc[n].y);
                    acc[n].z = __fmaf_rn(zv, w.z, acc[n].z);
                    acc[n].w = __fmaf_rn(zv, w.w, acc[n].w);
                }
            }
        }
    }
    #pragma unroll
    for (int n = 0; n < 4; n++)
        *(float4*)&out[(size_t)(rb + r0 + n) * DF + d0] = acc[n];
}

extern "C" void kernel_launch(void* const* d_in, const int* in_sizes, int n_in,
                              void* d_out, int out_size, void* d_ws, size_t ws_size,
                              hipStream_t stream)
{
    const float* nuc  = (const float*)d_in[0];
    const float* elec = (const float*)d_in[1];
    const float* dist = (const float*)d_in[2];
    const float* wsW1 = (const float*)d_in[3];
    const float* wsB1 = (const float*)d_in[4];
    const float* wsW2 = (const float*)d_in[5];
    const float* wsB2 = (const float*)d_in[6];
    const float* gsW  = (const float*)d_in[7];
    const float* gsB  = (const float*)d_in[8];
    const float* waW1 = (const float*)d_in[9];
    const float* waB1 = (const float*)d_in[10];
    const float* waW2 = (const float*)d_in[11];
    const float* waB2 = (const float*)d_in[12];
    const float* gaW  = (const float*)d_in[13];
    const float* gaB  = (const float*)d_in[14];
    const float* wnW1 = (const float*)d_in[15];
    const float* wnB1 = (const float*)d_in[16];
    const float* wnW2 = (const float*)d_in[17];
    const float* wnB2 = (const float*)d_in[18];
    const float* gnW  = (const float*)d_in[19];
    const float* gnB  = (const float*)d_in[20];
    const float* hW   = (const float*)d_in[21];
    const float* hb   = (const float*)d_in[22];
    const int* e_typ    = (const int*)d_in[23];
    const int* senders  = (const int*)d_in[24];
    const int* receivers= (const int*)d_in[25];
    float* out = (float*)d_out;

    char* ws = (char*)d_ws;
    int*   cur   = (int*)(ws + WS_CUR);
    float* z     = (float*)(ws + WS_Z);
    float* hx    = (float*)(ws + WS_HX);
    int*   slist = (int*)(ws + WS_SL);
    unsigned short* wo = (unsigned short*)(ws + WS_WO);

    zero_k<<<dim3(15), dim3(256), 0, stream>>>((float4*)cur);

    fused_k<<<dim3(HXBLK + EBLK), dim3(256), 0, stream>>>(
        nuc, elec, hW, hb, hx,
        dist, e_typ, senders, receivers, cur, slist, wo,
        wsW1, wsB1, wsW2, wsB2,    // slot 0: same (et==3)
        waW1, waB1, waW2, waB2,    // slot 1: anti (et==4)
        wnW1, wnB1, wnW2, wnB2);   // slot 2: n    (et==1)

    gather_k<<<dim3(NBUCK / 4), dim3(256), 0, stream>>>(wo, hx, slist, cur, z);

    out_k<<<dim3(128), dim3(256), 0, stream>>>(elec, z, gsW, gsB, gaW, gaB,
                                               gnW, gnB, out);
}

// Round 10
// 89.054 us; speedup vs baseline: 8.0751x; 1.1595x over previous
//
#include <hip/hip_runtime.h>
#include <math.h>

// Problem constants (fixed instance)
#define E_EDGES 524288
#define NNODES  5120
#define KF      64
#define DF      128
#define FF      32
#define NPER    80    // nodes per batch (16 nuc + 64 elec)
#define NBUCK   (3 * NNODES)      // 15360 buckets (slot, node)
#define CAP     64                // rows per bucket (lambda=20.5 -> ~1e-15 overflow)
#define HXBLK   1280              // hx blocks (5120 nodes, 4 waves/block)
#define EBLK    2048              // edge blocks (256 edges each)

// workspace layout (bytes)
#define WS_CUR   0u
#define CUR_BYTES (NBUCK*4u)                        // 61,440 (zeroed per call)
#define WS_Z     CUR_BYTES
#define Z_BYTES  (NBUCK*KF*4u)                      // 3,932,160 (fully written)
#define WS_HX    (WS_Z + Z_BYTES)
#define HX_BYTES (NNODES*KF*4u)                     // 1,310,720
#define WS_SL    (WS_HX + HX_BYTES)
#define SL_BYTES (NBUCK*CAP*4u)                     // 3,932,160
#define WS_WO    (WS_SL + SL_BYTES)                 // 9,236,480 (256-aligned)
#define WO_BYTES ((size_t)NBUCK*CAP*KF*2u)          // 125,829,120
#define WS_END   ((size_t)WS_WO + WO_BYTES)         // ~135 MB

typedef __attribute__((ext_vector_type(8))) short bf8_t;   // 8 bf16 (4 VGPRs)
typedef __attribute__((ext_vector_type(4))) float f4_t;    // MFMA 16x16 C/D

union U8 { bf8_t v; unsigned short u[8]; };

__device__ __forceinline__ float ssp_f(float x) {
    float t  = __expf(-fabsf(x));
    float sp = fmaxf(x, 0.0f) + __logf(1.0f + t);
    return sp - 0.6931471805599453f;
}

__device__ __forceinline__ unsigned short f2bf(float f) {
    union { float f; unsigned u; } c; c.f = f;
    unsigned r = c.u + 0x7FFFu + ((c.u >> 16) & 1u);   // RNE
    return (unsigned short)(r >> 16);
}
__device__ __forceinline__ float bf2f(unsigned short u) {
    union { unsigned u; float f; } c; c.u = ((unsigned)u) << 16;
    return c.f;
}

// ---- K1: zero the bucket cursors (61,440 B) ---------------------------------
__global__ void zero_k(float4* __restrict__ p)
{
    int i = blockIdx.x * blockDim.x + threadIdx.x;   // 15*256 = 3840 exact
    p[i] = make_float4(0.f, 0.f, 0.f, 0.f);
}

// ---- K2: fused hx build + block-sorted MFMA edge MLP + strided scatter ------
__global__ __launch_bounds__(256, 3) void fused_k(
    const float* __restrict__ nuc, const float* __restrict__ elec,
    const float* __restrict__ hW, const float* __restrict__ hb,
    float* __restrict__ hx,
    const float* __restrict__ dist, const int* __restrict__ et,
    const int* __restrict__ snd, const int* __restrict__ recv,
    int* __restrict__ cur, int* __restrict__ slist,
    unsigned short* __restrict__ wo,
    const float* __restrict__ w1_0, const float* __restrict__ b1_0,
    const float* __restrict__ w2_0, const float* __restrict__ b2_0,
    const float* __restrict__ w1_1, const float* __restrict__ b1_1,
    const float* __restrict__ w2_1, const float* __restrict__ b2_1,
    const float* __restrict__ w1_2, const float* __restrict__ b1_2,
    const float* __restrict__ w2_2, const float* __restrict__ b2_2)
{
    if (blockIdx.x < HXBLK) {
        // hx = concat(nuc, elec @ h_W + h_b), one wave per node
        int gw   = (blockIdx.x * 256 + threadIdx.x) >> 6;
        int lane = threadIdx.x & 63;
        int b = gw / NPER, p = gw % NPER;
        float v;
        if (p < 16) {
            v = nuc[((size_t)b * 16 + p) * KF + lane];
        } else {
            int pe = p - 16;
            const float* er = elec + ((size_t)b * 64 + pe) * DF;
            float acc = hb[lane];
            #pragma unroll 8
            for (int d = 0; d < DF; d++) acc = __fmaf_rn(er[d], hW[d * KF + lane], acc);
            v = acc;
        }
        hx[(size_t)gw * KF + lane] = v;
        return;
    }

    __shared__ unsigned short wlds[18 * 512];   // 18 KiB: pre-packed W frags
    __shared__ unsigned short dlds[256 * 32];   // 16 KiB: bf16 dist rows (XOR chunks)
    __shared__ float blds[3][96];               // biases: b1[32] | b2[64]
    __shared__ unsigned short tlds[4][512];     // per-wave 16x32 bf16 tile
    __shared__ unsigned short reorder[320];     // block-sorted local edge ids
    __shared__ int parr[256];                   // per-local-edge wo row (or -1)
    __shared__ int scnt[4][3], sbase_w[4][3];
    __shared__ int seg_tile[3];                 // first tile index per slot
    __shared__ int tcount;

    const int tid = threadIdx.x, lane = tid & 63, wid = tid >> 6;
    const int l15 = lane & 15, l4 = lane >> 4;
    const int ebase = (blockIdx.x - HXBLK) * 256;
    const int e = ebase + tid;

    // ---- issue own dist-row loads FIRST (latency overlapped with sort) ----
    const float4* dp = (const float4*)(dist + (size_t)e * FF);
    float4 dr[8];
    #pragma unroll
    for (int q = 0; q < 8; q++) dr[q] = dp[q];

    int etv = et[e], rv = recv[e], sv = snd[e];
    int slot = (etv == 3) ? 0 : (etv == 4) ? 1 : (etv == 1) ? 2 : -1;
    if ((rv % NPER) < 16) slot = -1;            // nuc receivers never read

    // ---- stage weights/biases, pad reorder ----
    {
        const float* W1s[3] = {w1_0, w1_1, w1_2};
        const float* W2s[3] = {w2_0, w2_1, w2_2};
        for (int f = wid; f < 18; f += 4) {
            int sg = f / 6, q = f % 6;
            const float* src = (q < 2) ? W1s[sg] : W2s[sg];
            int stride = (q < 2) ? 32 : 64;
            int cbase  = (q < 2) ? q * 16 : (q - 2) * 16;
            U8 pk;
            #pragma unroll
            for (int j = 0; j < 8; j++)
                pk.u[j] = f2bf(src[(l4 * 8 + j) * stride + cbase + l15]);
            *(bf8_t*)&wlds[f * 512 + lane * 8] = pk.v;
        }
        const float* B1s[3] = {b1_0, b1_1, b1_2};
        const float* B2s[3] = {b2_0, b2_1, b2_2};
        for (int i = tid; i < 288; i += 256) {
            int sg = i / 96, j = i % 96;
            blds[sg][j] = (j < 32) ? B1s[sg][j] : B2s[sg][j - 32];
        }
        for (int i = tid; i < 320; i += 256) reorder[i] = 0xFFFF;
    }
    // ---- park own dist row in LDS (bf16, chunk-XOR layout, b128 bank-floor) --
    #pragma unroll
    for (int c = 0; c < 4; c++) {
        float4 a = dr[2*c], b = dr[2*c+1];
        U8 pk;
        pk.u[0]=f2bf(a.x); pk.u[1]=f2bf(a.y); pk.u[2]=f2bf(a.z); pk.u[3]=f2bf(a.w);
        pk.u[4]=f2bf(b.x); pk.u[5]=f2bf(b.y); pk.u[6]=f2bf(b.z); pk.u[7]=f2bf(b.w);
        *(bf8_t*)&dlds[tid * 32 + ((c ^ (tid & 3)) << 3)] = pk.v;
    }
    // ---- block-local counting sort into 16-padded slot segments ----
    unsigned long long m0 = __ballot(slot == 0);
    unsigned long long m1 = __ballot(slot == 1);
    unsigned long long m2 = __ballot(slot == 2);
    if (lane == 0) {
        scnt[wid][0] = __popcll(m0); scnt[wid][1] = __popcll(m1); scnt[wid][2] = __popcll(m2);
    }
    __syncthreads();
    if (tid == 0) {
        int t = 0;
        for (int s = 0; s < 3; s++) {
            int b = 0;
            for (int w = 0; w < 4; w++) { sbase_w[w][s] = b; b += scnt[w][s]; }
            seg_tile[s] = t;
            t += (b + 15) >> 4;
        }
        tcount = t;                              // <= 19
    }
    __syncthreads();
    int wpos = -1;
    if (slot >= 0) {
        unsigned long long msel = (slot == 0) ? m0 : (slot == 1) ? m1 : m2;
        int rank = sbase_w[wid][slot] + __popcll(msel & ((1ull << lane) - 1ull));
        reorder[seg_tile[slot] * 16 + rank] = (unsigned short)tid;
        int bidx = slot * NNODES + rv;
        int p = atomicAdd(&cur[bidx], 1);
        if (p < CAP) { wpos = bidx * CAP + p; slist[wpos] = sv; }
    }
    parr[tid] = wpos;
    __syncthreads();

    // ---- per-wave tile processing (slot-pure 16x32 tiles, all-LDS operands) --
    unsigned short* hs = tlds[wid];
    const int T = tcount;
    for (int t = wid; t < T; t += 4) {
        int s = (t >= seg_tile[2]) ? 2 : (t >= seg_tile[1]) ? 1 : 0;
        s = __builtin_amdgcn_readfirstlane(s);

        int li  = reorder[t * 16 + l15];
        int lie = (li == 0xFFFF) ? 0 : li;
        int wp  = (li == 0xFFFF) ? -1 : parr[lie];

        // A-frag from LDS (row = local edge l15, chunk = l4)
        bf8_t a1 = *(bf8_t*)&dlds[lie * 32 + ((l4 ^ (lie & 3)) << 3)];

        // layer 1: 2 MFMA, bias-initialized C
        f4_t c1[2];
        float bv0 = blds[s][l15], bv1 = blds[s][16 + l15];
        #pragma unroll
        for (int j = 0; j < 4; j++) { c1[0][j] = bv0; c1[1][j] = bv1; }
        #pragma unroll
        for (int n = 0; n < 2; n++) {
            bf8_t wf = *(bf8_t*)&wlds[(s * 6 + n) * 512 + lane * 8];
            c1[n] = __builtin_amdgcn_mfma_f32_16x16x32_bf16(a1, wf, c1[n], 0, 0, 0);
        }
        // ssp -> swizzled h tile (16x32 bf16)
        #pragma unroll
        for (int n = 0; n < 2; n++)
            #pragma unroll
            for (int r = 0; r < 4; r++) {
                int row = l4 * 4 + r, col = n * 16 + l15;
                hs[row * 32 + (((col >> 3) ^ (row & 3)) << 3) + (col & 7)] =
                    f2bf(ssp_f(c1[n][r]));
            }
        // layer-2 A-frag (h tile dead after this read)
        bf8_t ha = *(bf8_t*)&hs[l15 * 32 + ((l4 ^ (l15 & 3)) << 3)];

        // layer 2: two 32-col halves
        #pragma unroll 1
        for (int nh = 0; nh < 2; nh++) {
            f4_t c2[2];
            float d0 = blds[s][32 + nh * 32 + l15];
            float d1 = blds[s][32 + nh * 32 + 16 + l15];
            #pragma unroll
            for (int j = 0; j < 4; j++) { c2[0][j] = d0; c2[1][j] = d1; }
            #pragma unroll
            for (int n = 0; n < 2; n++) {
                bf8_t wf = *(bf8_t*)&wlds[(s * 6 + 2 + nh * 2 + n) * 512 + lane * 8];
                c2[n] = __builtin_amdgcn_mfma_f32_16x16x32_bf16(ha, wf, c2[n], 0, 0, 0);
            }
            #pragma unroll
            for (int n = 0; n < 2; n++)
                #pragma unroll
                for (int r = 0; r < 4; r++) {
                    int row = l4 * 4 + r, col = n * 16 + l15;
                    hs[row * 32 + (((col >> 3) ^ (row & 3)) << 3) + (col & 7)] =
                        f2bf(c2[n][r]);
                }
            // drain: lane owns row l15, 16-B chunk l4 -> scattered bucket rows
            bf8_t ov = *(bf8_t*)&hs[l15 * 32 + ((l4 ^ (l15 & 3)) << 3)];
            if (wp >= 0)
                *(bf8_t*)&wo[(size_t)wp * KF + nh * 32 + l4 * 8] = ov;
        }
    }
}

// ---- K3: one wave per bucket, streaming sum, plain store --------------------
__global__ __launch_bounds__(256, 8) void gather_k(
    const unsigned short* __restrict__ wo, const float* __restrict__ hx,
    const int* __restrict__ slist, const int* __restrict__ cur,
    float* __restrict__ z)
{
    int wv   = blockIdx.x * 4 + (threadIdx.x >> 6);   // bucket
    int lane = threadIdx.x & 63;
    int n    = cur[wv]; if (n > CAP) n = CAP;
    size_t base = (size_t)wv * CAP;
    float acc = 0.0f;
    int i = 0;
    for (; i + 4 <= n; i += 4) {
        int4 ss = *(const int4*)&slist[base + i];
        float w0 = bf2f(wo[(base+i+0) * KF + lane]);
        float w1 = bf2f(wo[(base+i+1) * KF + lane]);
        float w2 = bf2f(wo[(base+i+2) * KF + lane]);
        float w3 = bf2f(wo[(base+i+3) * KF + lane]);
        float h0 = hx[(size_t)ss.x * KF + lane];
        float h1 = hx[(size_t)ss.y * KF + lane];
        float h2 = hx[(size_t)ss.z * KF + lane];
        float h3 = hx[(size_t)ss.w * KF + lane];
        acc = __fmaf_rn(w0, h0, acc); acc = __fmaf_rn(w1, h1, acc);
        acc = __fmaf_rn(w2, h2, acc); acc = __fmaf_rn(w3, h3, acc);
    }
    for (; i < n; ++i) {
        int sj = slist[base + i];
        float w = bf2f(wo[(base+i) * KF + lane]);
        acc = __fmaf_rn(w, hx[(size_t)sj * KF + lane], acc);
    }
    z[(size_t)wv * KF + lane] = acc;   // all buckets written -> no z memset
}

// ---- K4: out = elec + sum_s z_s[:,elec] @ gW_s + gb_s (high-TLP) ------------
__global__ __launch_bounds__(256, 4) void out_k(
    const float* __restrict__ elec, const float* __restrict__ z,
    const float* __restrict__ g0W, const float* __restrict__ g0b,
    const float* __restrict__ g1W, const float* __restrict__ g1b,
    const float* __restrict__ g2W, const float* __restrict__ g2b,
    float* __restrict__ out)
{
    __shared__ float zr[8 * 192];      // 6 KiB: 8 rows x 192 k
    const int tid = threadIdx.x;
    const int rb  = blockIdx.x * 8;    // 512 blocks x 8 elec rows

    // load z tile (coalesced float4)
    for (int u4 = tid; u4 < 8 * 48; u4 += 256) {
        int row = u4 / 48, kq = u4 % 48;
        int gr = rb + row;
        int node = (gr >> 6) * NPER + 16 + (gr & 63);
        int k = kq * 4, s = k >> 6, kk = k & 63;
        *(float4*)&zr[row * 192 + k] =
            *(const float4*)&z[((size_t)(s * NNODES + node)) * KF + kk];
    }
    __syncthreads();

    const int lane = tid & 63, wid = tid >> 6;
    const int r0 = wid * 2, r1 = r0 + 1;      // wave owns 2 rows
    const int d  = lane * 2;                  // float2 over DF=128

    float2 gb;
    gb.x = g0b[d]     + g1b[d]     + g2b[d];
    gb.y = g0b[d + 1] + g1b[d + 1] + g2b[d + 1];
    float2 e0 = *(const float2*)&elec[(size_t)(rb + r0) * DF + d];
    float2 e1 = *(const float2*)&elec[(size_t)(rb + r1) * DF + d];
    float2 a0 = make_float2(e0.x + gb.x, e0.y + gb.y);
    float2 a1 = make_float2(e1.x + gb.x, e1.y + gb.y);

    const float* Ws[3] = {g0W, g1W, g2W};
    #pragma unroll 1
    for (int s = 0; s < 3; s++) {
        const float* W = Ws[s];
        const float* zp0 = &zr[r0 * 192 + s * 64];
        const float* zp1 = &zr[r1 * 192 + s * 64];
        #pragma unroll 4
        for (int kk = 0; kk < 64; kk++) {
            float2 w = *(const float2*)&W[kk * DF + d];
            float z0 = zp0[kk], z1 = zp1[kk];
            a0.x = __fmaf_rn(z0, w.x, a0.x); a0.y = __fmaf_rn(z0, w.y, a0.y);
            a1.x = __fmaf_rn(z1, w.x, a1.x); a1.y = __fmaf_rn(z1, w.y, a1.y);
        }
    }
    *(float2*)&out[(size_t)(rb + r0) * DF + d] = a0;
    *(float2*)&out[(size_t)(rb + r1) * DF + d] = a1;
}

extern "C" void kernel_launch(void* const* d_in, const int* in_sizes, int n_in,
                              void* d_out, int out_size, void* d_ws, size_t ws_size,
                              hipStream_t stream)
{
    const float* nuc  = (const float*)d_in[0];
    const float* elec = (const float*)d_in[1];
    const float* dist = (const float*)d_in[2];
    const float* wsW1 = (const float*)d_in[3];
    const float* wsB1 = (const float*)d_in[4];
    const float* wsW2 = (const float*)d_in[5];
    const float* wsB2 = (const float*)d_in[6];
    const float* gsW  = (const float*)d_in[7];
    const float* gsB  = (const float*)d_in[8];
    const float* waW1 = (const float*)d_in[9];
    const float* waB1 = (const float*)d_in[10];
    const float* waW2 = (const float*)d_in[11];
    const float* waB2 = (const float*)d_in[12];
    const float* gaW  = (const float*)d_in[13];
    const float* gaB  = (const float*)d_in[14];
    const float* wnW1 = (const float*)d_in[15];
    const float* wnB1 = (const float*)d_in[16];
    const float* wnW2 = (const float*)d_in[17];
    const float* wnB2 = (const float*)d_in[18];
    const float* gnW  = (const float*)d_in[19];
    const float* gnB  = (const float*)d_in[20];
    const float* hW   = (const float*)d_in[21];
    const float* hb   = (const float*)d_in[22];
    const int* e_typ    = (const int*)d_in[23];
    const int* senders  = (const int*)d_in[24];
    const int* receivers= (const int*)d_in[25];
    float* out = (float*)d_out;

    char* ws = (char*)d_ws;
    int*   cur   = (int*)(ws + WS_CUR);
    float* z     = (float*)(ws + WS_Z);
    float* hx    = (float*)(ws + WS_HX);
    int*   slist = (int*)(ws + WS_SL);
    unsigned short* wo = (unsigned short*)(ws + WS_WO);

    zero_k<<<dim3(15), dim3(256), 0, stream>>>((float4*)cur);

    fused_k<<<dim3(HXBLK + EBLK), dim3(256), 0, stream>>>(
        nuc, elec, hW, hb, hx,
        dist, e_typ, senders, receivers, cur, slist, wo,
        wsW1, wsB1, wsW2, wsB2,    // slot 0: same (et==3)
        waW1, waB1, waW2, waB2,    // slot 1: anti (et==4)
        wnW1, wnB1, wnW2, wnB2);   // slot 2: n    (et==1)

    gather_k<<<dim3(NBUCK / 4), dim3(256), 0, stream>>>(wo, hx, slist, cur, z);

    out_k<<<dim3(512), dim3(256), 0, stream>>>(elec, z, gsW, gsB, gaW, gaB,
                                               gnW, gnB, out);
}

// Round 11
// 78.080 us; speedup vs baseline: 9.2101x; 1.1406x over previous
//
#include <hip/hip_runtime.h>
#include <math.h>

// Problem constants (fixed instance)
#define E_EDGES 524288
#define NNODES  5120
#define KF      64
#define DF      128
#define FF      32
#define NPER    80    // nodes per batch (16 nuc + 64 elec)
#define NBUCK   (3 * NNODES)      // 15360 buckets (slot, node)
#define CAP     64                // rows per bucket (lambda=20.5 -> ~1e-15 overflow)
#define HXBLK   1280              // hx blocks (5120 nodes, 4 waves/block)
#define EBLK    2048              // edge blocks (256 edges each)

// workspace layout (bytes)
#define WS_CUR   0u
#define CUR_BYTES (NBUCK*4u)                        // 61,440 (zeroed per call)
#define WS_Z     CUR_BYTES
#define Z_BYTES  (NBUCK*KF*4u)                      // 3,932,160 (fully written)
#define WS_HX    (WS_Z + Z_BYTES)
#define HX_BYTES (NNODES*KF*4u)                     // 1,310,720
#define WS_SL    (WS_HX + HX_BYTES)
#define SL_BYTES (NBUCK*CAP*4u)                     // 3,932,160
#define WS_WO    (WS_SL + SL_BYTES)                 // 9,236,480 (256-aligned)
#define WO_BYTES ((size_t)NBUCK*CAP*KF*2u)          // 125,829,120
#define WS_END   ((size_t)WS_WO + WO_BYTES)         // ~135 MB

typedef __attribute__((ext_vector_type(8))) short bf8_t;   // 8 bf16 (4 VGPRs)
typedef __attribute__((ext_vector_type(4))) float f4_t;    // MFMA 16x16 C/D

union U8 { bf8_t v; unsigned short u[8]; };

__device__ __forceinline__ float ssp_f(float x) {
    float t  = __expf(-fabsf(x));
    float sp = fmaxf(x, 0.0f) + __logf(1.0f + t);
    return sp - 0.6931471805599453f;
}

__device__ __forceinline__ unsigned short f2bf(float f) {
    union { float f; unsigned u; } c; c.f = f;
    unsigned r = c.u + 0x7FFFu + ((c.u >> 16) & 1u);   // RNE
    return (unsigned short)(r >> 16);
}
__device__ __forceinline__ float bf2f(unsigned short u) {
    union { unsigned u; float f; } c; c.u = ((unsigned)u) << 16;
    return c.f;
}

// ---- K1: zero the bucket cursors (61,440 B) ---------------------------------
__global__ void zero_k(float4* __restrict__ p)
{
    int i = blockIdx.x * blockDim.x + threadIdx.x;   // 15*256 = 3840 exact
    p[i] = make_float4(0.f, 0.f, 0.f, 0.f);
}

// ---- K2: fused hx build + block-sorted MFMA edge MLP + strided scatter ------
__global__ __launch_bounds__(256, 4) void fused_k(
    const float* __restrict__ nuc, const float* __restrict__ elec,
    const float* __restrict__ hW, const float* __restrict__ hb,
    float* __restrict__ hx,
    const float* __restrict__ dist, const int* __restrict__ et,
    const int* __restrict__ snd, const int* __restrict__ recv,
    int* __restrict__ cur, int* __restrict__ slist,
    unsigned short* __restrict__ wo,
    const float* __restrict__ w1_0, const float* __restrict__ b1_0,
    const float* __restrict__ w2_0, const float* __restrict__ b2_0,
    const float* __restrict__ w1_1, const float* __restrict__ b1_1,
    const float* __restrict__ w2_1, const float* __restrict__ b2_1,
    const float* __restrict__ w1_2, const float* __restrict__ b1_2,
    const float* __restrict__ w2_2, const float* __restrict__ b2_2)
{
    if (blockIdx.x < HXBLK) {
        // hx = concat(nuc, elec @ h_W + h_b), one wave per node
        int gw   = (blockIdx.x * 256 + threadIdx.x) >> 6;
        int lane = threadIdx.x & 63;
        int b = gw / NPER, p = gw % NPER;
        float v;
        if (p < 16) {
            v = nuc[((size_t)b * 16 + p) * KF + lane];
        } else {
            int pe = p - 16;
            const float* er = elec + ((size_t)b * 64 + pe) * DF;
            float acc = hb[lane];
            #pragma unroll 8
            for (int d = 0; d < DF; d++) acc = __fmaf_rn(er[d], hW[d * KF + lane], acc);
            v = acc;
        }
        hx[(size_t)gw * KF + lane] = v;
        return;
    }

    __shared__ unsigned short wlds[18 * 512];   // 18 KiB: pre-packed W frags
    __shared__ float blds[3][96];               // biases: b1[32] | b2[64]
    __shared__ unsigned short tlds[4][512];     // per-wave 16x32 bf16 tile
    __shared__ unsigned short reorder[320];     // block-sorted local edge ids
    __shared__ int parr[256];                   // per-local-edge wo row (or -1)
    __shared__ int scnt[4][3], sbase_w[4][3];
    __shared__ int seg_tile[3];                 // first tile index per slot
    __shared__ int tcount;

    const int tid = threadIdx.x, lane = tid & 63, wid = tid >> 6;
    const int l15 = lane & 15, l4 = lane >> 4;
    const int ebase = (blockIdx.x - HXBLK) * 256;
    const int e = ebase + tid;

    int etv = et[e], rv = recv[e], sv = snd[e];
    int slot = (etv == 3) ? 0 : (etv == 4) ? 1 : (etv == 1) ? 2 : -1;
    if ((rv % NPER) < 16) slot = -1;            // nuc receivers never read

    // ---- stage weights/biases, pad reorder ----
    {
        const float* W1s[3] = {w1_0, w1_1, w1_2};
        const float* W2s[3] = {w2_0, w2_1, w2_2};
        for (int f = wid; f < 18; f += 4) {
            int sg = f / 6, q = f % 6;
            const float* src = (q < 2) ? W1s[sg] : W2s[sg];
            int stride = (q < 2) ? 32 : 64;
            int cbase  = (q < 2) ? q * 16 : (q - 2) * 16;
            U8 pk;
            #pragma unroll
            for (int j = 0; j < 8; j++)
                pk.u[j] = f2bf(src[(l4 * 8 + j) * stride + cbase + l15]);
            *(bf8_t*)&wlds[f * 512 + lane * 8] = pk.v;
        }
        const float* B1s[3] = {b1_0, b1_1, b1_2};
        const float* B2s[3] = {b2_0, b2_1, b2_2};
        for (int i = tid; i < 288; i += 256) {
            int sg = i / 96, j = i % 96;
            blds[sg][j] = (j < 32) ? B1s[sg][j] : B2s[sg][j - 32];
        }
        for (int i = tid; i < 320; i += 256) reorder[i] = 0xFFFF;
    }
    // ---- block-local counting sort into 16-padded slot segments ----
    unsigned long long m0 = __ballot(slot == 0);
    unsigned long long m1 = __ballot(slot == 1);
    unsigned long long m2 = __ballot(slot == 2);
    if (lane == 0) {
        scnt[wid][0] = __popcll(m0); scnt[wid][1] = __popcll(m1); scnt[wid][2] = __popcll(m2);
    }
    __syncthreads();
    if (tid == 0) {
        int t = 0;
        for (int s = 0; s < 3; s++) {
            int b = 0;
            for (int w = 0; w < 4; w++) { sbase_w[w][s] = b; b += scnt[w][s]; }
            seg_tile[s] = t;
            t += (b + 15) >> 4;
        }
        tcount = t;                              // <= 19
    }
    __syncthreads();
    int wpos = -1;
    if (slot >= 0) {
        unsigned long long msel = (slot == 0) ? m0 : (slot == 1) ? m1 : m2;
        int rank = sbase_w[wid][slot] + __popcll(msel & ((1ull << lane) - 1ull));
        reorder[seg_tile[slot] * 16 + rank] = (unsigned short)tid;
        int bidx = slot * NNODES + rv;
        int p = atomicAdd(&cur[bidx], 1);
        if (p < CAP) { wpos = bidx * CAP + p; slist[wpos] = sv; }
    }
    parr[tid] = wpos;
    __syncthreads();

    const int T = tcount;

    // ---- PREFETCH: issue ALL wave-tile A-frag loads up front (ILP) ----------
    // Fully unrolled -> static register indices (no scratch). Pad lanes load a
    // safe default row (ebase+0) so no branches sit on the load path.
    bf8_t pa[5];
    int   pwp[5], psl[5];
    #pragma unroll
    for (int k = 0; k < 5; k++) {
        int t  = wid + k * 4;
        bool on = t < T;
        int tt  = on ? t : 0;
        int s   = (tt >= seg_tile[2]) ? 2 : (tt >= seg_tile[1]) ? 1 : 0;
        int li  = on ? reorder[tt * 16 + l15] : 0xFFFF;
        int lie = (li == 0xFFFF) ? 0 : li;
        pwp[k]  = (li == 0xFFFF) ? -1 : parr[lie];
        psl[k]  = s;
        const float* dp = dist + (size_t)(ebase + lie) * FF + l4 * 8;
        float4 v0 = *(const float4*)dp;
        float4 v1 = *(const float4*)(dp + 4);
        U8 pk;
        pk.u[0]=f2bf(v0.x); pk.u[1]=f2bf(v0.y); pk.u[2]=f2bf(v0.z); pk.u[3]=f2bf(v0.w);
        pk.u[4]=f2bf(v1.x); pk.u[5]=f2bf(v1.y); pk.u[6]=f2bf(v1.z); pk.u[7]=f2bf(v1.w);
        pa[k] = pk.v;
    }

    // ---- PROCESS: slot-pure 16x32 tiles, operands from registers/LDS --------
    unsigned short* hs = tlds[wid];
    #pragma unroll
    for (int k = 0; k < 5; k++) {
        if (wid + k * 4 >= T) break;
        int s  = __builtin_amdgcn_readfirstlane(psl[k]);
        int wp = pwp[k];
        bf8_t a1 = pa[k];

        // layer 1: 2 MFMA, bias-initialized C
        f4_t c1[2];
        float bv0 = blds[s][l15], bv1 = blds[s][16 + l15];
        #pragma unroll
        for (int j = 0; j < 4; j++) { c1[0][j] = bv0; c1[1][j] = bv1; }
        #pragma unroll
        for (int n = 0; n < 2; n++) {
            bf8_t wf = *(bf8_t*)&wlds[(s * 6 + n) * 512 + lane * 8];
            c1[n] = __builtin_amdgcn_mfma_f32_16x16x32_bf16(a1, wf, c1[n], 0, 0, 0);
        }
        // ssp -> swizzled h tile (16x32 bf16)
        #pragma unroll
        for (int n = 0; n < 2; n++)
            #pragma unroll
            for (int r = 0; r < 4; r++) {
                int row = l4 * 4 + r, col = n * 16 + l15;
                hs[row * 32 + (((col >> 3) ^ (row & 3)) << 3) + (col & 7)] =
                    f2bf(ssp_f(c1[n][r]));
            }
        // layer-2 A-frag (h tile dead after this read)
        bf8_t ha = *(bf8_t*)&hs[l15 * 32 + ((l4 ^ (l15 & 3)) << 3)];

        // layer 2: two 32-col halves
        #pragma unroll 1
        for (int nh = 0; nh < 2; nh++) {
            f4_t c2[2];
            float d0 = blds[s][32 + nh * 32 + l15];
            float d1 = blds[s][32 + nh * 32 + 16 + l15];
            #pragma unroll
            for (int j = 0; j < 4; j++) { c2[0][j] = d0; c2[1][j] = d1; }
            #pragma unroll
            for (int n = 0; n < 2; n++) {
                bf8_t wf = *(bf8_t*)&wlds[(s * 6 + 2 + nh * 2 + n) * 512 + lane * 8];
                c2[n] = __builtin_amdgcn_mfma_f32_16x16x32_bf16(ha, wf, c2[n], 0, 0, 0);
            }
            #pragma unroll
            for (int n = 0; n < 2; n++)
                #pragma unroll
                for (int r = 0; r < 4; r++) {
                    int row = l4 * 4 + r, col = n * 16 + l15;
                    hs[row * 32 + (((col >> 3) ^ (row & 3)) << 3) + (col & 7)] =
                        f2bf(c2[n][r]);
                }
            // drain: lane owns row l15, 16-B chunk l4 -> scattered bucket rows
            bf8_t ov = *(bf8_t*)&hs[l15 * 32 + ((l4 ^ (l15 & 3)) << 3)];
            if (wp >= 0)
                *(bf8_t*)&wo[(size_t)wp * KF + nh * 32 + l4 * 8] = ov;
        }
    }
}

// ---- K3: one wave per bucket, streaming sum, plain store --------------------
__global__ __launch_bounds__(256, 8) void gather_k(
    const unsigned short* __restrict__ wo, const float* __restrict__ hx,
    const int* __restrict__ slist, const int* __restrict__ cur,
    float* __restrict__ z)
{
    int wv   = blockIdx.x * 4 + (threadIdx.x >> 6);   // bucket
    int lane = threadIdx.x & 63;
    int n    = cur[wv]; if (n > CAP) n = CAP;
    size_t base = (size_t)wv * CAP;
    float acc = 0.0f;
    int i = 0;
    for (; i + 4 <= n; i += 4) {
        int4 ss = *(const int4*)&slist[base + i];
        float w0 = bf2f(wo[(base+i+0) * KF + lane]);
        float w1 = bf2f(wo[(base+i+1) * KF + lane]);
        float w2 = bf2f(wo[(base+i+2) * KF + lane]);
        float w3 = bf2f(wo[(base+i+3) * KF + lane]);
        float h0 = hx[(size_t)ss.x * KF + lane];
        float h1 = hx[(size_t)ss.y * KF + lane];
        float h2 = hx[(size_t)ss.z * KF + lane];
        float h3 = hx[(size_t)ss.w * KF + lane];
        acc = __fmaf_rn(w0, h0, acc); acc = __fmaf_rn(w1, h1, acc);
        acc = __fmaf_rn(w2, h2, acc); acc = __fmaf_rn(w3, h3, acc);
    }
    for (; i < n; ++i) {
        int sj = slist[base + i];
        float w = bf2f(wo[(base+i) * KF + lane]);
        acc = __fmaf_rn(w, hx[(size_t)sj * KF + lane], acc);
    }
    z[(size_t)wv * KF + lane] = acc;   // all buckets written -> no z memset
}

// ---- K4: out = elec + sum_s z_s[:,elec] @ gW_s + gb_s (high-TLP) ------------
__global__ __launch_bounds__(256, 4) void out_k(
    const float* __restrict__ elec, const float* __restrict__ z,
    const float* __restrict__ g0W, const float* __restrict__ g0b,
    const float* __restrict__ g1W, const float* __restrict__ g1b,
    const float* __restrict__ g2W, const float* __restrict__ g2b,
    float* __restrict__ out)
{
    __shared__ float zr[8 * 192];      // 6 KiB: 8 rows x 192 k
    const int tid = threadIdx.x;
    const int rb  = blockIdx.x * 8;    // 512 blocks x 8 elec rows

    // load z tile (coalesced float4)
    for (int u4 = tid; u4 < 8 * 48; u4 += 256) {
        int row = u4 / 48, kq = u4 % 48;
        int gr = rb + row;
        int node = (gr >> 6) * NPER + 16 + (gr & 63);
        int k = kq * 4, s = k >> 6, kk = k & 63;
        *(float4*)&zr[row * 192 + k] =
            *(const float4*)&z[((size_t)(s * NNODES + node)) * KF + kk];
    }
    __syncthreads();

    const int lane = tid & 63, wid = tid >> 6;
    const int r0 = wid * 2, r1 = r0 + 1;      // wave owns 2 rows
    const int d  = lane * 2;                  // float2 over DF=128

    float2 gb;
    gb.x = g0b[d]     + g1b[d]     + g2b[d];
    gb.y = g0b[d + 1] + g1b[d + 1] + g2b[d + 1];
    float2 e0 = *(const float2*)&elec[(size_t)(rb + r0) * DF + d];
    float2 e1 = *(const float2*)&elec[(size_t)(rb + r1) * DF + d];
    float2 a0 = make_float2(e0.x + gb.x, e0.y + gb.y);
    float2 a1 = make_float2(e1.x + gb.x, e1.y + gb.y);

    const float* Ws[3] = {g0W, g1W, g2W};
    #pragma unroll 1
    for (int s = 0; s < 3; s++) {
        const float* W = Ws[s];
        const float* zp0 = &zr[r0 * 192 + s * 64];
        const float* zp1 = &zr[r1 * 192 + s * 64];
        #pragma unroll 4
        for (int kk = 0; kk < 64; kk++) {
            float2 w = *(const float2*)&W[kk * DF + d];
            float z0 = zp0[kk], z1 = zp1[kk];
            a0.x = __fmaf_rn(z0, w.x, a0.x); a0.y = __fmaf_rn(z0, w.y, a0.y);
            a1.x = __fmaf_rn(z1, w.x, a1.x); a1.y = __fmaf_rn(z1, w.y, a1.y);
        }
    }
    *(float2*)&out[(size_t)(rb + r0) * DF + d] = a0;
    *(float2*)&out[(size_t)(rb + r1) * DF + d] = a1;
}

extern "C" void kernel_launch(void* const* d_in, const int* in_sizes, int n_in,
                              void* d_out, int out_size, void* d_ws, size_t ws_size,
                              hipStream_t stream)
{
    const float* nuc  = (const float*)d_in[0];
    const float* elec = (const float*)d_in[1];
    const float* dist = (const float*)d_in[2];
    const float* wsW1 = (const float*)d_in[3];
    const float* wsB1 = (const float*)d_in[4];
    const float* wsW2 = (const float*)d_in[5];
    const float* wsB2 = (const float*)d_in[6];
    const float* gsW  = (const float*)d_in[7];
    const float* gsB  = (const float*)d_in[8];
    const float* waW1 = (const float*)d_in[9];
    const float* waB1 = (const float*)d_in[10];
    const float* waW2 = (const float*)d_in[11];
    const float* waB2 = (const float*)d_in[12];
    const float* gaW  = (const float*)d_in[13];
    const float* gaB  = (const float*)d_in[14];
    const float* wnW1 = (const float*)d_in[15];
    const float* wnB1 = (const float*)d_in[16];
    const float* wnW2 = (const float*)d_in[17];
    const float* wnB2 = (const float*)d_in[18];
    const float* gnW  = (const float*)d_in[19];
    const float* gnB  = (const float*)d_in[20];
    const float* hW   = (const float*)d_in[21];
    const float* hb   = (const float*)d_in[22];
    const int* e_typ    = (const int*)d_in[23];
    const int* senders  = (const int*)d_in[24];
    const int* receivers= (const int*)d_in[25];
    float* out = (float*)d_out;

    char* ws = (char*)d_ws;
    int*   cur   = (int*)(ws + WS_CUR);
    float* z     = (float*)(ws + WS_Z);
    float* hx    = (float*)(ws + WS_HX);
    int*   slist = (int*)(ws + WS_SL);
    unsigned short* wo = (unsigned short*)(ws + WS_WO);

    zero_k<<<dim3(15), dim3(256), 0, stream>>>((float4*)cur);

    fused_k<<<dim3(HXBLK + EBLK), dim3(256), 0, stream>>>(
        nuc, elec, hW, hb, hx,
        dist, e_typ, senders, receivers, cur, slist, wo,
        wsW1, wsB1, wsW2, wsB2,    // slot 0: same (et==3)
        waW1, waB1, waW2, waB2,    // slot 1: anti (et==4)
        wnW1, wnB1, wnW2, wnB2);   // slot 2: n    (et==1)

    gather_k<<<dim3(NBUCK / 4), dim3(256), 0, stream>>>(wo, hx, slist, cur, z);

    out_k<<<dim3(512), dim3(256), 0, stream>>>(elec, z, gsW, gsB, gaW, gaB,
                                               gnW, gnB, out);
}